// Round 1
// baseline (3531.857 us; speedup 1.0000x reference)
//
#include <hip/hip_runtime.h>

#define BM 64
#define BN 64
#define BK 16

// ---------------- concat: A = [cls; x] ----------------
__global__ __launch_bounds__(256) void concat_k(const float* __restrict__ x,
    const float* __restrict__ cls, float* __restrict__ A)
{
  long t = (long)blockIdx.x * 256 + threadIdx.x;
  A[t] = (t < 512) ? cls[t] : x[t - 512];
}

// ---------------- per-row LN stats ----------------
__global__ __launch_bounds__(256) void lnstats_k(const float* __restrict__ X,
    float* __restrict__ mu, float* __restrict__ rs)
{
  __shared__ float red[256];
  const long row = blockIdx.x; const int tid = threadIdx.x;
  const float* r = X + row * 512;
  float v0 = r[tid], v1 = r[tid + 256];
  red[tid] = v0 + v1; __syncthreads();
  for (int s = 128; s > 0; s >>= 1) { if (tid < s) red[tid] += red[tid + s]; __syncthreads(); }
  float mean = red[0] * (1.f / 512.f); __syncthreads();
  float d0 = v0 - mean, d1 = v1 - mean;
  red[tid] = d0 * d0 + d1 * d1; __syncthreads();
  for (int s = 128; s > 0; s >>= 1) { if (tid < s) red[tid] += red[tid + s]; __syncthreads(); }
  if (tid == 0) { mu[row] = mean; rs[row] = rsqrtf(red[0] * (1.f / 512.f) + 1e-5f); }
}

// ---------------- generic tiled SGEMM ----------------
// C[r][c] = epi( alpha * sum_k pro(A[r][k]) * proB(B[k][c]) )
// LNF: A' = (A-mu[r])*rs[r]*lng[k]+lnb[k]
// DIAGB: B' = dac*(k==c) - B
// epi: + bias[c] (BIASF), + Res[r][c] (RESF), gelu (GELUF)
template<int LNF, int BIASF, int RESF, int GELUF, int DIAGB>
__global__ __launch_bounds__(256) void sgemm_k(
    const float* __restrict__ A, const float* __restrict__ Bw,
    float* __restrict__ C, const float* __restrict__ Res,
    const float* __restrict__ bias,
    const float* __restrict__ mu, const float* __restrict__ rs,
    const float* __restrict__ lng, const float* __restrict__ lnb,
    int Nr, int K, int Nc, float alpha, float dac,
    long sA, long sB, long sC)
{
  __shared__ float As[BK][BM + 4];
  __shared__ __align__(16) float Bs[BK][BN + 4];
  const int tid = threadIdx.x;
  const long z = blockIdx.z;
  const float* Ab = A + z * sA;
  const float* Bb = Bw + z * sB;
  float* Cb = C + z * sC;
  const int brow = blockIdx.y * BM;
  const int bcol = blockIdx.x * BN;
  const int tm = tid >> 4, tn = tid & 15;
  const int lam = tid >> 2;            // A tile row 0..63
  const int lak = (tid & 3) << 2;      // A tile k 0,4,8,12
  const int lbk = tid >> 4;            // B tile k 0..15
  const int lbn = (tid & 15) << 2;     // B tile col 0..60
  float rowmu = 0.f, rowrs = 0.f;
  if (LNF) { rowmu = mu[brow + lam]; rowrs = rs[brow + lam]; }
  float acc[4][4];
  #pragma unroll
  for (int i = 0; i < 4; i++)
    #pragma unroll
    for (int j = 0; j < 4; j++) acc[i][j] = 0.f;

  for (int k0 = 0; k0 < K; k0 += BK) {
    float4 av = *(const float4*)&Ab[(long)(brow + lam) * K + k0 + lak];
    if (LNF) {
      av.x = (av.x - rowmu) * rowrs * lng[k0 + lak + 0] + lnb[k0 + lak + 0];
      av.y = (av.y - rowmu) * rowrs * lng[k0 + lak + 1] + lnb[k0 + lak + 1];
      av.z = (av.z - rowmu) * rowrs * lng[k0 + lak + 2] + lnb[k0 + lak + 2];
      av.w = (av.w - rowmu) * rowrs * lng[k0 + lak + 3] + lnb[k0 + lak + 3];
    }
    As[lak + 0][lam] = av.x; As[lak + 1][lam] = av.y;
    As[lak + 2][lam] = av.z; As[lak + 3][lam] = av.w;
    float4 bv = *(const float4*)&Bb[(long)(k0 + lbk) * Nc + bcol + lbn];
    if (DIAGB) {
      int kr = k0 + lbk; int c0 = bcol + lbn;
      bv.x = ((kr == c0 + 0) ? dac : 0.f) - bv.x;
      bv.y = ((kr == c0 + 1) ? dac : 0.f) - bv.y;
      bv.z = ((kr == c0 + 2) ? dac : 0.f) - bv.z;
      bv.w = ((kr == c0 + 3) ? dac : 0.f) - bv.w;
    }
    *(float4*)&Bs[lbk][lbn] = bv;
    __syncthreads();
    #pragma unroll
    for (int kk = 0; kk < BK; kk++) {
      float a0 = As[kk][(tm << 2) + 0], a1 = As[kk][(tm << 2) + 1];
      float a2 = As[kk][(tm << 2) + 2], a3 = As[kk][(tm << 2) + 3];
      float b0 = Bs[kk][(tn << 2) + 0], b1 = Bs[kk][(tn << 2) + 1];
      float b2 = Bs[kk][(tn << 2) + 2], b3 = Bs[kk][(tn << 2) + 3];
      acc[0][0] += a0 * b0; acc[0][1] += a0 * b1; acc[0][2] += a0 * b2; acc[0][3] += a0 * b3;
      acc[1][0] += a1 * b0; acc[1][1] += a1 * b1; acc[1][2] += a1 * b2; acc[1][3] += a1 * b3;
      acc[2][0] += a2 * b0; acc[2][1] += a2 * b1; acc[2][2] += a2 * b2; acc[2][3] += a2 * b3;
      acc[3][0] += a3 * b0; acc[3][1] += a3 * b1; acc[3][2] += a3 * b2; acc[3][3] += a3 * b3;
    }
    __syncthreads();
  }
  #pragma unroll
  for (int i = 0; i < 4; i++) {
    const long row = brow + (tm << 2) + i;
    #pragma unroll
    for (int j = 0; j < 4; j++) {
      const int col = bcol + (tn << 2) + j;
      float v = acc[i][j] * alpha;
      if (BIASF) v += bias[col];
      if (RESF)  v += (Res + z * sC)[row * Nc + col];
      if (GELUF) v = 0.5f * v * (1.f + erff(v * 0.70710678118654752f));
      Cb[row * Nc + col] = v;
    }
  }
}

// ---------------- landmarks: QL (scaled), KL, KLT ----------------
__global__ __launch_bounds__(256) void landmarks_k(const float* __restrict__ QKV,
    float* __restrict__ QL, float* __restrict__ KL, float* __restrict__ KLT)
{
  int t = blockIdx.x * 256 + threadIdx.x;   // t = h*16384 + m*64 + d
  int d = t & 63; int m = (t >> 6) & 255; int h = t >> 14;
  const float* base = QKV + (long)(m * 32) * 1536 + (h << 6) + d;
  float sq = 0.f, sk = 0.f;
  for (int i = 0; i < 32; i++) { sq += base[(long)i * 1536]; sk += base[(long)i * 1536 + 512]; }
  QL[t] = sq * (0.125f / 32.f);
  float kv = sk * (1.f / 32.f);
  KL[t] = kv;
  KLT[(h << 14) + (d << 8) + m] = kv;
}

// ---------------- row softmax, width 256, in place ----------------
__global__ __launch_bounds__(256) void softmax256_k(float* __restrict__ X)
{
  __shared__ float red[256];
  const long row = blockIdx.x; const int tid = threadIdx.x;
  float v = X[row * 256 + tid];
  red[tid] = v; __syncthreads();
  for (int s = 128; s > 0; s >>= 1) { if (tid < s) red[tid] = fmaxf(red[tid], red[tid + s]); __syncthreads(); }
  float M = red[0]; __syncthreads();
  float e = __expf(v - M);
  red[tid] = e; __syncthreads();
  for (int s = 128; s > 0; s >>= 1) { if (tid < s) red[tid] += red[tid + s]; __syncthreads(); }
  float S = red[0];
  X[row * 256 + tid] = e / S;
}

// ---------------- pinv init scalars ----------------
__global__ __launch_bounds__(256) void rowsum_k(const float* __restrict__ X, float* __restrict__ out)
{
  int t = blockIdx.x * 256 + threadIdx.x;   // (h*256+i)
  const float* r = X + (long)t * 256;
  float s = 0.f;
  for (int j = 0; j < 256; j++) s += fabsf(r[j]);
  out[t] = s;
}
__global__ __launch_bounds__(256) void colsum_k(const float* __restrict__ X, float* __restrict__ out)
{
  int t = blockIdx.x * 256 + threadIdx.x; int h = t >> 8; int j = t & 255;
  const float* c = X + ((long)h << 16) + j;
  float s = 0.f;
  for (int i = 0; i < 256; i++) s += fabsf(c[(long)i << 8]);
  out[t] = s;
}
__global__ __launch_bounds__(256) void invscale_k(const float* __restrict__ rows,
    const float* __restrict__ cols, float* __restrict__ inv)
{
  __shared__ float red[256];
  int tid = threadIdx.x;
  float mr = -1e30f, mc = -1e30f;
  for (int i = tid; i < 2048; i += 256) { mr = fmaxf(mr, rows[i]); mc = fmaxf(mc, cols[i]); }
  red[tid] = mr; __syncthreads();
  for (int s = 128; s > 0; s >>= 1) { if (tid < s) red[tid] = fmaxf(red[tid], red[tid + s]); __syncthreads(); }
  mr = red[0]; __syncthreads();
  red[tid] = mc; __syncthreads();
  for (int s = 128; s > 0; s >>= 1) { if (tid < s) red[tid] = fmaxf(red[tid], red[tid + s]); __syncthreads(); }
  mc = red[0];
  if (tid == 0) inv[0] = 1.0f / (mr * mc);
}
__global__ __launch_bounds__(256) void zinit_k(const float* __restrict__ X,
    const float* __restrict__ inv, float* __restrict__ Z)
{
  long t = (long)blockIdx.x * 256 + threadIdx.x;  // h*65536 + i*256 + j
  int h = t >> 16; int i = (t >> 8) & 255; int j = t & 255;
  Z[t] = X[((long)h << 16) + ((long)j << 8) + i] * inv[0];
}

// ---------------- attn3 @ v (flash style, block per (h,m)) ----------------
__global__ __launch_bounds__(256) void attn3v_k(const float* __restrict__ QKV,
    const float* __restrict__ QL, float* __restrict__ AV)
{
  const int bid = blockIdx.x; const int h = bid & 7; const int m = bid >> 3;
  const int tid = threadIdx.x;
  __shared__ float ql[64];
  __shared__ float red[256];
  __shared__ float lg[8192];
  if (tid < 64) ql[tid] = QL[((h << 8) + m) * 64 + tid];
  __syncthreads();
  float lmax = -1e30f;
  for (int i = 0; i < 32; i++) {
    int n = tid + (i << 8);
    const float* kp = QKV + (long)n * 1536 + 512 + (h << 6);
    float s = 0.f;
    #pragma unroll
    for (int d = 0; d < 64; d += 4)
      s += ql[d] * kp[d] + ql[d+1] * kp[d+1] + ql[d+2] * kp[d+2] + ql[d+3] * kp[d+3];
    lg[n] = s; lmax = fmaxf(lmax, s);
  }
  red[tid] = lmax; __syncthreads();
  for (int s = 128; s > 0; s >>= 1) { if (tid < s) red[tid] = fmaxf(red[tid], red[tid + s]); __syncthreads(); }
  float M = red[0]; __syncthreads();
  float lsum = 0.f;
  for (int i = 0; i < 32; i++) { int n = tid + (i << 8); float e = __expf(lg[n] - M); lg[n] = e; lsum += e; }
  red[tid] = lsum; __syncthreads();
  for (int s = 128; s > 0; s >>= 1) { if (tid < s) red[tid] += red[tid + s]; __syncthreads(); }
  float S = red[0]; __syncthreads();
  const int c = tid >> 6, d = tid & 63;
  const float* vp = QKV + 1024 + (h << 6) + d;
  float acc = 0.f;
  for (int n = c * 2048; n < c * 2048 + 2048; n++) acc += lg[n] * vp[(long)n * 1536];
  red[tid] = acc; __syncthreads();
  if (tid < 64)
    AV[((h << 8) + m) * 64 + tid] = (red[tid] + red[tid + 64] + red[tid + 128] + red[tid + 192]) / S;
}

// ---------------- fused attn1 softmax @ CM (block per token n) ----------------
__global__ __launch_bounds__(256) void attn1C_k(const float* __restrict__ QKV,
    const float* __restrict__ KL, const float* __restrict__ CM, float* __restrict__ Bh)
{
  const long n = blockIdx.x; const int tid = threadIdx.x;
  __shared__ float q[512];
  __shared__ float p[256];
  __shared__ float red[256];
  q[tid]       = QKV[n * 1536 + tid] * 0.125f;
  q[tid + 256] = QKV[n * 1536 + 256 + tid] * 0.125f;
  __syncthreads();
  for (int h = 0; h < 8; h++) {
    const float* kl = KL + (long)((h << 8) + tid) * 64;
    const float* qh = q + (h << 6);
    float s = 0.f;
    #pragma unroll
    for (int d = 0; d < 64; d += 4)
      s += qh[d] * kl[d] + qh[d+1] * kl[d+1] + qh[d+2] * kl[d+2] + qh[d+3] * kl[d+3];
    red[tid] = s; __syncthreads();
    for (int st = 128; st > 0; st >>= 1) { if (tid < st) red[tid] = fmaxf(red[tid], red[tid + st]); __syncthreads(); }
    float M = red[0]; __syncthreads();
    float e = __expf(s - M);
    p[tid] = e; red[tid] = e; __syncthreads();
    for (int st = 128; st > 0; st >>= 1) { if (tid < st) red[tid] += red[tid + st]; __syncthreads(); }
    float S = red[0]; __syncthreads();
    const int c = tid >> 6, d = tid & 63;
    const float* cm = CM + (long)(h << 8) * 64 + d;
    float acc = 0.f;
    for (int m = c * 64; m < c * 64 + 64; m++) acc += p[m] * cm[(long)m * 64];
    red[tid] = acc; __syncthreads();
    if (tid < 64) {
      float o = (red[tid] + red[tid + 64] + red[tid + 128] + red[tid + 192]) * (1.f / S);
      Bh[n * 512 + (h << 6) + tid] = o;
    }
    __syncthreads();
  }
}

// ---------------- depthwise conv residual, += into Bh ----------------
__global__ __launch_bounds__(256) void convres_k(const float* __restrict__ QKV,
    const float* __restrict__ W, float* __restrict__ Bh)
{
  const int bid = blockIdx.x;                // 0..16383
  const int n = bid >> 1;
  const int j = ((bid & 1) << 8) + threadIdx.x;  // 0..511
  const int h = j >> 6;
  float acc = 0.f;
  #pragma unroll
  for (int kk = 0; kk < 33; kk++) {
    int nn = n + kk - 16;
    if (nn >= 0 && nn < 8192)
      acc += W[h * 33 + kk] * QKV[(long)nn * 1536 + 1024 + j];
  }
  Bh[(long)n * 512 + j] += acc;
}

// ---------------- host ----------------
extern "C" void kernel_launch(void* const* d_in, const int* in_sizes, int n_in,
                              void* d_out, int out_size, void* d_ws, size_t ws_size,
                              hipStream_t stream)
{
  const float* x     = (const float*)d_in[0];
  const float* cls   = (const float*)d_in[1];
  const float* ln1g  = (const float*)d_in[2];
  const float* ln1b  = (const float*)d_in[3];
  const float* wqkv  = (const float*)d_in[4];
  const float* wout  = (const float*)d_in[5];
  const float* bout  = (const float*)d_in[6];
  const float* convw = (const float*)d_in[7];
  const float* ln2g  = (const float*)d_in[8];
  const float* ln2b  = (const float*)d_in[9];
  const float* w1    = (const float*)d_in[10];
  const float* b1    = (const float*)d_in[11];
  const float* w2    = (const float*)d_in[12];
  const float* b2    = (const float*)d_in[13];
  float* out = (float*)d_out;
  float* ws  = (float*)d_ws;

  float* A    = ws;                    // [8192][512]
  float* Bh   = A + 4194304;           // [8192][512] head-major attn out
  float* QKV  = Bh + 4194304;          // [8192][1536]
  float* FF1  = Bh;                    // [8192][2048] overlays Bh+QKV (both dead then)
  float* mu1  = QKV + 12582912;
  float* rs1  = mu1 + 8192;
  float* mu2  = rs1 + 8192;
  float* rs2  = mu2 + 8192;
  float* QL   = rs2 + 8192;            // [8][256][64]
  float* KL   = QL + 131072;
  float* KLT  = KL + 131072;           // [8][64][256]
  float* ATT2 = KLT + 131072;          // [8][256][256]
  float* Za   = ATT2 + 524288;
  float* Zb   = Za + 524288;
  float* T1   = Zb + 524288;
  float* T2   = T1 + 524288;
  float* T3   = T2 + 524288;
  float* AV   = T3 + 524288;           // [8][256][64]
  float* CM   = AV + 131072;           // [8][256][64]
  float* rsum = CM + 131072;           // 2048
  float* csum = rsum + 2048;           // 2048
  float* inv  = csum + 2048;           // 1

  concat_k<<<16384, 256, 0, stream>>>(x, cls, A);
  lnstats_k<<<8192, 256, 0, stream>>>(A, mu1, rs1);
  // QKV = ln1(A) @ w_qkv
  sgemm_k<1,0,0,0,0><<<dim3(24,128,1), 256, 0, stream>>>(A, wqkv, QKV, nullptr, nullptr,
      mu1, rs1, ln1g, ln1b, 8192, 512, 1536, 1.f, 0.f, 0, 0, 0);
  landmarks_k<<<512, 256, 0, stream>>>(QKV, QL, KL, KLT);
  // attn2 logits = QL @ KLT  (batched over heads)
  sgemm_k<0,0,0,0,0><<<dim3(4,4,8), 256, 0, stream>>>(QL, KLT, ATT2, nullptr, nullptr,
      nullptr, nullptr, nullptr, nullptr, 256, 64, 256, 1.f, 0.f, 16384, 16384, 65536);
  softmax256_k<<<2048, 256, 0, stream>>>(ATT2);
  rowsum_k<<<8, 256, 0, stream>>>(ATT2, rsum);
  colsum_k<<<8, 256, 0, stream>>>(ATT2, csum);
  invscale_k<<<1, 256, 0, stream>>>(rsum, csum, inv);
  zinit_k<<<2048, 256, 0, stream>>>(ATT2, inv, Za);
  // iterative pinv: z = 0.25 z (13I - xz(15I - xz(7I - xz)))
  float* zc = Za; float* zo = Zb;
  for (int it = 0; it < 6; ++it) {
    sgemm_k<0,0,0,0,0><<<dim3(4,4,8), 256, 0, stream>>>(ATT2, zc, T1, nullptr, nullptr,
        nullptr, nullptr, nullptr, nullptr, 256, 256, 256, 1.f, 0.f, 65536, 65536, 65536);
    sgemm_k<0,0,0,0,1><<<dim3(4,4,8), 256, 0, stream>>>(T1, T1, T3, nullptr, nullptr,
        nullptr, nullptr, nullptr, nullptr, 256, 256, 256, 1.f, 7.f, 65536, 65536, 65536);
    sgemm_k<0,0,0,0,1><<<dim3(4,4,8), 256, 0, stream>>>(T1, T3, T2, nullptr, nullptr,
        nullptr, nullptr, nullptr, nullptr, 256, 256, 256, 1.f, 15.f, 65536, 65536, 65536);
    sgemm_k<0,0,0,0,1><<<dim3(4,4,8), 256, 0, stream>>>(zc, T2, zo, nullptr, nullptr,
        nullptr, nullptr, nullptr, nullptr, 256, 256, 256, 0.25f, 13.f, 65536, 65536, 65536);
    float* t = zc; zc = zo; zo = t;
  }
  // AV = softmax(q_l k^T) @ v
  attn3v_k<<<2048, 256, 0, stream>>>(QKV, QL, AV);
  // CM = Z @ AV
  sgemm_k<0,0,0,0,0><<<dim3(1,4,8), 256, 0, stream>>>(zc, AV, CM, nullptr, nullptr,
      nullptr, nullptr, nullptr, nullptr, 256, 256, 64, 1.f, 0.f, 65536, 16384, 16384);
  // Bh = softmax(q k_l^T) @ CM, then += conv residual
  attn1C_k<<<8192, 256, 0, stream>>>(QKV, KL, CM, Bh);
  convres_k<<<16384, 256, 0, stream>>>(QKV, convw, Bh);
  // A = A + Bh @ w_out + b_out
  sgemm_k<0,1,1,0,0><<<dim3(8,128,1), 256, 0, stream>>>(Bh, wout, A, A, bout,
      nullptr, nullptr, nullptr, nullptr, 8192, 512, 512, 1.f, 0.f, 0, 0, 0);
  lnstats_k<<<8192, 256, 0, stream>>>(A, mu2, rs2);
  // FF1 = gelu(ln2(A) @ w1 + b1)
  sgemm_k<1,1,0,1,0><<<dim3(32,128,1), 256, 0, stream>>>(A, w1, FF1, nullptr, b1,
      mu2, rs2, ln2g, ln2b, 8192, 512, 2048, 1.f, 0.f, 0, 0, 0);
  // out = A + FF1 @ w2 + b2
  sgemm_k<0,1,1,0,0><<<dim3(8,128,1), 256, 0, stream>>>(FF1, w2, out, A, b2,
      nullptr, nullptr, nullptr, nullptr, 8192, 2048, 512, 1.f, 0.f, 0, 0, 0);
}

// Round 2
// 1560.622 us; speedup vs baseline: 2.2631x; 2.2631x over previous
//
#include <hip/hip_runtime.h>

#define BM 64
#define BN 64
#define BK 16

// ---------------- concat: A = [cls; x] ----------------
__global__ __launch_bounds__(256) void concat_k(const float* __restrict__ x,
    const float* __restrict__ cls, float* __restrict__ A)
{
  long t = (long)blockIdx.x * 256 + threadIdx.x;
  A[t] = (t < 512) ? cls[t] : x[t - 512];
}

__global__ __launch_bounds__(256) void zero_k(float* __restrict__ p)
{
  p[(long)blockIdx.x * 256 + threadIdx.x] = 0.f;
}

// ---------------- per-row LN stats ----------------
__global__ __launch_bounds__(256) void lnstats_k(const float* __restrict__ X,
    float* __restrict__ mu, float* __restrict__ rs)
{
  __shared__ float red[256];
  const long row = blockIdx.x; const int tid = threadIdx.x;
  const float* r = X + row * 512;
  float v0 = r[tid], v1 = r[tid + 256];
  red[tid] = v0 + v1; __syncthreads();
  for (int s = 128; s > 0; s >>= 1) { if (tid < s) red[tid] += red[tid + s]; __syncthreads(); }
  float mean = red[0] * (1.f / 512.f); __syncthreads();
  float d0 = v0 - mean, d1 = v1 - mean;
  red[tid] = d0 * d0 + d1 * d1; __syncthreads();
  for (int s = 128; s > 0; s >>= 1) { if (tid < s) red[tid] += red[tid + s]; __syncthreads(); }
  if (tid == 0) { mu[row] = mean; rs[row] = rsqrtf(red[0] * (1.f / 512.f) + 1e-5f); }
}

// ---------------- generic tiled SGEMM ----------------
// C[r][c] = epi( alpha * sum_k pro(A[r][k]) * proB(B[k][c]) )
// batch z: h = z/NC, c = z%NC; base += h*s? + c*c?
template<int LNF, int BIASF, int RESF, int GELUF, int DIAGB, int ATOMIC>
__global__ __launch_bounds__(256) void sgemm_k(
    const float* __restrict__ A, const float* __restrict__ Bw,
    float* __restrict__ C, const float* __restrict__ Res,
    const float* __restrict__ bias,
    const float* __restrict__ mu, const float* __restrict__ rs,
    const float* __restrict__ lng, const float* __restrict__ lnb,
    int K, int Nc, float alpha, float dac,
    long lda, long ldb, long ldc,
    long sA, long sB, long sC, int NC, long cA, long cB, long cC)
{
  __shared__ float As[BK][BM + 4];
  __shared__ __align__(16) float Bs[BK][BN + 4];
  const int tid = threadIdx.x;
  const int zz = blockIdx.z;
  const int hh = zz / NC; const int cc = zz - hh * NC;
  const float* Ab = A + hh * sA + cc * cA;
  const float* Bb = Bw + hh * sB + cc * cB;
  float* Cb = C + hh * sC + cc * cC;
  const int brow = blockIdx.y * BM;
  const int bcol = blockIdx.x * BN;
  const int tm = tid >> 4, tn = tid & 15;
  const int lam = tid >> 2;            // A tile row 0..63
  const int lak = (tid & 3) << 2;      // A tile k 0,4,8,12
  const int lbk = tid >> 4;            // B tile k 0..15
  const int lbn = (tid & 15) << 2;     // B tile col 0..60
  float rowmu = 0.f, rowrs = 0.f;
  if (LNF) { rowmu = mu[brow + lam]; rowrs = rs[brow + lam]; }
  float acc[4][4];
  #pragma unroll
  for (int i = 0; i < 4; i++)
    #pragma unroll
    for (int j = 0; j < 4; j++) acc[i][j] = 0.f;

  for (int k0 = 0; k0 < K; k0 += BK) {
    float4 av = *(const float4*)&Ab[(long)(brow + lam) * lda + k0 + lak];
    if (LNF) {
      av.x = (av.x - rowmu) * rowrs * lng[k0 + lak + 0] + lnb[k0 + lak + 0];
      av.y = (av.y - rowmu) * rowrs * lng[k0 + lak + 1] + lnb[k0 + lak + 1];
      av.z = (av.z - rowmu) * rowrs * lng[k0 + lak + 2] + lnb[k0 + lak + 2];
      av.w = (av.w - rowmu) * rowrs * lng[k0 + lak + 3] + lnb[k0 + lak + 3];
    }
    As[lak + 0][lam] = av.x; As[lak + 1][lam] = av.y;
    As[lak + 2][lam] = av.z; As[lak + 3][lam] = av.w;
    float4 bv = *(const float4*)&Bb[(long)(k0 + lbk) * ldb + bcol + lbn];
    if (DIAGB) {
      int kr = k0 + lbk; int c0 = bcol + lbn;
      bv.x = ((kr == c0 + 0) ? dac : 0.f) - bv.x;
      bv.y = ((kr == c0 + 1) ? dac : 0.f) - bv.y;
      bv.z = ((kr == c0 + 2) ? dac : 0.f) - bv.z;
      bv.w = ((kr == c0 + 3) ? dac : 0.f) - bv.w;
    }
    *(float4*)&Bs[lbk][lbn] = bv;
    __syncthreads();
    #pragma unroll
    for (int kk = 0; kk < BK; kk++) {
      float a0 = As[kk][(tm << 2) + 0], a1 = As[kk][(tm << 2) + 1];
      float a2 = As[kk][(tm << 2) + 2], a3 = As[kk][(tm << 2) + 3];
      float b0 = Bs[kk][(tn << 2) + 0], b1 = Bs[kk][(tn << 2) + 1];
      float b2 = Bs[kk][(tn << 2) + 2], b3 = Bs[kk][(tn << 2) + 3];
      acc[0][0] += a0 * b0; acc[0][1] += a0 * b1; acc[0][2] += a0 * b2; acc[0][3] += a0 * b3;
      acc[1][0] += a1 * b0; acc[1][1] += a1 * b1; acc[1][2] += a1 * b2; acc[1][3] += a1 * b3;
      acc[2][0] += a2 * b0; acc[2][1] += a2 * b1; acc[2][2] += a2 * b2; acc[2][3] += a2 * b3;
      acc[3][0] += a3 * b0; acc[3][1] += a3 * b1; acc[3][2] += a3 * b2; acc[3][3] += a3 * b3;
    }
    __syncthreads();
  }
  #pragma unroll
  for (int i = 0; i < 4; i++) {
    const long row = brow + (tm << 2) + i;
    #pragma unroll
    for (int j = 0; j < 4; j++) {
      const int col = bcol + (tn << 2) + j;
      float v = acc[i][j] * alpha;
      if (BIASF) v += bias[col];
      if (RESF)  v += Res[row * ldc + col];
      if (GELUF) v = 0.5f * v * (1.f + erff(v * 0.70710678118654752f));
      if (ATOMIC) atomicAdd(&Cb[row * ldc + col], v);
      else        Cb[row * ldc + col] = v;
    }
  }
}

// ---------------- landmarks: QL (scaled), KL, KLT ----------------
__global__ __launch_bounds__(256) void landmarks_k(const float* __restrict__ QKV,
    float* __restrict__ QL, float* __restrict__ KL, float* __restrict__ KLT)
{
  int t = blockIdx.x * 256 + threadIdx.x;   // t = h*16384 + m*64 + d
  int d = t & 63; int m = (t >> 6) & 255; int h = t >> 14;
  const float* base = QKV + (long)(m * 32) * 1536 + (h << 6) + d;
  float sq = 0.f, sk = 0.f;
  for (int i = 0; i < 32; i++) { sq += base[(long)i * 1536]; sk += base[(long)i * 1536 + 512]; }
  QL[t] = sq * (0.125f / 32.f);
  float kv = sk * (1.f / 32.f);
  KL[t] = kv;
  KLT[(h << 14) + (d << 8) + m] = kv;
}

// ---------------- K transpose: KT[h][d][n] = QKV[n][512+h*64+d] ----------------
__global__ __launch_bounds__(256) void kt_k(const float* __restrict__ QKV,
    float* __restrict__ KT)
{
  __shared__ float t[64][65];
  const int h = blockIdx.x & 7; const int n0 = (blockIdx.x >> 3) << 6;
  const int c = threadIdx.x & 63; const int r4 = threadIdx.x >> 6;
  #pragma unroll 4
  for (int i = 0; i < 16; i++) {
    int r = r4 * 16 + i;
    t[r][c] = QKV[(long)(n0 + r) * 1536 + 512 + (h << 6) + c];
  }
  __syncthreads();
  #pragma unroll 4
  for (int i = 0; i < 16; i++) {
    int d = r4 * 16 + i;
    KT[((long)(h << 6) + d) * 8192 + n0 + c] = t[c][d];
  }
}

// ---------------- row softmax, width 256, in place ----------------
__global__ __launch_bounds__(256) void softmax256_k(float* __restrict__ X)
{
  __shared__ float red[256];
  const long row = blockIdx.x; const int tid = threadIdx.x;
  float v = X[row * 256 + tid];
  red[tid] = v; __syncthreads();
  for (int s = 128; s > 0; s >>= 1) { if (tid < s) red[tid] = fmaxf(red[tid], red[tid + s]); __syncthreads(); }
  float M = red[0]; __syncthreads();
  float e = __expf(v - M);
  red[tid] = e; __syncthreads();
  for (int s = 128; s > 0; s >>= 1) { if (tid < s) red[tid] += red[tid + s]; __syncthreads(); }
  float S = red[0];
  X[row * 256 + tid] = e / S;
}

// ---------------- row softmax, width 8192, in place ----------------
__global__ __launch_bounds__(256) void softmax8192_k(float* __restrict__ X)
{
  __shared__ float red[256];
  const long row = blockIdx.x; const int tid = threadIdx.x;
  float* r = X + row * 8192;
  float v[32]; float m = -1e30f;
  #pragma unroll
  for (int i = 0; i < 32; i++) { v[i] = r[tid + (i << 8)]; m = fmaxf(m, v[i]); }
  red[tid] = m; __syncthreads();
  for (int s = 128; s > 0; s >>= 1) { if (tid < s) red[tid] = fmaxf(red[tid], red[tid + s]); __syncthreads(); }
  float M = red[0]; __syncthreads();
  float sum = 0.f;
  #pragma unroll
  for (int i = 0; i < 32; i++) { v[i] = __expf(v[i] - M); sum += v[i]; }
  red[tid] = sum; __syncthreads();
  for (int s = 128; s > 0; s >>= 1) { if (tid < s) red[tid] += red[tid + s]; __syncthreads(); }
  float inv = 1.0f / red[0];
  #pragma unroll
  for (int i = 0; i < 32; i++) r[tid + (i << 8)] = v[i] * inv;
}

// ---------------- pinv init scalars ----------------
__global__ __launch_bounds__(256) void rowsum_k(const float* __restrict__ X, float* __restrict__ out)
{
  int t = blockIdx.x * 256 + threadIdx.x;
  const float* r = X + (long)t * 256;
  float s = 0.f;
  for (int j = 0; j < 256; j++) s += fabsf(r[j]);
  out[t] = s;
}
__global__ __launch_bounds__(256) void colsum_k(const float* __restrict__ X, float* __restrict__ out)
{
  int t = blockIdx.x * 256 + threadIdx.x; int h = t >> 8; int j = t & 255;
  const float* c = X + ((long)h << 16) + j;
  float s = 0.f;
  for (int i = 0; i < 256; i++) s += fabsf(c[(long)i << 8]);
  out[t] = s;
}
__global__ __launch_bounds__(256) void invscale_k(const float* __restrict__ rows,
    const float* __restrict__ cols, float* __restrict__ inv)
{
  __shared__ float red[256];
  int tid = threadIdx.x;
  float mr = -1e30f, mc = -1e30f;
  for (int i = tid; i < 2048; i += 256) { mr = fmaxf(mr, rows[i]); mc = fmaxf(mc, cols[i]); }
  red[tid] = mr; __syncthreads();
  for (int s = 128; s > 0; s >>= 1) { if (tid < s) red[tid] = fmaxf(red[tid], red[tid + s]); __syncthreads(); }
  mr = red[0]; __syncthreads();
  red[tid] = mc; __syncthreads();
  for (int s = 128; s > 0; s >>= 1) { if (tid < s) red[tid] = fmaxf(red[tid], red[tid + s]); __syncthreads(); }
  mc = red[0];
  if (tid == 0) inv[0] = 1.0f / (mr * mc);
}
__global__ __launch_bounds__(256) void zinit_k(const float* __restrict__ X,
    const float* __restrict__ inv, float* __restrict__ Z)
{
  long t = (long)blockIdx.x * 256 + threadIdx.x;
  int h = t >> 16; int i = (t >> 8) & 255; int j = t & 255;
  Z[t] = X[((long)h << 16) + ((long)j << 8) + i] * inv[0];
}

// ---------------- depthwise conv residual, += into Bh ----------------
__global__ __launch_bounds__(256) void convres_k(const float* __restrict__ QKV,
    const float* __restrict__ W, float* __restrict__ Bh)
{
  const int bid = blockIdx.x;                // 0..16383
  const int n = bid >> 1;
  const int j = ((bid & 1) << 8) + threadIdx.x;  // 0..511
  const int h = j >> 6;
  float acc = 0.f;
  #pragma unroll
  for (int kk = 0; kk < 33; kk++) {
    int nn = n + kk - 16;
    if (nn >= 0 && nn < 8192)
      acc += W[h * 33 + kk] * QKV[(long)nn * 1536 + 1024 + j];
  }
  Bh[(long)n * 512 + j] += acc;
}

// ---------------- host ----------------
extern "C" void kernel_launch(void* const* d_in, const int* in_sizes, int n_in,
                              void* d_out, int out_size, void* d_ws, size_t ws_size,
                              hipStream_t stream)
{
  const float* x     = (const float*)d_in[0];
  const float* cls   = (const float*)d_in[1];
  const float* ln1g  = (const float*)d_in[2];
  const float* ln1b  = (const float*)d_in[3];
  const float* wqkv  = (const float*)d_in[4];
  const float* wout  = (const float*)d_in[5];
  const float* bout  = (const float*)d_in[6];
  const float* convw = (const float*)d_in[7];
  const float* ln2g  = (const float*)d_in[8];
  const float* ln2b  = (const float*)d_in[9];
  const float* w1    = (const float*)d_in[10];
  const float* b1    = (const float*)d_in[11];
  const float* w2    = (const float*)d_in[12];
  const float* b2    = (const float*)d_in[13];
  float* out = (float*)d_out;
  float* ws  = (float*)d_ws;

  float* A    = ws;                    // [8192][512]
  float* Bh   = A + 4194304;           // [8192][512] head-major attn out
  float* KT   = Bh;                    // [8][64][8192] aliases Bh (dead until combine)
  float* QKV  = Bh + 4194304;          // [8192][1536]
  float* FF1  = Bh;                    // [8192][2048] overlays Bh+QKV (both dead then)
  float* mu1  = QKV + 12582912;
  float* rs1  = mu1 + 8192;
  float* mu2  = rs1 + 8192;
  float* rs2  = mu2 + 8192;
  float* QL   = rs2 + 8192;            // [8][256][64]
  float* KL   = QL + 131072;
  float* KLT  = KL + 131072;           // [8][64][256]
  float* ATT2 = KLT + 131072;          // [8][256][256]
  float* Za   = ATT2 + 524288;
  float* Zb   = Za + 524288;
  float* T1   = Zb + 524288;
  float* T2   = T1 + 524288;
  float* T3   = T2 + 524288;
  float* AV   = T3 + 524288;           // [8][256][64]
  float* CM   = AV + 131072;           // [8][256][64]
  float* rsum = CM + 131072;           // 2048
  float* csum = rsum + 2048;           // 2048
  float* inv  = csum + 2048;           // 1
  float* L    = inv + 4096;            // [8][256][8192] attn3 logits; then [8][8192][256] attn1

  concat_k<<<16384, 256, 0, stream>>>(x, cls, A);
  lnstats_k<<<8192, 256, 0, stream>>>(A, mu1, rs1);
  // QKV = ln1(A) @ w_qkv
  sgemm_k<1,0,0,0,0,0><<<dim3(24,128,1), 256, 0, stream>>>(A, wqkv, QKV, nullptr, nullptr,
      mu1, rs1, ln1g, ln1b, 512, 1536, 1.f, 0.f, 512, 1536, 1536, 0, 0, 0, 1, 0, 0, 0);
  landmarks_k<<<512, 256, 0, stream>>>(QKV, QL, KL, KLT);
  // attn2 logits = QL @ KLT  (batched over heads)
  sgemm_k<0,0,0,0,0,0><<<dim3(4,4,8), 256, 0, stream>>>(QL, KLT, ATT2, nullptr, nullptr,
      nullptr, nullptr, nullptr, nullptr, 64, 256, 1.f, 0.f, 64, 256, 256,
      16384, 16384, 65536, 1, 0, 0, 0);
  softmax256_k<<<2048, 256, 0, stream>>>(ATT2);
  rowsum_k<<<8, 256, 0, stream>>>(ATT2, rsum);
  colsum_k<<<8, 256, 0, stream>>>(ATT2, csum);
  invscale_k<<<1, 256, 0, stream>>>(rsum, csum, inv);
  zinit_k<<<2048, 256, 0, stream>>>(ATT2, inv, Za);
  // iterative pinv: z = 0.25 z (13I - xz(15I - xz(7I - xz)))
  float* zc = Za; float* zo = Zb;
  for (int it = 0; it < 6; ++it) {
    sgemm_k<0,0,0,0,0,0><<<dim3(4,4,8), 256, 0, stream>>>(ATT2, zc, T1, nullptr, nullptr,
        nullptr, nullptr, nullptr, nullptr, 256, 256, 1.f, 0.f, 256, 256, 256,
        65536, 65536, 65536, 1, 0, 0, 0);
    sgemm_k<0,0,0,0,1,0><<<dim3(4,4,8), 256, 0, stream>>>(T1, T1, T3, nullptr, nullptr,
        nullptr, nullptr, nullptr, nullptr, 256, 256, 1.f, 7.f, 256, 256, 256,
        65536, 65536, 65536, 1, 0, 0, 0);
    sgemm_k<0,0,0,0,1,0><<<dim3(4,4,8), 256, 0, stream>>>(T1, T3, T2, nullptr, nullptr,
        nullptr, nullptr, nullptr, nullptr, 256, 256, 1.f, 15.f, 256, 256, 256,
        65536, 65536, 65536, 1, 0, 0, 0);
    sgemm_k<0,0,0,0,1,0><<<dim3(4,4,8), 256, 0, stream>>>(zc, T2, zo, nullptr, nullptr,
        nullptr, nullptr, nullptr, nullptr, 256, 256, 0.25f, 13.f, 256, 256, 256,
        65536, 65536, 65536, 1, 0, 0, 0);
    float* t = zc; zc = zo; zo = t;
  }
  // ---- attn3 = softmax(QL @ K^T) @ V ----
  kt_k<<<1024, 256, 0, stream>>>(QKV, KT);
  // L[h] = QL[h] @ KT[h]   [256 x 8192]
  sgemm_k<0,0,0,0,0,0><<<dim3(128,4,8), 256, 0, stream>>>(QL, KT, L, nullptr, nullptr,
      nullptr, nullptr, nullptr, nullptr, 64, 8192, 1.f, 0.f, 64, 8192, 8192,
      16384, 524288, 2097152, 1, 0, 0, 0);
  softmax8192_k<<<2048, 256, 0, stream>>>(L);
  zero_k<<<512, 256, 0, stream>>>(AV);
  // AV[h] = P[h] @ V[h], split-K over 8 chunks of 1024, atomic combine
  sgemm_k<0,0,0,0,0,1><<<dim3(1,4,64), 256, 0, stream>>>(L, QKV + 1024, AV, nullptr, nullptr,
      nullptr, nullptr, nullptr, nullptr, 1024, 64, 1.f, 0.f, 8192, 1536, 64,
      2097152, 64, 16384, 8, 1024, 1572864, 0);
  // CM = Z @ AV
  sgemm_k<0,0,0,0,0,0><<<dim3(1,4,8), 256, 0, stream>>>(zc, AV, CM, nullptr, nullptr,
      nullptr, nullptr, nullptr, nullptr, 256, 64, 1.f, 0.f, 256, 64, 64,
      65536, 16384, 16384, 1, 0, 0, 0);
  // ---- attn1 = softmax(Q @ KL^T) @ CM ----
  // L1[h] = 0.125 * Q[h] @ KLT[h]   [8192 x 256]
  sgemm_k<0,0,0,0,0,0><<<dim3(4,128,8), 256, 0, stream>>>(QKV, KLT, L, nullptr, nullptr,
      nullptr, nullptr, nullptr, nullptr, 64, 256, 0.125f, 0.f, 1536, 256, 256,
      64, 16384, 2097152, 1, 0, 0, 0);
  softmax256_k<<<65536, 256, 0, stream>>>(L);
  // Bh[:, h*64:] = P1[h] @ CM[h]
  sgemm_k<0,0,0,0,0,0><<<dim3(1,128,8), 256, 0, stream>>>(L, CM, Bh, nullptr, nullptr,
      nullptr, nullptr, nullptr, nullptr, 256, 64, 1.f, 0.f, 256, 64, 512,
      2097152, 16384, 64, 1, 0, 0, 0);
  convres_k<<<16384, 256, 0, stream>>>(QKV, convw, Bh);
  // A = A + Bh @ w_out + b_out
  sgemm_k<0,1,1,0,0,0><<<dim3(8,128,1), 256, 0, stream>>>(Bh, wout, A, A, bout,
      nullptr, nullptr, nullptr, nullptr, 512, 512, 1.f, 0.f, 512, 512, 512,
      0, 0, 0, 1, 0, 0, 0);
  lnstats_k<<<8192, 256, 0, stream>>>(A, mu2, rs2);
  // FF1 = gelu(ln2(A) @ w1 + b1)
  sgemm_k<1,1,0,1,0,0><<<dim3(32,128,1), 256, 0, stream>>>(A, w1, FF1, nullptr, b1,
      mu2, rs2, ln2g, ln2b, 512, 2048, 1.f, 0.f, 512, 2048, 2048,
      0, 0, 0, 1, 0, 0, 0);
  // out = A + FF1 @ w2 + b2
  sgemm_k<0,1,1,0,0,0><<<dim3(8,128,1), 256, 0, stream>>>(FF1, w2, out, A, b2,
      nullptr, nullptr, nullptr, nullptr, 2048, 512, 1.f, 0.f, 2048, 512, 512,
      0, 0, 0, 1, 0, 0, 0);
}

// Round 3
// 930.570 us; speedup vs baseline: 3.7954x; 1.6771x over previous
//
#include <hip/hip_runtime.h>
#include <hip/hip_bf16.h>

#define BM 64
#define BN 64
#define BK 16

typedef __attribute__((ext_vector_type(8))) short short8;
typedef __attribute__((ext_vector_type(4))) float f32x4;

__device__ __forceinline__ void gl_lds16(const void* g, void* l) {
  __builtin_amdgcn_global_load_lds(
      (const __attribute__((address_space(1))) unsigned int*)g,
      (__attribute__((address_space(3))) unsigned int*)l, 16, 0, 0);
}

// ---------------- concat: A = [cls; x] ----------------
__global__ __launch_bounds__(256) void concat_k(const float* __restrict__ x,
    const float* __restrict__ cls, float* __restrict__ A)
{
  long t = (long)blockIdx.x * 256 + threadIdx.x;
  A[t] = (t < 512) ? cls[t] : x[t - 512];
}

__global__ __launch_bounds__(256) void zero_k(float* __restrict__ p)
{
  p[(long)blockIdx.x * 256 + threadIdx.x] = 0.f;
}

// ---------------- fused LN -> bf16 ----------------
__global__ __launch_bounds__(256) void ln_bf16_k(const float* __restrict__ X,
    const float* __restrict__ g, const float* __restrict__ b,
    __hip_bfloat16* __restrict__ O)
{
  __shared__ float red[256];
  const long row = blockIdx.x; const int tid = threadIdx.x;
  const float* r = X + row * 512;
  float v0 = r[tid], v1 = r[tid + 256];
  red[tid] = v0 + v1; __syncthreads();
  for (int s = 128; s > 0; s >>= 1) { if (tid < s) red[tid] += red[tid + s]; __syncthreads(); }
  float mean = red[0] * (1.f / 512.f); __syncthreads();
  float d0 = v0 - mean, d1 = v1 - mean;
  red[tid] = d0 * d0 + d1 * d1; __syncthreads();
  for (int s = 128; s > 0; s >>= 1) { if (tid < s) red[tid] += red[tid + s]; __syncthreads(); }
  float rs = rsqrtf(red[0] * (1.f / 512.f) + 1e-5f);
  O[row * 512 + tid]       = __float2bfloat16(d0 * rs * g[tid] + b[tid]);
  O[row * 512 + tid + 256] = __float2bfloat16(d1 * rs * g[tid + 256] + b[tid + 256]);
}

// ---------------- elementwise f32 -> bf16 ----------------
__global__ __launch_bounds__(256) void cvt_bf16_k(const float* __restrict__ X,
    __hip_bfloat16* __restrict__ O)
{
  long t = (long)blockIdx.x * 256 + threadIdx.x;
  O[t] = __float2bfloat16(X[t]);
}

// ---------------- weight transpose f32[K][N] -> bf16[N][K] ----------------
__global__ __launch_bounds__(256) void tconv_k(const float* __restrict__ W,
    __hip_bfloat16* __restrict__ WT, int K, int N)
{
  __shared__ float t[64][65];
  const int n0 = blockIdx.x << 6, k0 = blockIdx.y << 6;
  const int c = threadIdx.x & 63; const int r4 = threadIdx.x >> 6;
  #pragma unroll 4
  for (int i = 0; i < 16; i++) {
    int r = r4 * 16 + i;
    t[r][c] = W[(long)(k0 + r) * N + n0 + c];
  }
  __syncthreads();
  #pragma unroll 4
  for (int i = 0; i < 16; i++) {
    int r = r4 * 16 + i;
    WT[(long)(n0 + r) * K + k0 + c] = __float2bfloat16(t[c][r]);
  }
}

// ---------------- bf16 MFMA GEMM: C[M][N] = A[M][K] @ BT[N][K]^T ----------------
// EPI: 0 = f32 store; 1 = f32 store + bias + residual; 2 = bf16 store + bias + gelu
template<int EPI>
__global__ __launch_bounds__(256) void gemm_bf(
    const __hip_bfloat16* __restrict__ Ag, const __hip_bfloat16* __restrict__ Bg,
    void* __restrict__ Cg, const float* __restrict__ Res,
    const float* __restrict__ bias, int K, int N)
{
  __shared__ __align__(16) short As[2][128][32];
  __shared__ __align__(16) short Bs[2][128][32];
  const int tid = threadIdx.x;
  const int lane = tid & 63, wid = tid >> 6;
  const int brow = blockIdx.y << 7, bcol = blockIdx.x << 7;
  const int wr = (wid >> 1) << 6, wc = (wid & 1) << 6;
  const int fr = lane & 15, fs = lane >> 4;
  const int srow = lane >> 2;          // 0..15 within row group
  const int skp  = (lane & 3) << 3;    // k-elem offset within 32-half
  f32x4 acc[4][4];
  #pragma unroll
  for (int m = 0; m < 4; m++)
    #pragma unroll
    for (int n = 0; n < 4; n++) acc[m][n] = (f32x4){0.f, 0.f, 0.f, 0.f};

  const __hip_bfloat16* Arow = Ag + (long)brow * K;
  const __hip_bfloat16* Brow = Bg + (long)bcol * K;

  for (int k0 = 0; k0 < K; k0 += 64) {
    #pragma unroll
    for (int i = 0; i < 4; i++) {
      int c = (wid << 2) + i;          // chunk 0..15
      int rg = c >> 1, half = c & 1;
      gl_lds16(Arow + (long)(rg * 16 + srow) * K + k0 + half * 32 + skp,
               &As[half][rg * 16][0]);
      gl_lds16(Brow + (long)(rg * 16 + srow) * K + k0 + half * 32 + skp,
               &Bs[half][rg * 16][0]);
    }
    __syncthreads();
    #pragma unroll
    for (int kk = 0; kk < 2; kk++) {
      short8 a[4], b[4];
      #pragma unroll
      for (int m = 0; m < 4; m++)
        a[m] = *(const short8*)&As[kk][wr + m * 16 + fr][fs * 8];
      #pragma unroll
      for (int n = 0; n < 4; n++)
        b[n] = *(const short8*)&Bs[kk][wc + n * 16 + fr][fs * 8];
      #pragma unroll
      for (int m = 0; m < 4; m++)
        #pragma unroll
        for (int n = 0; n < 4; n++)
          acc[m][n] = __builtin_amdgcn_mfma_f32_16x16x32_bf16(a[m], b[n], acc[m][n], 0, 0, 0);
    }
    __syncthreads();
  }

  #pragma unroll
  for (int m = 0; m < 4; m++) {
    #pragma unroll
    for (int n = 0; n < 4; n++) {
      const int col = bcol + wc + n * 16 + fr;
      #pragma unroll
      for (int j = 0; j < 4; j++) {
        const long row = brow + wr + m * 16 + fs * 4 + j;
        float v = acc[m][n][j];
        if (EPI == 0) {
          ((float*)Cg)[row * N + col] = v;
        } else if (EPI == 1) {
          v += bias[col] + Res[row * N + col];
          ((float*)Cg)[row * N + col] = v;
        } else {
          v += bias[col];
          v = 0.5f * v * (1.f + erff(v * 0.70710678118654752f));
          ((__hip_bfloat16*)Cg)[row * N + col] = __float2bfloat16(v);
        }
      }
    }
  }
}

// ---------------- generic tiled SGEMM (fp32 paths) ----------------
template<int LNF, int BIASF, int RESF, int GELUF, int DIAGB, int ATOMIC>
__global__ __launch_bounds__(256) void sgemm_k(
    const float* __restrict__ A, const float* __restrict__ Bw,
    float* __restrict__ C, const float* __restrict__ Res,
    const float* __restrict__ bias,
    const float* __restrict__ mu, const float* __restrict__ rs,
    const float* __restrict__ lng, const float* __restrict__ lnb,
    int K, int Nc, float alpha, float dac,
    long lda, long ldb, long ldc,
    long sA, long sB, long sC, int NC, long cA, long cB, long cC)
{
  __shared__ float As[BK][BM + 4];
  __shared__ __align__(16) float Bs[BK][BN + 4];
  const int tid = threadIdx.x;
  const int zz = blockIdx.z;
  const int hh = zz / NC; const int cc = zz - hh * NC;
  const float* Ab = A + hh * sA + cc * cA;
  const float* Bb = Bw + hh * sB + cc * cB;
  float* Cb = C + hh * sC + cc * cC;
  const int brow = blockIdx.y * BM;
  const int bcol = blockIdx.x * BN;
  const int tm = tid >> 4, tn = tid & 15;
  const int lam = tid >> 2;
  const int lak = (tid & 3) << 2;
  const int lbk = tid >> 4;
  const int lbn = (tid & 15) << 2;
  float rowmu = 0.f, rowrs = 0.f;
  if (LNF) { rowmu = mu[brow + lam]; rowrs = rs[brow + lam]; }
  float acc[4][4];
  #pragma unroll
  for (int i = 0; i < 4; i++)
    #pragma unroll
    for (int j = 0; j < 4; j++) acc[i][j] = 0.f;

  for (int k0 = 0; k0 < K; k0 += BK) {
    float4 av = *(const float4*)&Ab[(long)(brow + lam) * lda + k0 + lak];
    if (LNF) {
      av.x = (av.x - rowmu) * rowrs * lng[k0 + lak + 0] + lnb[k0 + lak + 0];
      av.y = (av.y - rowmu) * rowrs * lng[k0 + lak + 1] + lnb[k0 + lak + 1];
      av.z = (av.z - rowmu) * rowrs * lng[k0 + lak + 2] + lnb[k0 + lak + 2];
      av.w = (av.w - rowmu) * rowrs * lng[k0 + lak + 3] + lnb[k0 + lak + 3];
    }
    As[lak + 0][lam] = av.x; As[lak + 1][lam] = av.y;
    As[lak + 2][lam] = av.z; As[lak + 3][lam] = av.w;
    float4 bv = *(const float4*)&Bb[(long)(k0 + lbk) * ldb + bcol + lbn];
    if (DIAGB) {
      int kr = k0 + lbk; int c0 = bcol + lbn;
      bv.x = ((kr == c0 + 0) ? dac : 0.f) - bv.x;
      bv.y = ((kr == c0 + 1) ? dac : 0.f) - bv.y;
      bv.z = ((kr == c0 + 2) ? dac : 0.f) - bv.z;
      bv.w = ((kr == c0 + 3) ? dac : 0.f) - bv.w;
    }
    *(float4*)&Bs[lbk][lbn] = bv;
    __syncthreads();
    #pragma unroll
    for (int kk = 0; kk < BK; kk++) {
      float a0 = As[kk][(tm << 2) + 0], a1 = As[kk][(tm << 2) + 1];
      float a2 = As[kk][(tm << 2) + 2], a3 = As[kk][(tm << 2) + 3];
      float b0 = Bs[kk][(tn << 2) + 0], b1 = Bs[kk][(tn << 2) + 1];
      float b2 = Bs[kk][(tn << 2) + 2], b3 = Bs[kk][(tn << 2) + 3];
      acc[0][0] += a0 * b0; acc[0][1] += a0 * b1; acc[0][2] += a0 * b2; acc[0][3] += a0 * b3;
      acc[1][0] += a1 * b0; acc[1][1] += a1 * b1; acc[1][2] += a1 * b2; acc[1][3] += a1 * b3;
      acc[2][0] += a2 * b0; acc[2][1] += a2 * b1; acc[2][2] += a2 * b2; acc[2][3] += a2 * b3;
      acc[3][0] += a3 * b0; acc[3][1] += a3 * b1; acc[3][2] += a3 * b2; acc[3][3] += a3 * b3;
    }
    __syncthreads();
  }
  #pragma unroll
  for (int i = 0; i < 4; i++) {
    const long row = brow + (tm << 2) + i;
    #pragma unroll
    for (int j = 0; j < 4; j++) {
      const int col = bcol + (tn << 2) + j;
      float v = acc[i][j] * alpha;
      if (BIASF) v += bias[col];
      if (RESF)  v += Res[row * ldc + col];
      if (GELUF) v = 0.5f * v * (1.f + erff(v * 0.70710678118654752f));
      if (ATOMIC) atomicAdd(&Cb[row * ldc + col], v);
      else        Cb[row * ldc + col] = v;
    }
  }
}

// ---------------- landmarks: QL (scaled), KL, KLT ----------------
__global__ __launch_bounds__(256) void landmarks_k(const float* __restrict__ QKV,
    float* __restrict__ QL, float* __restrict__ KL, float* __restrict__ KLT)
{
  int t = blockIdx.x * 256 + threadIdx.x;
  int d = t & 63; int m = (t >> 6) & 255; int h = t >> 14;
  const float* base = QKV + (long)(m * 32) * 1536 + (h << 6) + d;
  float sq = 0.f, sk = 0.f;
  for (int i = 0; i < 32; i++) { sq += base[(long)i * 1536]; sk += base[(long)i * 1536 + 512]; }
  QL[t] = sq * (0.125f / 32.f);
  float kv = sk * (1.f / 32.f);
  KL[t] = kv;
  KLT[(h << 14) + (d << 8) + m] = kv;
}

// ---------------- K transpose ----------------
__global__ __launch_bounds__(256) void kt_k(const float* __restrict__ QKV,
    float* __restrict__ KT)
{
  __shared__ float t[64][65];
  const int h = blockIdx.x & 7; const int n0 = (blockIdx.x >> 3) << 6;
  const int c = threadIdx.x & 63; const int r4 = threadIdx.x >> 6;
  #pragma unroll 4
  for (int i = 0; i < 16; i++) {
    int r = r4 * 16 + i;
    t[r][c] = QKV[(long)(n0 + r) * 1536 + 512 + (h << 6) + c];
  }
  __syncthreads();
  #pragma unroll 4
  for (int i = 0; i < 16; i++) {
    int d = r4 * 16 + i;
    KT[((long)(h << 6) + d) * 8192 + n0 + c] = t[c][d];
  }
}

// ---------------- row softmax, width 256, in place ----------------
__global__ __launch_bounds__(256) void softmax256_k(float* __restrict__ X)
{
  __shared__ float red[256];
  const long row = blockIdx.x; const int tid = threadIdx.x;
  float v = X[row * 256 + tid];
  red[tid] = v; __syncthreads();
  for (int s = 128; s > 0; s >>= 1) { if (tid < s) red[tid] = fmaxf(red[tid], red[tid + s]); __syncthreads(); }
  float M = red[0]; __syncthreads();
  float e = __expf(v - M);
  red[tid] = e; __syncthreads();
  for (int s = 128; s > 0; s >>= 1) { if (tid < s) red[tid] += red[tid + s]; __syncthreads(); }
  float S = red[0];
  X[row * 256 + tid] = e / S;
}

// ---------------- row softmax, width 8192, in place ----------------
__global__ __launch_bounds__(256) void softmax8192_k(float* __restrict__ X)
{
  __shared__ float red[256];
  const long row = blockIdx.x; const int tid = threadIdx.x;
  float* r = X + row * 8192;
  float v[32]; float m = -1e30f;
  #pragma unroll
  for (int i = 0; i < 32; i++) { v[i] = r[tid + (i << 8)]; m = fmaxf(m, v[i]); }
  red[tid] = m; __syncthreads();
  for (int s = 128; s > 0; s >>= 1) { if (tid < s) red[tid] = fmaxf(red[tid], red[tid + s]); __syncthreads(); }
  float M = red[0]; __syncthreads();
  float sum = 0.f;
  #pragma unroll
  for (int i = 0; i < 32; i++) { v[i] = __expf(v[i] - M); sum += v[i]; }
  red[tid] = sum; __syncthreads();
  for (int s = 128; s > 0; s >>= 1) { if (tid < s) red[tid] += red[tid + s]; __syncthreads(); }
  float inv = 1.0f / red[0];
  #pragma unroll
  for (int i = 0; i < 32; i++) r[tid + (i << 8)] = v[i] * inv;
}

// ---------------- pinv init scalars ----------------
__global__ __launch_bounds__(256) void rowsum_k(const float* __restrict__ X, float* __restrict__ out)
{
  int t = blockIdx.x * 256 + threadIdx.x;
  const float* r = X + (long)t * 256;
  float s = 0.f;
  for (int j = 0; j < 256; j++) s += fabsf(r[j]);
  out[t] = s;
}
__global__ __launch_bounds__(256) void colsum_k(const float* __restrict__ X, float* __restrict__ out)
{
  int t = blockIdx.x * 256 + threadIdx.x; int h = t >> 8; int j = t & 255;
  const float* c = X + ((long)h << 16) + j;
  float s = 0.f;
  for (int i = 0; i < 256; i++) s += fabsf(c[(long)i << 8]);
  out[t] = s;
}
__global__ __launch_bounds__(256) void invscale_k(const float* __restrict__ rows,
    const float* __restrict__ cols, float* __restrict__ inv)
{
  __shared__ float red[256];
  int tid = threadIdx.x;
  float mr = -1e30f, mc = -1e30f;
  for (int i = tid; i < 2048; i += 256) { mr = fmaxf(mr, rows[i]); mc = fmaxf(mc, cols[i]); }
  red[tid] = mr; __syncthreads();
  for (int s = 128; s > 0; s >>= 1) { if (tid < s) red[tid] = fmaxf(red[tid], red[tid + s]); __syncthreads(); }
  mr = red[0]; __syncthreads();
  red[tid] = mc; __syncthreads();
  for (int s = 128; s > 0; s >>= 1) { if (tid < s) red[tid] = fmaxf(red[tid], red[tid + s]); __syncthreads(); }
  mc = red[0];
  if (tid == 0) inv[0] = 1.0f / (mr * mc);
}
__global__ __launch_bounds__(256) void zinit_k(const float* __restrict__ X,
    const float* __restrict__ inv, float* __restrict__ Z)
{
  long t = (long)blockIdx.x * 256 + threadIdx.x;
  int h = t >> 16; int i = (t >> 8) & 255; int j = t & 255;
  Z[t] = X[((long)h << 16) + ((long)j << 8) + i] * inv[0];
}

// ---------------- depthwise conv residual, += into Bh ----------------
__global__ __launch_bounds__(256) void convres_k(const float* __restrict__ QKV,
    const float* __restrict__ W, float* __restrict__ Bh)
{
  const int bid = blockIdx.x;
  const int n = bid >> 1;
  const int j = ((bid & 1) << 8) + threadIdx.x;
  const int h = j >> 6;
  float acc = 0.f;
  #pragma unroll
  for (int kk = 0; kk < 33; kk++) {
    int nn = n + kk - 16;
    if (nn >= 0 && nn < 8192)
      acc += W[h * 33 + kk] * QKV[(long)nn * 1536 + 1024 + j];
  }
  Bh[(long)n * 512 + j] += acc;
}

// ---------------- host ----------------
extern "C" void kernel_launch(void* const* d_in, const int* in_sizes, int n_in,
                              void* d_out, int out_size, void* d_ws, size_t ws_size,
                              hipStream_t stream)
{
  const float* x     = (const float*)d_in[0];
  const float* cls   = (const float*)d_in[1];
  const float* ln1g  = (const float*)d_in[2];
  const float* ln1b  = (const float*)d_in[3];
  const float* wqkv  = (const float*)d_in[4];
  const float* wout  = (const float*)d_in[5];
  const float* bout  = (const float*)d_in[6];
  const float* convw = (const float*)d_in[7];
  const float* ln2g  = (const float*)d_in[8];
  const float* ln2b  = (const float*)d_in[9];
  const float* w1    = (const float*)d_in[10];
  const float* b1    = (const float*)d_in[11];
  const float* w2    = (const float*)d_in[12];
  const float* b2    = (const float*)d_in[13];
  float* out = (float*)d_out;
  float* ws  = (float*)d_ws;

  float* A    = ws;                    // [8192][512]
  float* Bh   = A + 4194304;           // [8192][512]
  float* KT   = Bh;                    // [8][64][8192] aliases Bh
  float* QKV  = Bh + 4194304;          // [8192][1536]
  float* mu1  = QKV + 12582912;
  float* rs1  = mu1 + 8192;
  float* mu2  = rs1 + 8192;
  float* rs2  = mu2 + 8192;
  float* QL   = rs2 + 8192;            // [8][256][64]
  float* KL   = QL + 131072;
  float* KLT  = KL + 131072;           // [8][64][256]
  float* ATT2 = KLT + 131072;          // [8][256][256]
  float* Za   = ATT2 + 524288;
  float* Zb   = Za + 524288;
  float* T1   = Zb + 524288;
  float* T2   = T1 + 524288;
  float* T3   = T2 + 524288;
  float* AV   = T3 + 524288;           // [8][256][64]
  float* CM   = AV + 131072;           // [8][256][64]
  float* rsum = CM + 131072;           // 2048
  float* csum = rsum + 2048;           // 2048
  float* inv  = csum + 2048;           // 1
  float* L    = inv + 4096;            // [8][256][8192] / [8][8192][256]

  // bf16 aliases (into dead fp32 regions)
  __hip_bfloat16* wqkvT = (__hip_bfloat16*)T1;   // [1536][512], dead before pinv uses T1
  __hip_bfloat16* w1T   = (__hip_bfloat16*)Za;   // [2048][512], after pinv/CM
  __hip_bfloat16* w2T   = (__hip_bfloat16*)Zb;   // [512][2048]
  __hip_bfloat16* woutT = (__hip_bfloat16*)T2;   // [512][512]
  __hip_bfloat16* ln1bf = (__hip_bfloat16*)L;            // [8192][512]
  __hip_bfloat16* ln2bf = (__hip_bfloat16*)L;            // [8192][512]
  __hip_bfloat16* FF1bf = (__hip_bfloat16*)(L + 2097152);// [8192][2048]
  __hip_bfloat16* Bhbf  = (__hip_bfloat16*)QKV;          // [8192][512], QKV dead

  concat_k<<<16384, 256, 0, stream>>>(x, cls, A);
  ln_bf16_k<<<8192, 256, 0, stream>>>(A, ln1g, ln1b, ln1bf);
  tconv_k<<<dim3(24, 8), 256, 0, stream>>>(wqkv, wqkvT, 512, 1536);
  // QKV = ln1bf @ wqkvT^T   (MFMA)
  gemm_bf<0><<<dim3(12, 64), 256, 0, stream>>>(ln1bf, wqkvT, QKV, nullptr, nullptr, 512, 1536);
  landmarks_k<<<512, 256, 0, stream>>>(QKV, QL, KL, KLT);
  // attn2 logits = QL @ KLT
  sgemm_k<0,0,0,0,0,0><<<dim3(4,4,8), 256, 0, stream>>>(QL, KLT, ATT2, nullptr, nullptr,
      nullptr, nullptr, nullptr, nullptr, 64, 256, 1.f, 0.f, 64, 256, 256,
      16384, 16384, 65536, 1, 0, 0, 0);
  softmax256_k<<<2048, 256, 0, stream>>>(ATT2);
  rowsum_k<<<8, 256, 0, stream>>>(ATT2, rsum);
  colsum_k<<<8, 256, 0, stream>>>(ATT2, csum);
  invscale_k<<<1, 256, 0, stream>>>(rsum, csum, inv);
  zinit_k<<<2048, 256, 0, stream>>>(ATT2, inv, Za);
  // iterative pinv
  float* zc = Za; float* zo = Zb;
  for (int it = 0; it < 6; ++it) {
    sgemm_k<0,0,0,0,0,0><<<dim3(4,4,8), 256, 0, stream>>>(ATT2, zc, T1, nullptr, nullptr,
        nullptr, nullptr, nullptr, nullptr, 256, 256, 1.f, 0.f, 256, 256, 256,
        65536, 65536, 65536, 1, 0, 0, 0);
    sgemm_k<0,0,0,0,1,0><<<dim3(4,4,8), 256, 0, stream>>>(T1, T1, T3, nullptr, nullptr,
        nullptr, nullptr, nullptr, nullptr, 256, 256, 1.f, 7.f, 256, 256, 256,
        65536, 65536, 65536, 1, 0, 0, 0);
    sgemm_k<0,0,0,0,1,0><<<dim3(4,4,8), 256, 0, stream>>>(T1, T3, T2, nullptr, nullptr,
        nullptr, nullptr, nullptr, nullptr, 256, 256, 1.f, 15.f, 256, 256, 256,
        65536, 65536, 65536, 1, 0, 0, 0);
    sgemm_k<0,0,0,0,1,0><<<dim3(4,4,8), 256, 0, stream>>>(zc, T2, zo, nullptr, nullptr,
        nullptr, nullptr, nullptr, nullptr, 256, 256, 0.25f, 13.f, 256, 256, 256,
        65536, 65536, 65536, 1, 0, 0, 0);
    float* t = zc; zc = zo; zo = t;
  }
  // ---- attn3 = softmax(QL @ K^T) @ V ----
  kt_k<<<1024, 256, 0, stream>>>(QKV, KT);
  sgemm_k<0,0,0,0,0,0><<<dim3(128,4,8), 256, 0, stream>>>(QL, KT, L, nullptr, nullptr,
      nullptr, nullptr, nullptr, nullptr, 64, 8192, 1.f, 0.f, 64, 8192, 8192,
      16384, 524288, 2097152, 1, 0, 0, 0);
  softmax8192_k<<<2048, 256, 0, stream>>>(L);
  zero_k<<<512, 256, 0, stream>>>(AV);
  sgemm_k<0,0,0,0,0,1><<<dim3(1,4,64), 256, 0, stream>>>(L, QKV + 1024, AV, nullptr, nullptr,
      nullptr, nullptr, nullptr, nullptr, 1024, 64, 1.f, 0.f, 8192, 1536, 64,
      2097152, 64, 16384, 8, 1024, 1572864, 0);
  // CM = Z @ AV
  sgemm_k<0,0,0,0,0,0><<<dim3(1,4,8), 256, 0, stream>>>(zc, AV, CM, nullptr, nullptr,
      nullptr, nullptr, nullptr, nullptr, 256, 64, 1.f, 0.f, 256, 64, 64,
      65536, 16384, 16384, 1, 0, 0, 0);
  // weight transposes for the tail GEMMs (Za/Zb/T2 now dead)
  tconv_k<<<dim3(32, 8), 256, 0, stream>>>(w1, w1T, 512, 2048);
  tconv_k<<<dim3(8, 32), 256, 0, stream>>>(w2, w2T, 2048, 512);
  tconv_k<<<dim3(8, 8), 256, 0, stream>>>(wout, woutT, 512, 512);
  // ---- attn1 = softmax(Q @ KL^T) @ CM ----
  sgemm_k<0,0,0,0,0,0><<<dim3(4,128,8), 256, 0, stream>>>(QKV, KLT, L, nullptr, nullptr,
      nullptr, nullptr, nullptr, nullptr, 64, 256, 0.125f, 0.f, 1536, 256, 256,
      64, 16384, 2097152, 1, 0, 0, 0);
  softmax256_k<<<65536, 256, 0, stream>>>(L);
  sgemm_k<0,0,0,0,0,0><<<dim3(1,128,8), 256, 0, stream>>>(L, CM, Bh, nullptr, nullptr,
      nullptr, nullptr, nullptr, nullptr, 256, 64, 1.f, 0.f, 256, 64, 512,
      2097152, 16384, 64, 1, 0, 0, 0);
  convres_k<<<16384, 256, 0, stream>>>(QKV, convw, Bh);
  // Bh -> bf16 (QKV now dead)
  cvt_bf16_k<<<16384, 256, 0, stream>>>(Bh, Bhbf);
  // A = A + Bhbf @ woutT^T + bout   (MFMA)
  gemm_bf<1><<<dim3(4, 64), 256, 0, stream>>>(Bhbf, woutT, A, A, bout, 512, 512);
  ln_bf16_k<<<8192, 256, 0, stream>>>(A, ln2g, ln2b, ln2bf);
  // FF1bf = gelu(ln2bf @ w1T^T + b1)   (MFMA, bf16 out)
  gemm_bf<2><<<dim3(16, 64), 256, 0, stream>>>(ln2bf, w1T, FF1bf, nullptr, b1, 512, 2048);
  // out = A + FF1bf @ w2T^T + b2   (MFMA)
  gemm_bf<1><<<dim3(4, 64), 256, 0, stream>>>(FF1bf, w2T, out, A, b2, 2048, 512);
}

// Round 4
// 797.015 us; speedup vs baseline: 4.4314x; 1.1676x over previous
//
#include <hip/hip_runtime.h>
#include <hip/hip_bf16.h>

typedef __attribute__((ext_vector_type(8))) short short8;
typedef __attribute__((ext_vector_type(4))) short short4v;
typedef __attribute__((ext_vector_type(4))) float f32x4;

__device__ __forceinline__ void gl_lds16(const void* g, void* l) {
  __builtin_amdgcn_global_load_lds(
      (const __attribute__((address_space(1))) unsigned int*)g,
      (__attribute__((address_space(3))) unsigned int*)l, 16, 0, 0);
}
__device__ __forceinline__ unsigned short f2b(float f) {
  __hip_bfloat16 h = __float2bfloat16(f);
  return *reinterpret_cast<unsigned short*>(&h);
}
__device__ __forceinline__ float b2f(unsigned short u) {
  unsigned v = ((unsigned)u) << 16;
  return __uint_as_float(v);
}

// ---------------- concat: A = [cls; x] ----------------
__global__ __launch_bounds__(256) void concat_k(const float* __restrict__ x,
    const float* __restrict__ cls, float* __restrict__ A)
{
  long t = (long)blockIdx.x * 256 + threadIdx.x;
  A[t] = (t < 512) ? cls[t] : x[t - 512];
}

// ---------------- fused LN -> bf16 ----------------
__global__ __launch_bounds__(256) void ln_bf16_k(const float* __restrict__ X,
    const float* __restrict__ g, const float* __restrict__ b,
    __hip_bfloat16* __restrict__ O)
{
  __shared__ float red[256];
  const long row = blockIdx.x; const int tid = threadIdx.x;
  const float* r = X + row * 512;
  float v0 = r[tid], v1 = r[tid + 256];
  red[tid] = v0 + v1; __syncthreads();
  for (int s = 128; s > 0; s >>= 1) { if (tid < s) red[tid] += red[tid + s]; __syncthreads(); }
  float mean = red[0] * (1.f / 512.f); __syncthreads();
  float d0 = v0 - mean, d1 = v1 - mean;
  red[tid] = d0 * d0 + d1 * d1; __syncthreads();
  for (int s = 128; s > 0; s >>= 1) { if (tid < s) red[tid] += red[tid + s]; __syncthreads(); }
  float rs = rsqrtf(red[0] * (1.f / 512.f) + 1e-5f);
  O[row * 512 + tid]       = __float2bfloat16(d0 * rs * g[tid] + b[tid]);
  O[row * 512 + tid + 256] = __float2bfloat16(d1 * rs * g[tid + 256] + b[tid + 256]);
}

// ---------------- elementwise f32 -> bf16 ----------------
__global__ __launch_bounds__(256) void cvt_bf16_k(const float* __restrict__ X,
    __hip_bfloat16* __restrict__ O)
{
  long t = (long)blockIdx.x * 256 + threadIdx.x;
  O[t] = __float2bfloat16(X[t]);
}

// ---------------- weight transpose f32[K][N] -> bf16[N][K] ----------------
__global__ __launch_bounds__(256) void tconv_k(const float* __restrict__ W,
    __hip_bfloat16* __restrict__ WT, int K, int N)
{
  __shared__ float t[64][65];
  const int n0 = blockIdx.x << 6, k0 = blockIdx.y << 6;
  const int c = threadIdx.x & 63; const int r4 = threadIdx.x >> 6;
  #pragma unroll 4
  for (int i = 0; i < 16; i++) {
    int r = r4 * 16 + i;
    t[r][c] = W[(long)(k0 + r) * N + n0 + c];
  }
  __syncthreads();
  #pragma unroll 4
  for (int i = 0; i < 16; i++) {
    int r = r4 * 16 + i;
    WT[(long)(n0 + r) * K + k0 + c] = __float2bfloat16(t[c][r]);
  }
}

// ---------------- main bf16 MFMA GEMM (dense path): C = A @ B^T ----------------
// EPI: 1 = f32 + bias + residual; 2 = bf16 + bias + gelu; 3 = f32 store + head-major Q/K bf16
template<int EPI>
__global__ __launch_bounds__(256) void gemm_bf(
    const __hip_bfloat16* __restrict__ Ag, const __hip_bfloat16* __restrict__ Bg,
    void* __restrict__ Cg, const float* __restrict__ Res,
    const float* __restrict__ bias, int K, int N,
    __hip_bfloat16* __restrict__ Qb, __hip_bfloat16* __restrict__ Kb)
{
  __shared__ __align__(16) short As[2][128][32];
  __shared__ __align__(16) short Bs[2][128][32];
  const int tid = threadIdx.x;
  const int lane = tid & 63, wid = tid >> 6;
  const int brow = blockIdx.y << 7, bcol = blockIdx.x << 7;
  const int wr = (wid >> 1) << 6, wc = (wid & 1) << 6;
  const int fr = lane & 15, fs = lane >> 4;
  const int srow = lane >> 2;
  const int skp  = (lane & 3) << 3;
  f32x4 acc[4][4];
  #pragma unroll
  for (int m = 0; m < 4; m++)
    #pragma unroll
    for (int n = 0; n < 4; n++) acc[m][n] = (f32x4){0.f, 0.f, 0.f, 0.f};

  const __hip_bfloat16* Arow = Ag + (long)brow * K;
  const __hip_bfloat16* Brow = Bg + (long)bcol * K;

  for (int k0 = 0; k0 < K; k0 += 64) {
    #pragma unroll
    for (int i = 0; i < 4; i++) {
      int c = (wid << 2) + i;
      int rg = c >> 1, half = c & 1;
      gl_lds16(Arow + (long)(rg * 16 + srow) * K + k0 + half * 32 + skp,
               &As[half][rg * 16][0]);
      gl_lds16(Brow + (long)(rg * 16 + srow) * K + k0 + half * 32 + skp,
               &Bs[half][rg * 16][0]);
    }
    __syncthreads();
    #pragma unroll
    for (int kk = 0; kk < 2; kk++) {
      short8 a[4], b[4];
      #pragma unroll
      for (int m = 0; m < 4; m++)
        a[m] = *(const short8*)&As[kk][wr + m * 16 + fr][fs * 8];
      #pragma unroll
      for (int n = 0; n < 4; n++)
        b[n] = *(const short8*)&Bs[kk][wc + n * 16 + fr][fs * 8];
      #pragma unroll
      for (int m = 0; m < 4; m++)
        #pragma unroll
        for (int n = 0; n < 4; n++)
          acc[m][n] = __builtin_amdgcn_mfma_f32_16x16x32_bf16(a[m], b[n], acc[m][n], 0, 0, 0);
    }
    __syncthreads();
  }

  #pragma unroll
  for (int m = 0; m < 4; m++) {
    #pragma unroll
    for (int n = 0; n < 4; n++) {
      const int col = bcol + wc + n * 16 + fr;
      #pragma unroll
      for (int j = 0; j < 4; j++) {
        const long row = brow + wr + m * 16 + fs * 4 + j;
        float v = acc[m][n][j];
        if (EPI == 1) {
          v += bias[col] + Res[row * N + col];
          ((float*)Cg)[row * N + col] = v;
        } else if (EPI == 2) {
          v += bias[col];
          v = 0.5f * v * (1.f + erff(v * 0.70710678118654752f));
          ((__hip_bfloat16*)Cg)[row * N + col] = __float2bfloat16(v);
        } else {  // EPI 3: qkv dual store
          ((float*)Cg)[row * N + col] = v;
          int sect = col >> 9, h = (col >> 6) & 7, d = col & 63;
          if (sect == 0)      Qb[(long)h * 524288 + row * 64 + d] = __float2bfloat16(v * 0.125f);
          else if (sect == 1) Kb[(long)h * 524288 + row * 64 + d] = __float2bfloat16(v);
        }
      }
    }
  }
}

// ---------------- batched bf16 MFMA GEMM ----------------
// C = alpha * A @ B^T, per batch z: hh = z/NCH, cc = z%NCH
// EPI 0: f32 store (col<Nc), chunk C offset cC
// EPI 1: bf16 store
// EPI 3: bf16 C + TB[c][r] = (r==c? s:0) - v
// EPI 4: TB only, (r==c? s:0) - v
// EPI 5: bf16 C + TB[c][r] = +v
// EPI 6: TB only, +v, col<Nc guard
template<int EPI>
__global__ __launch_bounds__(256) void bgemm(
    const __hip_bfloat16* __restrict__ Ag, const __hip_bfloat16* __restrict__ Bg,
    void* __restrict__ Cg, __hip_bfloat16* __restrict__ Tg,
    int K, int Nc, float alpha, float s,
    long lda, long ldb, long ldc, long ldt,
    long sA, long sB, long sC, long sT,
    int NCH, long cA, long cB, long cC)
{
  __shared__ __align__(16) short As[2][128][32];
  __shared__ __align__(16) short Bs[2][128][32];
  const int tid = threadIdx.x;
  const int lane = tid & 63, wid = tid >> 6;
  const int zz = blockIdx.z;
  const int hh = zz / NCH, cc = zz - hh * NCH;
  const int brow = blockIdx.y << 7, bcol = blockIdx.x << 7;
  const int wr = (wid >> 1) << 6, wc = (wid & 1) << 6;
  const int fr = lane & 15, fs = lane >> 4;
  const int srow = lane >> 2;
  const int skp  = (lane & 3) << 3;
  f32x4 acc[4][4];
  #pragma unroll
  for (int m = 0; m < 4; m++)
    #pragma unroll
    for (int n = 0; n < 4; n++) acc[m][n] = (f32x4){0.f, 0.f, 0.f, 0.f};

  const __hip_bfloat16* Arow = Ag + hh * sA + cc * cA + (long)brow * lda;
  const __hip_bfloat16* Brow = Bg + hh * sB + cc * cB + (long)bcol * ldb;

  for (int k0 = 0; k0 < K; k0 += 64) {
    #pragma unroll
    for (int i = 0; i < 4; i++) {
      int c = (wid << 2) + i;
      int rg = c >> 1, half = c & 1;
      gl_lds16(Arow + (long)(rg * 16 + srow) * lda + k0 + half * 32 + skp,
               &As[half][rg * 16][0]);
      gl_lds16(Brow + (long)(rg * 16 + srow) * ldb + k0 + half * 32 + skp,
               &Bs[half][rg * 16][0]);
    }
    __syncthreads();
    #pragma unroll
    for (int kk = 0; kk < 2; kk++) {
      short8 a[4], b[4];
      #pragma unroll
      for (int m = 0; m < 4; m++)
        a[m] = *(const short8*)&As[kk][wr + m * 16 + fr][fs * 8];
      #pragma unroll
      for (int n = 0; n < 4; n++)
        b[n] = *(const short8*)&Bs[kk][wc + n * 16 + fr][fs * 8];
      #pragma unroll
      for (int m = 0; m < 4; m++)
        #pragma unroll
        for (int n = 0; n < 4; n++)
          acc[m][n] = __builtin_amdgcn_mfma_f32_16x16x32_bf16(a[m], b[n], acc[m][n], 0, 0, 0);
    }
    __syncthreads();
  }

  #pragma unroll
  for (int m = 0; m < 4; m++) {
    #pragma unroll
    for (int n = 0; n < 4; n++) {
      const int col = bcol + wc + n * 16 + fr;
      const int rbase = brow + wr + m * 16 + fs * 4;
      if (EPI == 0) {
        if (col < Nc) {
          float* Cb = (float*)Cg + hh * sC + cc * cC;
          #pragma unroll
          for (int j = 0; j < 4; j++)
            Cb[(long)(rbase + j) * ldc + col] = acc[m][n][j] * alpha;
        }
      }
      if (EPI == 1) {
        __hip_bfloat16* Cb = (__hip_bfloat16*)Cg + hh * sC;
        #pragma unroll
        for (int j = 0; j < 4; j++)
          Cb[(long)(rbase + j) * ldc + col] = __float2bfloat16(acc[m][n][j] * alpha);
      }
      if (EPI == 3 || EPI == 5) {
        __hip_bfloat16* Cb = (__hip_bfloat16*)Cg + hh * sC;
        #pragma unroll
        for (int j = 0; j < 4; j++)
          Cb[(long)(rbase + j) * ldc + col] = __float2bfloat16(acc[m][n][j] * alpha);
      }
      if (EPI == 3 || EPI == 4 || EPI == 5 || EPI == 6) {
        if (EPI != 6 || col < Nc) {
          __hip_bfloat16* Tb = Tg + hh * sT;
          short4v tv;
          #pragma unroll
          for (int j = 0; j < 4; j++) {
            float v = acc[m][n][j] * alpha;
            float o = (EPI == 3 || EPI == 4)
                      ? (((rbase + j) == col) ? (s - v) : (-v)) : v;
            tv[j] = (short)f2b(o);
          }
          *(short4v*)&Tb[(long)col * ldt + rbase] = tv;
        }
      }
    }
  }
}

// ---------------- generic tiled SGEMM (attn2 logits only) ----------------
template<int DUMMY>
__global__ __launch_bounds__(256) void sgemm_k(
    const float* __restrict__ A, const float* __restrict__ Bw,
    float* __restrict__ C,
    int K, int Nc, long lda, long ldb, long ldc,
    long sA, long sB, long sC)
{
  __shared__ float As[16][68];
  __shared__ __align__(16) float Bs[16][68];
  const int tid = threadIdx.x;
  const int zz = blockIdx.z;
  const float* Ab = A + zz * sA;
  const float* Bb = Bw + zz * sB;
  float* Cb = C + zz * sC;
  const int brow = blockIdx.y * 64;
  const int bcol = blockIdx.x * 64;
  const int tm = tid >> 4, tn = tid & 15;
  const int lam = tid >> 2;
  const int lak = (tid & 3) << 2;
  const int lbk = tid >> 4;
  const int lbn = (tid & 15) << 2;
  float acc[4][4];
  #pragma unroll
  for (int i = 0; i < 4; i++)
    #pragma unroll
    for (int j = 0; j < 4; j++) acc[i][j] = 0.f;

  for (int k0 = 0; k0 < K; k0 += 16) {
    float4 av = *(const float4*)&Ab[(long)(brow + lam) * lda + k0 + lak];
    As[lak + 0][lam] = av.x; As[lak + 1][lam] = av.y;
    As[lak + 2][lam] = av.z; As[lak + 3][lam] = av.w;
    float4 bv = *(const float4*)&Bb[(long)(k0 + lbk) * ldb + bcol + lbn];
    *(float4*)&Bs[lbk][lbn] = bv;
    __syncthreads();
    #pragma unroll
    for (int kk = 0; kk < 16; kk++) {
      float a0 = As[kk][(tm << 2) + 0], a1 = As[kk][(tm << 2) + 1];
      float a2 = As[kk][(tm << 2) + 2], a3 = As[kk][(tm << 2) + 3];
      float b0 = Bs[kk][(tn << 2) + 0], b1 = Bs[kk][(tn << 2) + 1];
      float b2 = Bs[kk][(tn << 2) + 2], b3 = Bs[kk][(tn << 2) + 3];
      acc[0][0] += a0 * b0; acc[0][1] += a0 * b1; acc[0][2] += a0 * b2; acc[0][3] += a0 * b3;
      acc[1][0] += a1 * b0; acc[1][1] += a1 * b1; acc[1][2] += a1 * b2; acc[1][3] += a1 * b3;
      acc[2][0] += a2 * b0; acc[2][1] += a2 * b1; acc[2][2] += a2 * b2; acc[2][3] += a2 * b3;
      acc[3][0] += a3 * b0; acc[3][1] += a3 * b1; acc[3][2] += a3 * b2; acc[3][3] += a3 * b3;
    }
    __syncthreads();
  }
  #pragma unroll
  for (int i = 0; i < 4; i++) {
    const long row = brow + (tm << 2) + i;
    #pragma unroll
    for (int j = 0; j < 4; j++) {
      const int col = bcol + (tn << 2) + j;
      Cb[row * ldc + col] = acc[i][j];
    }
  }
}

// ---------------- landmarks: QL f32, KLT f32, QLbf, KLbf ----------------
__global__ __launch_bounds__(256) void landmarks_k(const float* __restrict__ QKV,
    float* __restrict__ QL, float* __restrict__ KLT,
    __hip_bfloat16* __restrict__ QLb, __hip_bfloat16* __restrict__ KLb)
{
  int t = blockIdx.x * 256 + threadIdx.x;   // t = h*16384 + m*64 + d
  int d = t & 63; int m = (t >> 6) & 255; int h = t >> 14;
  const float* base = QKV + (long)(m * 32) * 1536 + (h << 6) + d;
  float sq = 0.f, sk = 0.f;
  for (int i = 0; i < 32; i++) { sq += base[(long)i * 1536]; sk += base[(long)i * 1536 + 512]; }
  float qv = sq * (0.125f / 32.f);
  QL[t] = qv;
  QLb[t] = __float2bfloat16(qv);
  float kv = sk * (1.f / 32.f);
  KLb[t] = __float2bfloat16(kv);
  KLT[(h << 14) + (d << 8) + m] = kv;
}

// ---------------- V transpose -> bf16: VT[h][d][n] ----------------
__global__ __launch_bounds__(256) void vt_k(const float* __restrict__ QKV,
    __hip_bfloat16* __restrict__ VT)
{
  __shared__ float t[64][65];
  const int h = blockIdx.x & 7; const int n0 = (blockIdx.x >> 3) << 6;
  const int c = threadIdx.x & 63; const int r4 = threadIdx.x >> 6;
  #pragma unroll 4
  for (int i = 0; i < 16; i++) {
    int r = r4 * 16 + i;
    t[r][c] = QKV[(long)(n0 + r) * 1536 + 1024 + (h << 6) + c];
  }
  __syncthreads();
  #pragma unroll 4
  for (int i = 0; i < 16; i++) {
    int d = r4 * 16 + i;
    VT[(long)((h << 6) + d) * 8192 + n0 + c] = __float2bfloat16(t[c][d]);
  }
}

// ---------------- row softmax, width 256, f32 in place ----------------
__global__ __launch_bounds__(256) void softmax256_k(float* __restrict__ X)
{
  __shared__ float red[256];
  const long row = blockIdx.x; const int tid = threadIdx.x;
  float v = X[row * 256 + tid];
  red[tid] = v; __syncthreads();
  for (int s = 128; s > 0; s >>= 1) { if (tid < s) red[tid] = fmaxf(red[tid], red[tid + s]); __syncthreads(); }
  float M = red[0]; __syncthreads();
  float e = __expf(v - M);
  red[tid] = e; __syncthreads();
  for (int s = 128; s > 0; s >>= 1) { if (tid < s) red[tid] += red[tid + s]; __syncthreads(); }
  float S = red[0];
  X[row * 256 + tid] = e / S;
}

// ---------------- row softmax, width 8192, bf16 in place ----------------
__global__ __launch_bounds__(256) void softmax8192b_k(__hip_bfloat16* __restrict__ X)
{
  __shared__ float red[256];
  const long row = blockIdx.x; const int tid = threadIdx.x;
  unsigned short* r = (unsigned short*)(X + row * 8192);
  float v[32]; float m = -1e30f;
  #pragma unroll
  for (int i = 0; i < 4; i++) {
    short8 sv = *(const short8*)&r[i * 2048 + tid * 8];
    #pragma unroll
    for (int e = 0; e < 8; e++) { float f = b2f((unsigned short)sv[e]); v[i * 8 + e] = f; m = fmaxf(m, f); }
  }
  red[tid] = m; __syncthreads();
  for (int s = 128; s > 0; s >>= 1) { if (tid < s) red[tid] = fmaxf(red[tid], red[tid + s]); __syncthreads(); }
  float M = red[0]; __syncthreads();
  float sum = 0.f;
  #pragma unroll
  for (int i = 0; i < 32; i++) { v[i] = __expf(v[i] - M); sum += v[i]; }
  red[tid] = sum; __syncthreads();
  for (int s = 128; s > 0; s >>= 1) { if (tid < s) red[tid] += red[tid + s]; __syncthreads(); }
  float inv = 1.0f / red[0];
  #pragma unroll
  for (int i = 0; i < 4; i++) {
    short8 so;
    #pragma unroll
    for (int e = 0; e < 8; e++) so[e] = (short)f2b(v[i * 8 + e] * inv);
    *(short8*)&r[i * 2048 + tid * 8] = so;
  }
}

// ---------------- pinv scalars ----------------
__global__ __launch_bounds__(256) void rowsum_k(const float* __restrict__ X, float* __restrict__ out)
{
  int t = blockIdx.x * 256 + threadIdx.x;
  const float* r = X + (long)t * 256;
  float s = 0.f;
  for (int j = 0; j < 256; j++) s += fabsf(r[j]);
  out[t] = s;
}
__global__ __launch_bounds__(256) void colsum_k(const float* __restrict__ X, float* __restrict__ out)
{
  int t = blockIdx.x * 256 + threadIdx.x; int h = t >> 8; int j = t & 255;
  const float* c = X + ((long)h << 16) + j;
  float s = 0.f;
  for (int i = 0; i < 256; i++) s += fabsf(c[(long)i << 8]);
  out[t] = s;
}
__global__ __launch_bounds__(256) void invscale_k(const float* __restrict__ rows,
    const float* __restrict__ cols, float* __restrict__ inv)
{
  __shared__ float red[256];
  int tid = threadIdx.x;
  float mr = -1e30f, mc = -1e30f;
  for (int i = tid; i < 2048; i += 256) { mr = fmaxf(mr, rows[i]); mc = fmaxf(mc, cols[i]); }
  red[tid] = mr; __syncthreads();
  for (int s = 128; s > 0; s >>= 1) { if (tid < s) red[tid] = fmaxf(red[tid], red[tid + s]); __syncthreads(); }
  mr = red[0]; __syncthreads();
  red[tid] = mc; __syncthreads();
  for (int s = 128; s > 0; s >>= 1) { if (tid < s) red[tid] = fmaxf(red[tid], red[tid + s]); __syncthreads(); }
  mc = red[0];
  if (tid == 0) inv[0] = 1.0f / (mr * mc);
}

// ---------------- pinv init: Xbf, z0 = X^T*inv, z0T = X*inv ----------------
__global__ __launch_bounds__(256) void xz_init_k(const float* __restrict__ ATT2,
    const float* __restrict__ inv, __hip_bfloat16* __restrict__ Xb,
    __hip_bfloat16* __restrict__ z0, __hip_bfloat16* __restrict__ z0T)
{
  __shared__ float t[64][65];
  const int h = blockIdx.z;
  const int j0 = blockIdx.x << 6, i0 = blockIdx.y << 6;
  const int c = threadIdx.x & 63; const int r4 = threadIdx.x >> 6;
  const float iv = inv[0];
  #pragma unroll 4
  for (int i = 0; i < 16; i++) {
    int r = r4 * 16 + i;
    float v = ATT2[((long)h << 16) + (long)(i0 + r) * 256 + j0 + c];
    t[r][c] = v;
    Xb[((long)h << 16) + (long)(i0 + r) * 256 + j0 + c]  = __float2bfloat16(v);
    z0T[((long)h << 16) + (long)(i0 + r) * 256 + j0 + c] = __float2bfloat16(v * iv);
  }
  __syncthreads();
  #pragma unroll 4
  for (int i = 0; i < 16; i++) {
    int r = r4 * 16 + i;
    z0[((long)h << 16) + (long)(j0 + r) * 256 + i0 + c] = __float2bfloat16(t[c][r] * iv);
  }
}

// ---------------- AV chunk reduce -> AVT bf16 ----------------
__global__ __launch_bounds__(256) void avred_k(const float* __restrict__ AVp,
    __hip_bfloat16* __restrict__ AVT)
{
  const int h = blockIdx.x; const int tid = threadIdx.x;
  for (int i = 0; i < 64; i++) {
    int idx = i * 256 + tid;           // = d*256 + m
    int d = idx >> 8, m = idx & 255;
    float s = 0.f;
    #pragma unroll
    for (int cc = 0; cc < 16; cc++)
      s += AVp[(long)cc * 131072 + (long)h * 16384 + m * 64 + d];
    AVT[(long)h * 16384 + idx] = __float2bfloat16(s);
  }
}

// ---------------- fused attn1: logits(K=64) -> softmax -> @CM -> Bh ----------------
__global__ __launch_bounds__(256) void attn1_k(
    const __hip_bfloat16* __restrict__ Qb, const __hip_bfloat16* __restrict__ KLb,
    const __hip_bfloat16* __restrict__ CMT, float* __restrict__ Bh)
{
  __shared__ __align__(16) char U[65536];
  short (*As)[128][32] = (short(*)[128][32])U;           // [2][128][32]
  short (*Bs)[256][32] = (short(*)[256][32])(U + 16384); // [2][256][32]
  short (*Ps)[128][32] = (short(*)[128][32])U;           // [8][128][32] aliases As+Bs
  __shared__ __align__(16) short Cs[8][64][32];
  __shared__ float red[2][2][128];

  const int tid = threadIdx.x;
  const int lane = tid & 63, wid = tid >> 6;
  const int fr = lane & 15, fs = lane >> 4;
  const int srow = lane >> 2, skp = (lane & 3) << 3;
  const int n0 = blockIdx.x << 7, h = blockIdx.y;
  const int half = wid & 1, wrb = (wid >> 1) << 6;

  const __hip_bfloat16* Aq = Qb  + (long)h * 524288 + (long)n0 * 64;
  const __hip_bfloat16* Bk = KLb + (long)h * 16384;
  const __hip_bfloat16* Cm = CMT + (long)h * 16384;

  for (int i = 0; i < 20; i++) {
    int c = wid * 20 + i;
    if (c < 16) {
      int rg = c >> 1, hf = c & 1;
      gl_lds16(Aq + (long)(rg * 16 + srow) * 64 + hf * 32 + skp, &As[hf][rg * 16][0]);
    } else if (c < 48) {
      int c2 = c - 16; int rg = c2 >> 1, hf = c2 & 1;
      gl_lds16(Bk + (long)(rg * 16 + srow) * 64 + hf * 32 + skp, &Bs[hf][rg * 16][0]);
    } else {
      int c3 = c - 48; int rg = c3 >> 3, ks = c3 & 7;
      gl_lds16(Cm + (long)(rg * 16 + srow) * 256 + ks * 32 + skp, &Cs[ks][rg * 16][0]);
    }
  }
  __syncthreads();

  // phase 1: logits = Q @ KL^T  (wave tile 64 rows x 128 cols)
  f32x4 acc[4][8];
  #pragma unroll
  for (int m = 0; m < 4; m++)
    #pragma unroll
    for (int n = 0; n < 8; n++) acc[m][n] = (f32x4){0.f, 0.f, 0.f, 0.f};
  #pragma unroll
  for (int kk = 0; kk < 2; kk++) {
    short8 a[4];
    #pragma unroll
    for (int m = 0; m < 4; m++)
      a[m] = *(const short8*)&As[kk][wrb + m * 16 + fr][fs * 8];
    #pragma unroll
    for (int n = 0; n < 8; n++) {
      short8 b = *(const short8*)&Bs[kk][half * 128 + n * 16 + fr][fs * 8];
      #pragma unroll
      for (int m = 0; m < 4; m++)
        acc[m][n] = __builtin_amdgcn_mfma_f32_16x16x32_bf16(a[m], b, acc[m][n], 0, 0, 0);
    }
  }

  // softmax over 256 cols per row
  #pragma unroll
  for (int m = 0; m < 4; m++)
    #pragma unroll
    for (int j = 0; j < 4; j++) {
      float mx = -1e30f;
      #pragma unroll
      for (int n = 0; n < 8; n++) mx = fmaxf(mx, acc[m][n][j]);
      mx = fmaxf(mx, __shfl_xor(mx, 1));
      mx = fmaxf(mx, __shfl_xor(mx, 2));
      mx = fmaxf(mx, __shfl_xor(mx, 4));
      mx = fmaxf(mx, __shfl_xor(mx, 8));
      int rloc = wrb + m * 16 + fs * 4 + j;
      if (fr == 0) red[0][half][rloc] = mx;
    }
  __syncthreads();
  #pragma unroll
  for (int m = 0; m < 4; m++)
    #pragma unroll
    for (int j = 0; j < 4; j++) {
      int rloc = wrb + m * 16 + fs * 4 + j;
      float Mx = fmaxf(red[0][0][rloc], red[0][1][rloc]);
      float s = 0.f;
      #pragma unroll
      for (int n = 0; n < 8; n++) {
        float e = __expf(acc[m][n][j] - Mx);
        acc[m][n][j] = e; s += e;
      }
      s += __shfl_xor(s, 1);
      s += __shfl_xor(s, 2);
      s += __shfl_xor(s, 4);
      s += __shfl_xor(s, 8);
      if (fr == 0) red[1][half][rloc] = s;
    }
  __syncthreads();
  // write P (bf16) into k-sliced LDS (overwrites As/Bs — phase1 reads done)
  #pragma unroll
  for (int m = 0; m < 4; m++)
    #pragma unroll
    for (int j = 0; j < 4; j++) {
      int rloc = wrb + m * 16 + fs * 4 + j;
      float inv = 1.0f / (red[1][0][rloc] + red[1][1][rloc]);
      #pragma unroll
      for (int n = 0; n < 8; n++) {
        int col = half * 128 + n * 16 + fr;
        Ps[col >> 5][rloc][col & 31] = (short)f2b(acc[m][n][j] * inv);
      }
    }
  __syncthreads();

  // phase 2: P @ CM  (wave tile 64 rows x 32 cols, K=256)
  f32x4 acc2[4][2];
  #pragma unroll
  for (int m = 0; m < 4; m++)
    #pragma unroll
    for (int n = 0; n < 2; n++) acc2[m][n] = (f32x4){0.f, 0.f, 0.f, 0.f};
  const int wc2 = half * 32;
  #pragma unroll
  for (int kk = 0; kk < 8; kk++) {
    short8 a2[4];
    #pragma unroll
    for (int m = 0; m < 4; m++)
      a2[m] = *(const short8*)&Ps[kk][wrb + m * 16 + fr][fs * 8];
    #pragma unroll
    for (int n = 0; n < 2; n++) {
      short8 b2 = *(const short8*)&Cs[kk][wc2 + n * 16 + fr][fs * 8];
      #pragma unroll
      for (int m = 0; m < 4; m++)
        acc2[m][n] = __builtin_amdgcn_mfma_f32_16x16x32_bf16(a2[m], b2, acc2[m][n], 0, 0, 0);
    }
  }
  #pragma unroll
  for (int m = 0; m < 4; m++)
    #pragma unroll
    for (int n = 0; n < 2; n++) {
      int col = wc2 + n * 16 + fr;
      #pragma unroll
      for (int j = 0; j < 4; j++) {
        long row = n0 + wrb + m * 16 + fs * 4 + j;
        Bh[row * 512 + h * 64 + col] = acc2[m][n][j];
      }
    }
}

// ---------------- depthwise conv residual, += into Bh ----------------
__global__ __launch_bounds__(256) void convres_k(const float* __restrict__ QKV,
    const float* __restrict__ W, float* __restrict__ Bh)
{
  const int bid = blockIdx.x;
  const int n = bid >> 1;
  const int j = ((bid & 1) << 8) + threadIdx.x;
  const int h = j >> 6;
  float acc = 0.f;
  #pragma unroll
  for (int kk = 0; kk < 33; kk++) {
    int nn = n + kk - 16;
    if (nn >= 0 && nn < 8192)
      acc += W[h * 33 + kk] * QKV[(long)nn * 1536 + 1024 + j];
  }
  Bh[(long)n * 512 + j] += acc;
}

// ---------------- host ----------------
extern "C" void kernel_launch(void* const* d_in, const int* in_sizes, int n_in,
                              void* d_out, int out_size, void* d_ws, size_t ws_size,
                              hipStream_t stream)
{
  const float* x     = (const float*)d_in[0];
  const float* cls   = (const float*)d_in[1];
  const float* ln1g  = (const float*)d_in[2];
  const float* ln1b  = (const float*)d_in[3];
  const float* wqkv  = (const float*)d_in[4];
  const float* wout  = (const float*)d_in[5];
  const float* bout  = (const float*)d_in[6];
  const float* convw = (const float*)d_in[7];
  const float* ln2g  = (const float*)d_in[8];
  const float* ln2b  = (const float*)d_in[9];
  const float* w1    = (const float*)d_in[10];
  const float* b1    = (const float*)d_in[11];
  const float* w2    = (const float*)d_in[12];
  const float* b2    = (const float*)d_in[13];
  float* out = (float*)d_out;
  float* ws  = (float*)d_ws;
  typedef __hip_bfloat16 bf;

  float* A    = ws + 0;              // [8192][512]
  float* Bh   = ws + 4194304;        // [8192][512]
  float* QKV  = ws + 8388608;        // [8192][1536]
  float* QL   = ws + 20971520;       // [8][256][64]
  float* KLT  = ws + 21102592;       // [8][64][256]
  float* ATT2 = ws + 21233664;       // [8][256][256]
  float* rsum = ws + 21757952;
  float* csum = ws + 21760000;
  float* inv  = ws + 21762048;       // 8 floats
  float* AVp  = ws + 21762056;       // [16][8][256][64]
  bf* Qbf  = (bf*)(ws + 23859208);   // [8][8192][64], prescaled 0.125
  bf* Kbf  = (bf*)(ws + 25956360);   // [8][8192][64]
  bf* VT   = (bf*)(ws + 28053512);   // [8][64][8192] + 64-row pad
  bf* QLbf = (bf*)(ws + 30412808);   // [8][256][64]
  bf* KLbf = (bf*)(ws + 30478344);   // [8][256][64]
  bf* Xbf  = (bf*)(ws + 30543880);   // [8][256][256]
  bf* zA   = (bf*)(ws + 30806024);
  bf* zAT  = (bf*)(ws + 31068168);
  bf* zB   = (bf*)(ws + 31330312);
  bf* zBT  = (bf*)(ws + 31592456);
  bf* Gbf  = (bf*)(ws + 31854600);
  bf* TB0  = (bf*)(ws + 32116744);
  bf* TB1  = (bf*)(ws + 32378888);
  bf* AVT  = (bf*)(ws + 32641032);   // [8][64][256] + pad
  bf* CMT  = (bf*)(ws + 32714760);   // [8][64][256]
  bf* Lbf  = (bf*)(ws + 32780296);   // [8][256][8192]
  // aliases
  bf* wqkvT = Lbf;                   // [1536][512], dead before logits3
  bf* ln1bf = Lbf + 786432;          // [8192][512], dead before logits3
  bf* Bhbf  = Qbf;                   // Qbf dead after attn1
  bf* w1T   = Kbf;                   // Kbf dead after logits3
  bf* w2T   = Kbf + 1048576;
  bf* woutT = Kbf + 2097152;
  bf* ln2bf = VT;                    // VT dead after PV
  bf* FF1bf = Lbf;                   // Lbf dead after PV

  concat_k<<<16384, 256, 0, stream>>>(x, cls, A);
  ln_bf16_k<<<8192, 256, 0, stream>>>(A, ln1g, ln1b, ln1bf);
  tconv_k<<<dim3(24, 8), 256, 0, stream>>>(wqkv, wqkvT, 512, 1536);
  // QKV (f32) + Qbf/Kbf head-major (MFMA, dual store)
  gemm_bf<3><<<dim3(12, 64), 256, 0, stream>>>(ln1bf, wqkvT, QKV, nullptr, nullptr,
      512, 1536, Qbf, Kbf);
  landmarks_k<<<512, 256, 0, stream>>>(QKV, QL, KLT, QLbf, KLbf);
  // attn2 logits (fp32) + softmax + pinv scalars
  sgemm_k<0><<<dim3(4, 4, 8), 256, 0, stream>>>(QL, KLT, ATT2,
      64, 256, 64, 256, 256, 16384, 16384, 65536);
  softmax256_k<<<2048, 256, 0, stream>>>(ATT2);
  rowsum_k<<<8, 256, 0, stream>>>(ATT2, rsum);
  colsum_k<<<8, 256, 0, stream>>>(ATT2, csum);
  invscale_k<<<1, 256, 0, stream>>>(rsum, csum, inv);
  xz_init_k<<<dim3(4, 4, 8), 256, 0, stream>>>(ATT2, inv, Xbf, zA, zAT);
  // pinv: 6 iterations, 4 MFMA GEMMs each, B-operands produced transposed+diag'ed
  bf* zc = zA; bf* zcT = zAT; bf* zn = zB; bf* znT = zBT;
  for (int it = 0; it < 6; ++it) {
    bgemm<3><<<dim3(2, 2, 8), 256, 0, stream>>>(Xbf, zcT, Gbf, TB0,
        256, 256, 1.f, 7.f, 256, 256, 256, 256, 65536, 65536, 65536, 65536, 1, 0, 0, 0);
    bgemm<4><<<dim3(2, 2, 8), 256, 0, stream>>>(Gbf, TB0, nullptr, TB1,
        256, 256, 1.f, 15.f, 256, 256, 256, 256, 65536, 65536, 0, 65536, 1, 0, 0, 0);
    bgemm<4><<<dim3(2, 2, 8), 256, 0, stream>>>(Gbf, TB1, nullptr, TB0,
        256, 256, 1.f, 13.f, 256, 256, 256, 256, 65536, 65536, 0, 65536, 1, 0, 0, 0);
    bgemm<5><<<dim3(2, 2, 8), 256, 0, stream>>>(zc, TB0, zn, znT,
        256, 256, 0.25f, 0.f, 256, 256, 256, 256, 65536, 65536, 65536, 65536, 1, 0, 0, 0);
    bf* t;
    t = zc; zc = zn; zn = t;
    t = zcT; zcT = znT; znT = t;
  }
  // ---- attn3 = softmax(QL @ K^T) @ V ----
  vt_k<<<1024, 256, 0, stream>>>(QKV, VT);
  bgemm<1><<<dim3(64, 2, 8), 256, 0, stream>>>(QLbf, Kbf, Lbf, nullptr,
      64, 8192, 1.f, 0.f, 64, 64, 8192, 0, 16384, 524288, 2097152, 0, 1, 0, 0, 0);
  // weight transposes for tail (Kbf dead now)
  tconv_k<<<dim3(32, 8), 256, 0, stream>>>(w1, w1T, 512, 2048);
  tconv_k<<<dim3(8, 32), 256, 0, stream>>>(w2, w2T, 2048, 512);
  tconv_k<<<dim3(8, 8), 256, 0, stream>>>(wout, woutT, 512, 512);
  softmax8192b_k<<<2048, 256, 0, stream>>>(Lbf);
  // P @ V, 16 K-chunks into AVp slabs
  bgemm<0><<<dim3(1, 2, 128), 256, 0, stream>>>(Lbf, VT, AVp, nullptr,
      512, 64, 1.f, 0.f, 8192, 8192, 64, 0, 2097152, 524288, 16384, 0, 16, 512, 512, 131072);
  avred_k<<<8, 256, 0, stream>>>(AVp, AVT);
  // CM^T = (Z @ AV)^T
  bgemm<6><<<dim3(1, 2, 8), 256, 0, stream>>>(zc, AVT, nullptr, CMT,
      256, 64, 1.f, 0.f, 256, 256, 0, 256, 65536, 16384, 0, 16384, 1, 0, 0, 0);
  // ---- fused attn1 ----
  attn1_k<<<dim3(64, 8), 256, 0, stream>>>(Qbf, KLbf, CMT, Bh);
  convres_k<<<16384, 256, 0, stream>>>(QKV, convw, Bh);
  cvt_bf16_k<<<16384, 256, 0, stream>>>(Bh, Bhbf);
  // A = A + Bh @ wout + bout
  gemm_bf<1><<<dim3(4, 64), 256, 0, stream>>>(Bhbf, woutT, A, A, bout, 512, 512, nullptr, nullptr);
  ln_bf16_k<<<8192, 256, 0, stream>>>(A, ln2g, ln2b, ln2bf);
  // FF1 = gelu(ln2 @ w1 + b1)  (bf16 out)
  gemm_bf<2><<<dim3(16, 64), 256, 0, stream>>>(ln2bf, w1T, FF1bf, nullptr, b1, 512, 2048, nullptr, nullptr);
  // out = A + FF1 @ w2 + b2
  gemm_bf<1><<<dim3(4, 64), 256, 0, stream>>>(FF1bf, w2T, out, A, b2, 2048, 512, nullptr, nullptr);
}

// Round 5
// 646.361 us; speedup vs baseline: 5.4642x; 1.2331x over previous
//
#include <hip/hip_runtime.h>
#include <hip/hip_bf16.h>

typedef __attribute__((ext_vector_type(8))) short short8;
typedef __attribute__((ext_vector_type(4))) short short4v;
typedef __attribute__((ext_vector_type(4))) float f32x4;
typedef __hip_bfloat16 bf;

__device__ __forceinline__ void gl_lds16(const void* g, void* l) {
  __builtin_amdgcn_global_load_lds(
      (const __attribute__((address_space(1))) unsigned int*)g,
      (__attribute__((address_space(3))) unsigned int*)l, 16, 0, 0);
}
__device__ __forceinline__ unsigned short f2b(float f) {
  bf h = __float2bfloat16(f);
  return *reinterpret_cast<unsigned short*>(&h);
}
__device__ __forceinline__ float b2f(unsigned short u) {
  unsigned v = ((unsigned)u) << 16;
  return __uint_as_float(v);
}

// ---------------- concat: A = [cls; x] ----------------
__global__ __launch_bounds__(256) void concat_k(const float* __restrict__ x,
    const float* __restrict__ cls, float* __restrict__ A)
{
  long t = (long)blockIdx.x * 256 + threadIdx.x;
  A[t] = (t < 512) ? cls[t] : x[t - 512];
}

// ---------------- fused LN -> bf16 ----------------
__global__ __launch_bounds__(256) void ln_bf16_k(const float* __restrict__ X,
    const float* __restrict__ g, const float* __restrict__ b,
    bf* __restrict__ O)
{
  __shared__ float red[256];
  const long row = blockIdx.x; const int tid = threadIdx.x;
  const float* r = X + row * 512;
  float v0 = r[tid], v1 = r[tid + 256];
  red[tid] = v0 + v1; __syncthreads();
  for (int s = 128; s > 0; s >>= 1) { if (tid < s) red[tid] += red[tid + s]; __syncthreads(); }
  float mean = red[0] * (1.f / 512.f); __syncthreads();
  float d0 = v0 - mean, d1 = v1 - mean;
  red[tid] = d0 * d0 + d1 * d1; __syncthreads();
  for (int s = 128; s > 0; s >>= 1) { if (tid < s) red[tid] += red[tid + s]; __syncthreads(); }
  float rs = rsqrtf(red[0] * (1.f / 512.f) + 1e-5f);
  O[row * 512 + tid]       = __float2bfloat16(d0 * rs * g[tid] + b[tid]);
  O[row * 512 + tid + 256] = __float2bfloat16(d1 * rs * g[tid + 256] + b[tid + 256]);
}

// ---------------- weight transpose f32[K][N] -> bf16[N][K] ----------------
__global__ __launch_bounds__(256) void tconv_k(const float* __restrict__ W,
    bf* __restrict__ WT, int K, int N)
{
  __shared__ float t[64][65];
  const int n0 = blockIdx.x << 6, k0 = blockIdx.y << 6;
  const int c = threadIdx.x & 63; const int r4 = threadIdx.x >> 6;
  #pragma unroll 4
  for (int i = 0; i < 16; i++) {
    int r = r4 * 16 + i;
    t[r][c] = W[(long)(k0 + r) * N + n0 + c];
  }
  __syncthreads();
  #pragma unroll 4
  for (int i = 0; i < 16; i++) {
    int r = r4 * 16 + i;
    WT[(long)(n0 + r) * K + k0 + c] = __float2bfloat16(t[c][r]);
  }
}

// ---------------- main bf16 MFMA GEMM (dense path): C = A @ B^T ----------------
// EPI: 1 = f32 + bias + residual; 2 = bf16 + bias + gelu; 3 = head-major Q/K/V bf16 stores
template<int EPI>
__global__ __launch_bounds__(256) void gemm_bf(
    const bf* __restrict__ Ag, const bf* __restrict__ Bg,
    void* __restrict__ Cg, const float* __restrict__ Res,
    const float* __restrict__ bias, int K, int N,
    bf* __restrict__ Qb, bf* __restrict__ Kb, bf* __restrict__ Vb)
{
  __shared__ __align__(16) short As[2][128][32];
  __shared__ __align__(16) short Bs[2][128][32];
  const int tid = threadIdx.x;
  const int lane = tid & 63, wid = tid >> 6;
  const int brow = blockIdx.y << 7, bcol = blockIdx.x << 7;
  const int wr = (wid >> 1) << 6, wc = (wid & 1) << 6;
  const int fr = lane & 15, fs = lane >> 4;
  const int srow = lane >> 2;
  const int skp  = (lane & 3) << 3;
  f32x4 acc[4][4];
  #pragma unroll
  for (int m = 0; m < 4; m++)
    #pragma unroll
    for (int n = 0; n < 4; n++) acc[m][n] = (f32x4){0.f, 0.f, 0.f, 0.f};

  const bf* Arow = Ag + (long)brow * K;
  const bf* Brow = Bg + (long)bcol * K;

  for (int k0 = 0; k0 < K; k0 += 64) {
    #pragma unroll
    for (int i = 0; i < 4; i++) {
      int c = (wid << 2) + i;
      int rg = c >> 1, half = c & 1;
      gl_lds16(Arow + (long)(rg * 16 + srow) * K + k0 + half * 32 + skp,
               &As[half][rg * 16][0]);
      gl_lds16(Brow + (long)(rg * 16 + srow) * K + k0 + half * 32 + skp,
               &Bs[half][rg * 16][0]);
    }
    __syncthreads();
    #pragma unroll
    for (int kk = 0; kk < 2; kk++) {
      short8 a[4], b[4];
      #pragma unroll
      for (int m = 0; m < 4; m++)
        a[m] = *(const short8*)&As[kk][wr + m * 16 + fr][fs * 8];
      #pragma unroll
      for (int n = 0; n < 4; n++)
        b[n] = *(const short8*)&Bs[kk][wc + n * 16 + fr][fs * 8];
      #pragma unroll
      for (int m = 0; m < 4; m++)
        #pragma unroll
        for (int n = 0; n < 4; n++)
          acc[m][n] = __builtin_amdgcn_mfma_f32_16x16x32_bf16(a[m], b[n], acc[m][n], 0, 0, 0);
    }
    __syncthreads();
  }

  #pragma unroll
  for (int m = 0; m < 4; m++) {
    #pragma unroll
    for (int n = 0; n < 4; n++) {
      const int col = bcol + wc + n * 16 + fr;
      #pragma unroll
      for (int j = 0; j < 4; j++) {
        const long row = brow + wr + m * 16 + fs * 4 + j;
        float v = acc[m][n][j];
        if (EPI == 1) {
          v += bias[col] + Res[row * N + col];
          ((float*)Cg)[row * N + col] = v;
        } else if (EPI == 2) {
          v += bias[col];
          v = 0.5f * v * (1.f + erff(v * 0.70710678118654752f));
          ((bf*)Cg)[row * N + col] = __float2bfloat16(v);
        } else {  // EPI 3: head-major bf16 q/k/v
          int sect = col >> 9, h = (col >> 6) & 7, d = col & 63;
          long o = ((long)h * 8192 + row) * 64 + d;
          if (sect == 0)      Qb[o] = __float2bfloat16(v * 0.125f);
          else if (sect == 1) Kb[o] = __float2bfloat16(v);
          else                Vb[o] = __float2bfloat16(v);
        }
      }
    }
  }
}

// ---------------- batched bf16 MFMA GEMM (pinv / CM) ----------------
// EPI 3: bf16 C + TB[c][r] = (r==c? s:0) - v
// EPI 4: TB only, (r==c? s:0) - v
// EPI 5: bf16 C + TB[c][r] = +v
// EPI 6: TB only, +v, col<Nc guard
template<int EPI>
__global__ __launch_bounds__(256) void bgemm(
    const bf* __restrict__ Ag, const bf* __restrict__ Bg,
    void* __restrict__ Cg, bf* __restrict__ Tg,
    int K, int Nc, float alpha, float s,
    long lda, long ldb, long ldc, long ldt,
    long sA, long sB, long sC, long sT)
{
  __shared__ __align__(16) short As[2][128][32];
  __shared__ __align__(16) short Bs[2][128][32];
  const int tid = threadIdx.x;
  const int lane = tid & 63, wid = tid >> 6;
  const int hh = blockIdx.z;
  const int brow = blockIdx.y << 7, bcol = blockIdx.x << 7;
  const int wr = (wid >> 1) << 6, wc = (wid & 1) << 6;
  const int fr = lane & 15, fs = lane >> 4;
  const int srow = lane >> 2;
  const int skp  = (lane & 3) << 3;
  f32x4 acc[4][4];
  #pragma unroll
  for (int m = 0; m < 4; m++)
    #pragma unroll
    for (int n = 0; n < 4; n++) acc[m][n] = (f32x4){0.f, 0.f, 0.f, 0.f};

  const bf* Arow = Ag + hh * sA + (long)brow * lda;
  const bf* Brow = Bg + hh * sB + (long)bcol * ldb;

  for (int k0 = 0; k0 < K; k0 += 64) {
    #pragma unroll
    for (int i = 0; i < 4; i++) {
      int c = (wid << 2) + i;
      int rg = c >> 1, half = c & 1;
      gl_lds16(Arow + (long)(rg * 16 + srow) * lda + k0 + half * 32 + skp,
               &As[half][rg * 16][0]);
      gl_lds16(Brow + (long)(rg * 16 + srow) * ldb + k0 + half * 32 + skp,
               &Bs[half][rg * 16][0]);
    }
    __syncthreads();
    #pragma unroll
    for (int kk = 0; kk < 2; kk++) {
      short8 a[4], b[4];
      #pragma unroll
      for (int m = 0; m < 4; m++)
        a[m] = *(const short8*)&As[kk][wr + m * 16 + fr][fs * 8];
      #pragma unroll
      for (int n = 0; n < 4; n++)
        b[n] = *(const short8*)&Bs[kk][wc + n * 16 + fr][fs * 8];
      #pragma unroll
      for (int m = 0; m < 4; m++)
        #pragma unroll
        for (int n = 0; n < 4; n++)
          acc[m][n] = __builtin_amdgcn_mfma_f32_16x16x32_bf16(a[m], b[n], acc[m][n], 0, 0, 0);
    }
    __syncthreads();
  }

  #pragma unroll
  for (int m = 0; m < 4; m++) {
    #pragma unroll
    for (int n = 0; n < 4; n++) {
      const int col = bcol + wc + n * 16 + fr;
      const int rbase = brow + wr + m * 16 + fs * 4;
      if (EPI == 3 || EPI == 5) {
        bf* Cb = (bf*)Cg + hh * sC;
        #pragma unroll
        for (int j = 0; j < 4; j++)
          Cb[(long)(rbase + j) * ldc + col] = __float2bfloat16(acc[m][n][j] * alpha);
      }
      if (EPI != 6 || col < Nc) {
        bf* Tb = Tg + hh * sT;
        short4v tv;
        #pragma unroll
        for (int j = 0; j < 4; j++) {
          float v = acc[m][n][j] * alpha;
          float o = (EPI == 3 || EPI == 4)
                    ? (((rbase + j) == col) ? (s - v) : (-v)) : v;
          tv[j] = (short)f2b(o);
        }
        *(short4v*)&Tb[(long)col * ldt + rbase] = tv;
      }
    }
  }
}

// ---------------- fp32 tiled GEMM (attn2 logits only) ----------------
__global__ __launch_bounds__(256) void sgemm_k(
    const float* __restrict__ A, const float* __restrict__ Bw,
    float* __restrict__ C,
    int K, long lda, long ldb, long ldc,
    long sA, long sB, long sC)
{
  __shared__ float As[16][68];
  __shared__ __align__(16) float Bs[16][68];
  const int tid = threadIdx.x;
  const int zz = blockIdx.z;
  const float* Ab = A + zz * sA;
  const float* Bb = Bw + zz * sB;
  float* Cb = C + zz * sC;
  const int brow = blockIdx.y * 64;
  const int bcol = blockIdx.x * 64;
  const int tm = tid >> 4, tn = tid & 15;
  const int lam = tid >> 2;
  const int lak = (tid & 3) << 2;
  const int lbk = tid >> 4;
  const int lbn = (tid & 15) << 2;
  float acc[4][4];
  #pragma unroll
  for (int i = 0; i < 4; i++)
    #pragma unroll
    for (int j = 0; j < 4; j++) acc[i][j] = 0.f;

  for (int k0 = 0; k0 < K; k0 += 16) {
    float4 av = *(const float4*)&Ab[(long)(brow + lam) * lda + k0 + lak];
    As[lak + 0][lam] = av.x; As[lak + 1][lam] = av.y;
    As[lak + 2][lam] = av.z; As[lak + 3][lam] = av.w;
    float4 bv = *(const float4*)&Bb[(long)(k0 + lbk) * ldb + bcol + lbn];
    *(float4*)&Bs[lbk][lbn] = bv;
    __syncthreads();
    #pragma unroll
    for (int kk = 0; kk < 16; kk++) {
      float a0 = As[kk][(tm << 2) + 0], a1 = As[kk][(tm << 2) + 1];
      float a2 = As[kk][(tm << 2) + 2], a3 = As[kk][(tm << 2) + 3];
      float b0 = Bs[kk][(tn << 2) + 0], b1 = Bs[kk][(tn << 2) + 1];
      float b2 = Bs[kk][(tn << 2) + 2], b3 = Bs[kk][(tn << 2) + 3];
      acc[0][0] += a0 * b0; acc[0][1] += a0 * b1; acc[0][2] += a0 * b2; acc[0][3] += a0 * b3;
      acc[1][0] += a1 * b0; acc[1][1] += a1 * b1; acc[1][2] += a1 * b2; acc[1][3] += a1 * b3;
      acc[2][0] += a2 * b0; acc[2][1] += a2 * b1; acc[2][2] += a2 * b2; acc[2][3] += a2 * b3;
      acc[3][0] += a3 * b0; acc[3][1] += a3 * b1; acc[3][2] += a3 * b2; acc[3][3] += a3 * b3;
    }
    __syncthreads();
  }
  #pragma unroll
  for (int i = 0; i < 4; i++) {
    const long row = brow + (tm << 2) + i;
    #pragma unroll
    for (int j = 0; j < 4; j++) {
      const int col = bcol + (tn << 2) + j;
      Cb[row * ldc + col] = acc[i][j];
    }
  }
}

// ---------------- landmarks from bf16 Q/K: QL f32, KLT f32, QLbf, KLbf ----------------
__global__ __launch_bounds__(256) void landmarks_k(const bf* __restrict__ Qb,
    const bf* __restrict__ Kb,
    float* __restrict__ QL, float* __restrict__ KLT,
    bf* __restrict__ QLb, bf* __restrict__ KLb)
{
  int t = blockIdx.x * 256 + threadIdx.x;   // t = h*16384 + m*64 + d
  int d = t & 63; int m = (t >> 6) & 255; int h = t >> 14;
  const unsigned short* qp = (const unsigned short*)Qb + ((long)h * 8192 + m * 32) * 64 + d;
  const unsigned short* kp = (const unsigned short*)Kb + ((long)h * 8192 + m * 32) * 64 + d;
  float sq = 0.f, sk = 0.f;
  for (int i = 0; i < 32; i++) { sq += b2f(qp[i * 64]); sk += b2f(kp[i * 64]); }
  float qv = sq * (1.f / 32.f);       // Qb already prescaled 0.125
  QL[t] = qv;
  QLb[t] = __float2bfloat16(qv);
  float kv = sk * (1.f / 32.f);
  KLb[t] = __float2bfloat16(kv);
  KLT[(h << 14) + (d << 8) + m] = kv;
}

// ---------------- V transpose (bf16 -> bf16): VT[h][d][n] ----------------
__global__ __launch_bounds__(256) void vt_k(const bf* __restrict__ Vb,
    bf* __restrict__ VT)
{
  __shared__ unsigned short t[64][68];
  const int h = blockIdx.x & 7; const int n0 = (blockIdx.x >> 3) << 6;
  const int c = threadIdx.x & 63; const int r4 = threadIdx.x >> 6;
  const unsigned short* vp = (const unsigned short*)Vb;
  unsigned short* vo = (unsigned short*)VT;
  #pragma unroll 4
  for (int i = 0; i < 16; i++) {
    int r = r4 * 16 + i;
    t[r][c] = vp[((long)h * 8192 + n0 + r) * 64 + c];
  }
  __syncthreads();
  #pragma unroll 4
  for (int i = 0; i < 16; i++) {
    int d = r4 * 16 + i;
    vo[((long)(h << 6) + d) * 8192 + n0 + c] = t[c][d];
  }
}

// ---------------- row softmax, width 256, f32 in place ----------------
__global__ __launch_bounds__(256) void softmax256_k(float* __restrict__ X)
{
  __shared__ float red[256];
  const long row = blockIdx.x; const int tid = threadIdx.x;
  float v = X[row * 256 + tid];
  red[tid] = v; __syncthreads();
  for (int s = 128; s > 0; s >>= 1) { if (tid < s) red[tid] = fmaxf(red[tid], red[tid + s]); __syncthreads(); }
  float M = red[0]; __syncthreads();
  float e = __expf(v - M);
  red[tid] = e; __syncthreads();
  for (int s = 128; s > 0; s >>= 1) { if (tid < s) red[tid] += red[tid + s]; __syncthreads(); }
  float S = red[0];
  X[row * 256 + tid] = e / S;
}

// ---------------- pinv scalars ----------------
__global__ __launch_bounds__(256) void rowsum_k(const float* __restrict__ X, float* __restrict__ out)
{
  int t = blockIdx.x * 256 + threadIdx.x;
  const float* r = X + (long)t * 256;
  float s = 0.f;
  for (int j = 0; j < 256; j++) s += fabsf(r[j]);
  out[t] = s;
}
__global__ __launch_bounds__(256) void colsum_k(const float* __restrict__ X, float* __restrict__ out)
{
  int t = blockIdx.x * 256 + threadIdx.x; int h = t >> 8; int j = t & 255;
  const float* c = X + ((long)h << 16) + j;
  float s = 0.f;
  for (int i = 0; i < 256; i++) s += fabsf(c[(long)i << 8]);
  out[t] = s;
}
__global__ __launch_bounds__(256) void invscale_k(const float* __restrict__ rows,
    const float* __restrict__ cols, float* __restrict__ inv)
{
  __shared__ float red[256];
  int tid = threadIdx.x;
  float mr = -1e30f, mc = -1e30f;
  for (int i = tid; i < 2048; i += 256) { mr = fmaxf(mr, rows[i]); mc = fmaxf(mc, cols[i]); }
  red[tid] = mr; __syncthreads();
  for (int s = 128; s > 0; s >>= 1) { if (tid < s) red[tid] = fmaxf(red[tid], red[tid + s]); __syncthreads(); }
  mr = red[0]; __syncthreads();
  red[tid] = mc; __syncthreads();
  for (int s = 128; s > 0; s >>= 1) { if (tid < s) red[tid] = fmaxf(red[tid], red[tid + s]); __syncthreads(); }
  mc = red[0];
  if (tid == 0) inv[0] = 1.0f / (mr * mc);
}

// ---------------- pinv init: Xbf, z0 = X^T*inv, z0T = X*inv ----------------
__global__ __launch_bounds__(256) void xz_init_k(const float* __restrict__ ATT2,
    const float* __restrict__ inv, bf* __restrict__ Xb,
    bf* __restrict__ z0, bf* __restrict__ z0T)
{
  __shared__ float t[64][65];
  const int h = blockIdx.z;
  const int j0 = blockIdx.x << 6, i0 = blockIdx.y << 6;
  const int c = threadIdx.x & 63; const int r4 = threadIdx.x >> 6;
  const float iv = inv[0];
  #pragma unroll 4
  for (int i = 0; i < 16; i++) {
    int r = r4 * 16 + i;
    float v = ATT2[((long)h << 16) + (long)(i0 + r) * 256 + j0 + c];
    t[r][c] = v;
    Xb[((long)h << 16) + (long)(i0 + r) * 256 + j0 + c]  = __float2bfloat16(v);
    z0T[((long)h << 16) + (long)(i0 + r) * 256 + j0 + c] = __float2bfloat16(v * iv);
  }
  __syncthreads();
  #pragma unroll 4
  for (int i = 0; i < 16; i++) {
    int r = r4 * 16 + i;
    z0[((long)h << 16) + (long)(j0 + r) * 256 + i0 + c] = __float2bfloat16(t[c][r] * iv);
  }
}

// ---------------- flash attn3: per (chunk, mtile, head) partials ----------------
__global__ __launch_bounds__(256) void attn3f_k(
    const bf* __restrict__ Qlb, const bf* __restrict__ Kb, const bf* __restrict__ Vt,
    float* __restrict__ Op, float* __restrict__ Mp, float* __restrict__ Lp)
{
  __shared__ __align__(16) short Qs[2][128][32];
  __shared__ __align__(16) short Ks[2][128][32];
  __shared__ __align__(16) short Vs[4][64][32];
  __shared__ __align__(16) short Ps[4][4][32][32];
  const int tid = threadIdx.x, lane = tid & 63, wid = tid >> 6;
  const int fr = lane & 15, fs = lane >> 4;
  const int srow = lane >> 2, skp = (lane & 3) << 3;
  const int chunk = blockIdx.x, mt = blockIdx.y, h = blockIdx.z;
  const int wrb = wid << 5;
  const bf* Qg = Qlb + ((long)h * 256 + mt * 128) * 64;
  #pragma unroll
  for (int i = 0; i < 4; i++) {
    int c = (wid << 2) + i, rg = c >> 1, hf = c & 1;
    gl_lds16(Qg + (long)(rg * 16 + srow) * 64 + hf * 32 + skp, &Qs[hf][rg * 16][0]);
  }
  f32x4 acc2[2][4];
  float mrun[2][4], lrun[2][4];
  #pragma unroll
  for (int m = 0; m < 2; m++)
    #pragma unroll
    for (int n = 0; n < 4; n++) { acc2[m][n] = (f32x4){0.f,0.f,0.f,0.f}; mrun[m][n] = -1e30f; lrun[m][n] = 0.f; }

  for (int t = 0; t < 8; t++) {
    const int key0 = (chunk << 10) + (t << 7);
    const bf* Kg = Kb + ((long)h * 8192 + key0) * 64;
    #pragma unroll
    for (int i = 0; i < 4; i++) {
      int c = (wid << 2) + i, rg = c >> 1, hf = c & 1;
      gl_lds16(Kg + (long)(rg * 16 + srow) * 64 + hf * 32 + skp, &Ks[hf][rg * 16][0]);
    }
    #pragma unroll
    for (int i = 0; i < 4; i++) {
      int c = (wid << 2) + i, dg = c >> 2, ks = c & 3;
      gl_lds16(Vt + ((long)h * 64 + dg * 16 + srow) * 8192 + key0 + ks * 32 + skp,
               &Vs[ks][dg * 16][0]);
    }
    __syncthreads();
    // logits 32 rows x 128 cols per wave
    f32x4 lac[2][8];
    #pragma unroll
    for (int m = 0; m < 2; m++)
      #pragma unroll
      for (int n = 0; n < 8; n++) lac[m][n] = (f32x4){0.f,0.f,0.f,0.f};
    #pragma unroll
    for (int kk = 0; kk < 2; kk++) {
      short8 a[2];
      #pragma unroll
      for (int m = 0; m < 2; m++)
        a[m] = *(const short8*)&Qs[kk][wrb + m * 16 + fr][fs * 8];
      #pragma unroll
      for (int n = 0; n < 8; n++) {
        short8 b = *(const short8*)&Ks[kk][n * 16 + fr][fs * 8];
        #pragma unroll
        for (int m = 0; m < 2; m++)
          lac[m][n] = __builtin_amdgcn_mfma_f32_16x16x32_bf16(a[m], b, lac[m][n], 0, 0, 0);
      }
    }
    // online softmax per row (row = wrb + m*16 + fs*4 + j)
    #pragma unroll
    for (int m = 0; m < 2; m++) {
      #pragma unroll
      for (int j = 0; j < 4; j++) {
        float tmax = lac[m][0][j];
        #pragma unroll
        for (int n = 1; n < 8; n++) tmax = fmaxf(tmax, lac[m][n][j]);
        tmax = fmaxf(tmax, __shfl_xor(tmax, 1));
        tmax = fmaxf(tmax, __shfl_xor(tmax, 2));
        tmax = fmaxf(tmax, __shfl_xor(tmax, 4));
        tmax = fmaxf(tmax, __shfl_xor(tmax, 8));
        float mnew = fmaxf(mrun[m][j], tmax);
        float sc = __expf(mrun[m][j] - mnew);
        #pragma unroll
        for (int n2 = 0; n2 < 4; n2++) acc2[m][n2][j] *= sc;
        float lsum = 0.f;
        #pragma unroll
        for (int n = 0; n < 8; n++) {
          float p = __expf(lac[m][n][j] - mnew);
          lac[m][n][j] = p; lsum += p;
        }
        lsum += __shfl_xor(lsum, 1);
        lsum += __shfl_xor(lsum, 2);
        lsum += __shfl_xor(lsum, 4);
        lsum += __shfl_xor(lsum, 8);
        lrun[m][j] = lrun[m][j] * sc + lsum;
        mrun[m][j] = mnew;
      }
    }
    // P -> LDS bf16 (per-wave region)
    #pragma unroll
    for (int m = 0; m < 2; m++)
      #pragma unroll
      for (int n = 0; n < 8; n++) {
        int col = n * 16 + fr;
        #pragma unroll
        for (int j = 0; j < 4; j++)
          Ps[wid][col >> 5][m * 16 + fs * 4 + j][col & 31] = (short)f2b(lac[m][n][j]);
      }
    // PV: O(32x64) += P(32x128) @ V^T-slice
    #pragma unroll
    for (int ks = 0; ks < 4; ks++) {
      short8 a2[2];
      #pragma unroll
      for (int m = 0; m < 2; m++)
        a2[m] = *(const short8*)&Ps[wid][ks][m * 16 + fr][fs * 8];
      #pragma unroll
      for (int n = 0; n < 4; n++) {
        short8 b2 = *(const short8*)&Vs[ks][n * 16 + fr][fs * 8];
        #pragma unroll
        for (int m = 0; m < 2; m++)
          acc2[m][n] = __builtin_amdgcn_mfma_f32_16x16x32_bf16(a2[m], b2, acc2[m][n], 0, 0, 0);
      }
    }
    __syncthreads();
  }
  const long base = (long)(chunk * 8 + h) * 2 + mt;
  #pragma unroll
  for (int m = 0; m < 2; m++)
    #pragma unroll
    for (int n = 0; n < 4; n++) {
      int col = n * 16 + fr;
      #pragma unroll
      for (int j = 0; j < 4; j++)
        Op[base * 8192 + (long)(wrb + m * 16 + fs * 4 + j) * 64 + col] = acc2[m][n][j];
    }
  if (fr == 0) {
    #pragma unroll
    for (int m = 0; m < 2; m++)
      #pragma unroll
      for (int j = 0; j < 4; j++) {
        int r = wrb + m * 16 + fs * 4 + j;
        Mp[base * 128 + r] = mrun[m][j];
        Lp[base * 128 + r] = lrun[m][j];
      }
  }
}

// ---------------- flash attn3 combine -> AVT bf16 [h][d][m] ----------------
__global__ __launch_bounds__(256) void attn3c_k(
    const float* __restrict__ Op, const float* __restrict__ Mp,
    const float* __restrict__ Lp, bf* __restrict__ AVT)
{
  __shared__ float wm[8][128];
  __shared__ float wl[8][128];
  const int bid = blockIdx.x;
  const int h = bid >> 1, mt = bid & 1, tid = threadIdx.x;
  for (int i = 0; i < 4; i++) {
    int idx = i * 256 + tid;
    int c = idx >> 7, r = idx & 127;
    wm[c][r] = Mp[((long)(c * 8 + h) * 2 + mt) * 128 + r];
    wl[c][r] = Lp[((long)(c * 8 + h) * 2 + mt) * 128 + r];
  }
  __syncthreads();
  if (tid < 128) {
    float M = wm[0][tid];
    #pragma unroll
    for (int c = 1; c < 8; c++) M = fmaxf(M, wm[c][tid]);
    float D = 0.f;
    #pragma unroll
    for (int c = 0; c < 8; c++) D += __expf(wm[c][tid] - M) * wl[c][tid];
    float rv = 1.0f / D;
    #pragma unroll
    for (int c = 0; c < 8; c++) wm[c][tid] = __expf(wm[c][tid] - M) * rv;
  }
  __syncthreads();
  for (int i = 0; i < 32; i++) {
    int idx = i * 256 + tid;
    int r = idx >> 6, d = idx & 63;
    float s = 0.f;
    #pragma unroll
    for (int c = 0; c < 8; c++)
      s += wm[c][r] * Op[((long)(c * 8 + h) * 2 + mt) * 8192 + (long)r * 64 + d];
    AVT[(long)h * 16384 + d * 256 + mt * 128 + r] = __float2bfloat16(s);
  }
}

// ---------------- fused attn1: logits -> softmax -> @CM -> Bhbf ----------------
__global__ __launch_bounds__(256) void attn1_k(
    const bf* __restrict__ Qb, const bf* __restrict__ KLb,
    const bf* __restrict__ CMT, bf* __restrict__ Bhb)
{
  __shared__ __align__(16) char U[65536];
  short (*As)[128][32] = (short(*)[128][32])U;           // [2][128][32]
  short (*Bs)[256][32] = (short(*)[256][32])(U + 16384); // [2][256][32]
  short (*Ps)[128][32] = (short(*)[128][32])U;           // [8][128][32] aliases As+Bs
  __shared__ __align__(16) short Cs[8][64][32];
  __shared__ float red[2][2][128];

  const int tid = threadIdx.x;
  const int lane = tid & 63, wid = tid >> 6;
  const int fr = lane & 15, fs = lane >> 4;
  const int srow = lane >> 2, skp = (lane & 3) << 3;
  const int n0 = blockIdx.x << 7, h = blockIdx.y;
  const int half = wid & 1, wrb = (wid >> 1) << 6;

  const bf* Aq = Qb  + (long)h * 524288 + (long)n0 * 64;
  const bf* Bk = KLb + (long)h * 16384;
  const bf* Cm = CMT + (long)h * 16384;

  for (int i = 0; i < 20; i++) {
    int c = wid * 20 + i;
    if (c < 16) {
      int rg = c >> 1, hf = c & 1;
      gl_lds16(Aq + (long)(rg * 16 + srow) * 64 + hf * 32 + skp, &As[hf][rg * 16][0]);
    } else if (c < 48) {
      int c2 = c - 16; int rg = c2 >> 1, hf = c2 & 1;
      gl_lds16(Bk + (long)(rg * 16 + srow) * 64 + hf * 32 + skp, &Bs[hf][rg * 16][0]);
    } else {
      int c3 = c - 48; int rg = c3 >> 3, ks = c3 & 7;
      gl_lds16(Cm + (long)(rg * 16 + srow) * 256 + ks * 32 + skp, &Cs[ks][rg * 16][0]);
    }
  }
  __syncthreads();

  // phase 1: logits = Q @ KL^T  (wave tile 64 rows x 128 cols)
  f32x4 acc[4][8];
  #pragma unroll
  for (int m = 0; m < 4; m++)
    #pragma unroll
    for (int n = 0; n < 8; n++) acc[m][n] = (f32x4){0.f, 0.f, 0.f, 0.f};
  #pragma unroll
  for (int kk = 0; kk < 2; kk++) {
    short8 a[4];
    #pragma unroll
    for (int m = 0; m < 4; m++)
      a[m] = *(const short8*)&As[kk][wrb + m * 16 + fr][fs * 8];
    #pragma unroll
    for (int n = 0; n < 8; n++) {
      short8 b = *(const short8*)&Bs[kk][half * 128 + n * 16 + fr][fs * 8];
      #pragma unroll
      for (int m = 0; m < 4; m++)
        acc[m][n] = __builtin_amdgcn_mfma_f32_16x16x32_bf16(a[m], b, acc[m][n], 0, 0, 0);
    }
  }

  // softmax over 256 cols per row
  #pragma unroll
  for (int m = 0; m < 4; m++)
    #pragma unroll
    for (int j = 0; j < 4; j++) {
      float mx = -1e30f;
      #pragma unroll
      for (int n = 0; n < 8; n++) mx = fmaxf(mx, acc[m][n][j]);
      mx = fmaxf(mx, __shfl_xor(mx, 1));
      mx = fmaxf(mx, __shfl_xor(mx, 2));
      mx = fmaxf(mx, __shfl_xor(mx, 4));
      mx = fmaxf(mx, __shfl_xor(mx, 8));
      int rloc = wrb + m * 16 + fs * 4 + j;
      if (fr == 0) red[0][half][rloc] = mx;
    }
  __syncthreads();
  #pragma unroll
  for (int m = 0; m < 4; m++)
    #pragma unroll
    for (int j = 0; j < 4; j++) {
      int rloc = wrb + m * 16 + fs * 4 + j;
      float Mx = fmaxf(red[0][0][rloc], red[0][1][rloc]);
      float s = 0.f;
      #pragma unroll
      for (int n = 0; n < 8; n++) {
        float e = __expf(acc[m][n][j] - Mx);
        acc[m][n][j] = e; s += e;
      }
      s += __shfl_xor(s, 1);
      s += __shfl_xor(s, 2);
      s += __shfl_xor(s, 4);
      s += __shfl_xor(s, 8);
      if (fr == 0) red[1][half][rloc] = s;
    }
  __syncthreads();
  #pragma unroll
  for (int m = 0; m < 4; m++)
    #pragma unroll
    for (int j = 0; j < 4; j++) {
      int rloc = wrb + m * 16 + fs * 4 + j;
      float inv = 1.0f / (red[1][0][rloc] + red[1][1][rloc]);
      #pragma unroll
      for (int n = 0; n < 8; n++) {
        int col = half * 128 + n * 16 + fr;
        Ps[col >> 5][rloc][col & 31] = (short)f2b(acc[m][n][j] * inv);
      }
    }
  __syncthreads();

  // phase 2: P @ CM  (wave tile 64 rows x 32 cols, K=256)
  f32x4 acc2[4][2];
  #pragma unroll
  for (int m = 0; m < 4; m++)
    #pragma unroll
    for (int n = 0; n < 2; n++) acc2[m][n] = (f32x4){0.f, 0.f, 0.f, 0.f};
  const int wc2 = half * 32;
  #pragma unroll
  for (int kk = 0; kk < 8; kk++) {
    short8 a2[4];
    #pragma unroll
    for (int m = 0; m < 4; m++)
      a2[m] = *(const short8*)&Ps[kk][wrb + m * 16 + fr][fs * 8];
    #pragma unroll
    for (int n = 0; n < 2; n++) {
      short8 b2 = *(const short8*)&Cs[kk][wc2 + n * 16 + fr][fs * 8];
      #pragma unroll
      for (int m = 0; m < 4; m++)
        acc2[m][n] = __builtin_amdgcn_mfma_f32_16x16x32_bf16(a2[m], b2, acc2[m][n], 0, 0, 0);
    }
  }
  #pragma unroll
  for (int m = 0; m < 4; m++)
    #pragma unroll
    for (int n = 0; n < 2; n++) {
      int col = wc2 + n * 16 + fr;
      #pragma unroll
      for (int j = 0; j < 4; j++) {
        long row = n0 + wrb + m * 16 + fs * 4 + j;
        Bhb[row * 512 + h * 64 + col] = __float2bfloat16(acc2[m][n][j]);
      }
    }
}

// ---------------- depthwise conv residual, bf16 RMW into Bhbf ----------------
__global__ __launch_bounds__(256) void convres_k(const bf* __restrict__ Vb,
    const float* __restrict__ W, bf* __restrict__ Bhb)
{
  const int gid = blockIdx.x * 256 + threadIdx.x;   // 0..1048575
  const int n = gid >> 7, q = gid & 127;
  const int j0 = q << 2, h = j0 >> 6, d0 = j0 & 63;
  float a0 = 0.f, a1 = 0.f, a2 = 0.f, a3 = 0.f;
  const unsigned short* vb = (const unsigned short*)Vb + (long)h * 524288 + d0;
  #pragma unroll
  for (int kk = 0; kk < 33; kk++) {
    int nn = n + kk - 16;
    if (nn >= 0 && nn < 8192) {
      float w = W[h * 33 + kk];
      uint2 raw = *(const uint2*)(vb + (long)nn * 64);
      a0 += w * b2f(raw.x & 0xffff); a1 += w * b2f(raw.x >> 16);
      a2 += w * b2f(raw.y & 0xffff); a3 += w * b2f(raw.y >> 16);
    }
  }
  unsigned short* o = (unsigned short*)Bhb + (long)n * 512 + j0;
  uint2 cur = *(uint2*)o;
  uint2 outv;
  outv.x = (unsigned)f2b(b2f(cur.x & 0xffff) + a0) | ((unsigned)f2b(b2f(cur.x >> 16) + a1) << 16);
  outv.y = (unsigned)f2b(b2f(cur.y & 0xffff) + a2) | ((unsigned)f2b(b2f(cur.y >> 16) + a3) << 16);
  *(uint2*)o = outv;
}

// ---------------- host ----------------
extern "C" void kernel_launch(void* const* d_in, const int* in_sizes, int n_in,
                              void* d_out, int out_size, void* d_ws, size_t ws_size,
                              hipStream_t stream)
{
  const float* x     = (const float*)d_in[0];
  const float* cls   = (const float*)d_in[1];
  const float* ln1g  = (const float*)d_in[2];
  const float* ln1b  = (const float*)d_in[3];
  const float* wqkv  = (const float*)d_in[4];
  const float* wout  = (const float*)d_in[5];
  const float* bout  = (const float*)d_in[6];
  const float* convw = (const float*)d_in[7];
  const float* ln2g  = (const float*)d_in[8];
  const float* ln2b  = (const float*)d_in[9];
  const float* w1    = (const float*)d_in[10];
  const float* b1    = (const float*)d_in[11];
  const float* w2    = (const float*)d_in[12];
  const float* b2    = (const float*)d_in[13];
  float* out = (float*)d_out;
  float* ws  = (float*)d_ws;

  float* A     = ws + 0;              // [8192][512] f32
  float* QL    = ws + 4194304;        // [8][256][64]
  float* KLT   = ws + 4325376;        // [8][64][256]
  float* ATT2  = ws + 4456448;        // [8][256][256]
  float* rsum  = ws + 4980736;
  float* csum  = ws + 4982784;
  float* inv   = ws + 4984832;        // 8
  float* Opart = ws + 4984840;        // [8][8][2][128][64] f32
  float* Mpart = ws + 6033416;        // [8][8][2][128]
  float* Lpart = ws + 6049800;
  bf* Qbf  = (bf*)(ws + 6066184);     // [8][8192][64] prescaled 0.125
  bf* Kbf  = (bf*)(ws + 8163336);     // [8][8192][64]
  bf* Vbf  = (bf*)(ws + 10260488);    // [8][8192][64]
  bf* VT   = (bf*)(ws + 12357640);    // [8][64][8192]
  bf* QLbf = (bf*)(ws + 14454792);    // [8][256][64]
  bf* KLbf = (bf*)(ws + 14520328);
  bf* Xbf  = (bf*)(ws + 14585864);    // [8][256][256]
  bf* zA   = (bf*)(ws + 14848008);
  bf* zAT  = (bf*)(ws + 15110152);
  bf* zB   = (bf*)(ws + 15372296);
  bf* zBT  = (bf*)(ws + 15634440);
  bf* Gbf  = (bf*)(ws + 15896584);
  bf* TB0  = (bf*)(ws + 16158728);
  bf* TB1  = (bf*)(ws + 16420872);
  bf* AVT  = (bf*)(ws + 16683016);    // [8][64][256]
  bf* CMT  = (bf*)(ws + 16748552);    // [8][64][256]
  float* R = ws + 16814088;           // reusable region (8.39M floats)
  bf* wqkvT = (bf*)R;                 // [1536][512]
  bf* ln1bf = (bf*)(R + 393216);      // [8192][512]
  bf* Bhbf  = (bf*)(R + 393216);      // [8192][512] (after ln1bf dead)
  bf* FF1bf = (bf*)R;                 // [8192][2048] (after Bhbf dead)
  bf* w1T   = Kbf;                    // [2048][512] alias (Kbf dead after attn3f)
  bf* w2T   = Kbf + 1048576;          // [512][2048]
  bf* woutT = Kbf + 2097152;          // [512][512]
  bf* ln2bf = VT;                     // [8192][512] alias (VT dead after attn3f)

  concat_k<<<16384, 256, 0, stream>>>(x, cls, A);
  ln_bf16_k<<<8192, 256, 0, stream>>>(A, ln1g, ln1b, ln1bf);
  tconv_k<<<dim3(24, 8), 256, 0, stream>>>(wqkv, wqkvT, 512, 1536);
  // qkv: head-major bf16 Q(.125)/K/V
  gemm_bf<3><<<dim3(12, 64), 256, 0, stream>>>(ln1bf, wqkvT, nullptr, nullptr, nullptr,
      512, 1536, Qbf, Kbf, Vbf);
  landmarks_k<<<512, 256, 0, stream>>>(Qbf, Kbf, QL, KLT, QLbf, KLbf);
  vt_k<<<1024, 256, 0, stream>>>(Vbf, VT);
  // attn2 logits (fp32) + softmax + pinv scalars
  sgemm_k<<<dim3(4, 4, 8), 256, 0, stream>>>(QL, KLT, ATT2,
      64, 64, 256, 256, 16384, 16384, 65536);
  softmax256_k<<<2048, 256, 0, stream>>>(ATT2);
  rowsum_k<<<8, 256, 0, stream>>>(ATT2, rsum);
  colsum_k<<<8, 256, 0, stream>>>(ATT2, csum);
  invscale_k<<<1, 256, 0, stream>>>(rsum, csum, inv);
  xz_init_k<<<dim3(4, 4, 8), 256, 0, stream>>>(ATT2, inv, Xbf, zA, zAT);
  // pinv: 6 iters x 4 MFMA GEMMs, B-operands produced transposed+diag'ed
  bf* zc = zA; bf* zcT = zAT; bf* zn = zB; bf* znT = zBT;
  for (int it = 0; it < 6; ++it) {
    bgemm<3><<<dim3(2, 2, 8), 256, 0, stream>>>(Xbf, zcT, Gbf, TB0,
        256, 256, 1.f, 7.f, 256, 256, 256, 256, 65536, 65536, 65536, 65536);
    bgemm<4><<<dim3(2, 2, 8), 256, 0, stream>>>(Gbf, TB0, nullptr, TB1,
        256, 256, 1.f, 15.f, 256, 256, 256, 256, 65536, 65536, 0, 65536);
    bgemm<4><<<dim3(2, 2, 8), 256, 0, stream>>>(Gbf, TB1, nullptr, TB0,
        256, 256, 1.f, 13.f, 256, 256, 256, 256, 65536, 65536, 0, 65536);
    bgemm<5><<<dim3(2, 2, 8), 256, 0, stream>>>(zc, TB0, zn, znT,
        256, 256, 0.25f, 0.f, 256, 256, 256, 256, 65536, 65536, 65536, 65536);
    bf* t;
    t = zc; zc = zn; zn = t;
    t = zcT; zcT = znT; znT = t;
  }
  // flash attn3 + combine -> AVT
  attn3f_k<<<dim3(8, 2, 8), 256, 0, stream>>>(QLbf, Kbf, VT, Opart, Mpart, Lpart);
  attn3c_k<<<16, 256, 0, stream>>>(Opart, Mpart, Lpart, AVT);
  // CM^T = (Z @ AV)^T
  bgemm<6><<<dim3(1, 2, 8), 256, 0, stream>>>(zc, AVT, nullptr, CMT,
      256, 64, 1.f, 0.f, 256, 256, 0, 256, 65536, 16384, 0, 16384);
  // weight transposes (Kbf/VT now dead)
  tconv_k<<<dim3(32, 8), 256, 0, stream>>>(w1, w1T, 512, 2048);
  tconv_k<<<dim3(8, 32), 256, 0, stream>>>(w2, w2T, 2048, 512);
  tconv_k<<<dim3(8, 8), 256, 0, stream>>>(wout, woutT, 512, 512);
  // fused attn1 -> Bhbf, conv residual RMW
  attn1_k<<<dim3(64, 8), 256, 0, stream>>>(Qbf, KLbf, CMT, Bhbf);
  convres_k<<<4096, 256, 0, stream>>>(Vbf, convw, Bhbf);
  // A = A + Bh @ wout + bout
  gemm_bf<1><<<dim3(4, 64), 256, 0, stream>>>(Bhbf, woutT, A, A, bout, 512, 512,
      nullptr, nullptr, nullptr);
  ln_bf16_k<<<8192, 256, 0, stream>>>(A, ln2g, ln2b, ln2bf);
  // FF1 = gelu(ln2 @ w1 + b1)  (bf16 out)
  gemm_bf<2><<<dim3(16, 64), 256, 0, stream>>>(ln2bf, w1T, FF1bf, nullptr, b1, 512, 2048,
      nullptr, nullptr, nullptr);
  // out = A + FF1 @ w2 + b2
  gemm_bf<1><<<dim3(4, 64), 256, 0, stream>>>(FF1bf, w2T, out, A, b2, 2048, 512,
      nullptr, nullptr, nullptr);
}

// Round 6
// 636.791 us; speedup vs baseline: 5.5463x; 1.0150x over previous
//
#include <hip/hip_runtime.h>
#include <hip/hip_bf16.h>

typedef __attribute__((ext_vector_type(8))) short short8;
typedef __attribute__((ext_vector_type(4))) short short4v;
typedef __attribute__((ext_vector_type(4))) float f32x4;
typedef __hip_bfloat16 bf;

__device__ __forceinline__ void gl_lds16(const void* g, void* l) {
  __builtin_amdgcn_global_load_lds(
      (const __attribute__((address_space(1))) unsigned int*)g,
      (__attribute__((address_space(3))) unsigned int*)l, 16, 0, 0);
}
__device__ __forceinline__ unsigned short f2b(float f) {
  bf h = __float2bfloat16(f);
  return *reinterpret_cast<unsigned short*>(&h);
}
__device__ __forceinline__ float b2f(unsigned short u) {
  unsigned v = ((unsigned)u) << 16;
  return __uint_as_float(v);
}

// ---------------- fused concat + LN1 -> bf16 (also writes A f32) ----------------
__global__ __launch_bounds__(256) void concat_ln_k(const float* __restrict__ x,
    const float* __restrict__ cls, const float* __restrict__ g,
    const float* __restrict__ b, float* __restrict__ A, bf* __restrict__ O)
{
  __shared__ float red[256];
  const long row = blockIdx.x; const int tid = threadIdx.x;
  const float* src = (row == 0) ? cls : (x + (row - 1) * 512);
  float v0 = src[tid], v1 = src[tid + 256];
  A[row * 512 + tid] = v0; A[row * 512 + tid + 256] = v1;
  red[tid] = v0 + v1; __syncthreads();
  for (int s = 128; s > 0; s >>= 1) { if (tid < s) red[tid] += red[tid + s]; __syncthreads(); }
  float mean = red[0] * (1.f / 512.f); __syncthreads();
  float d0 = v0 - mean, d1 = v1 - mean;
  red[tid] = d0 * d0 + d1 * d1; __syncthreads();
  for (int s = 128; s > 0; s >>= 1) { if (tid < s) red[tid] += red[tid + s]; __syncthreads(); }
  float rs = rsqrtf(red[0] * (1.f / 512.f) + 1e-5f);
  O[row * 512 + tid]       = __float2bfloat16(d0 * rs * g[tid] + b[tid]);
  O[row * 512 + tid + 256] = __float2bfloat16(d1 * rs * g[tid + 256] + b[tid + 256]);
}

// ---------------- fused LN -> bf16 ----------------
__global__ __launch_bounds__(256) void ln_bf16_k(const float* __restrict__ X,
    const float* __restrict__ g, const float* __restrict__ b,
    bf* __restrict__ O)
{
  __shared__ float red[256];
  const long row = blockIdx.x; const int tid = threadIdx.x;
  const float* r = X + row * 512;
  float v0 = r[tid], v1 = r[tid + 256];
  red[tid] = v0 + v1; __syncthreads();
  for (int s = 128; s > 0; s >>= 1) { if (tid < s) red[tid] += red[tid + s]; __syncthreads(); }
  float mean = red[0] * (1.f / 512.f); __syncthreads();
  float d0 = v0 - mean, d1 = v1 - mean;
  red[tid] = d0 * d0 + d1 * d1; __syncthreads();
  for (int s = 128; s > 0; s >>= 1) { if (tid < s) red[tid] += red[tid + s]; __syncthreads(); }
  float rs = rsqrtf(red[0] * (1.f / 512.f) + 1e-5f);
  O[row * 512 + tid]       = __float2bfloat16(d0 * rs * g[tid] + b[tid]);
  O[row * 512 + tid + 256] = __float2bfloat16(d1 * rs * g[tid + 256] + b[tid + 256]);
}

// ---------------- weight transpose f32[K][N] -> bf16[N][K] ----------------
__global__ __launch_bounds__(256) void tconv_k(const float* __restrict__ W,
    bf* __restrict__ WT, int K, int N)
{
  __shared__ float t[64][65];
  const int n0 = blockIdx.x << 6, k0 = blockIdx.y << 6;
  const int c = threadIdx.x & 63; const int r4 = threadIdx.x >> 6;
  #pragma unroll 4
  for (int i = 0; i < 16; i++) {
    int r = r4 * 16 + i;
    t[r][c] = W[(long)(k0 + r) * N + n0 + c];
  }
  __syncthreads();
  #pragma unroll 4
  for (int i = 0; i < 16; i++) {
    int r = r4 * 16 + i;
    WT[(long)(n0 + r) * K + k0 + c] = __float2bfloat16(t[c][r]);
  }
}

// ---------------- panel-staged bf16 MFMA GEMM: C = A @ B^T, K = KP*256 ----------------
// 128 KiB dynamic LDS: one full 128x256 A-panel + B-panel, ONE barrier per panel.
// EPI: 1 = f32 + bias + residual; 2 = bf16 + bias + gelu; 3 = head-major Q/K/V bf16
template<int EPI, int KP>
__global__ __launch_bounds__(256) void mgemm(
    const bf* __restrict__ Ag, const bf* __restrict__ Bg,
    void* __restrict__ Cg, const float* __restrict__ Res,
    const float* __restrict__ bias, int N,
    bf* __restrict__ Qb, bf* __restrict__ Kb, bf* __restrict__ Vb)
{
  extern __shared__ short LDS[];
  short (*As)[128][32] = (short(*)[128][32])LDS;            // [8][128][32]
  short (*Bs)[128][32] = (short(*)[128][32])(LDS + 32768);  // [8][128][32]
  const int K = KP << 8;
  const int tid = threadIdx.x, lane = tid & 63, wid = tid >> 6;
  const int brow = blockIdx.y << 7, bcol = blockIdx.x << 7;
  const int wr = (wid >> 1) << 6, wc = (wid & 1) << 6;
  const int fr = lane & 15, fs = lane >> 4;
  const int srow = lane >> 2, skp = (lane & 3) << 3;
  f32x4 acc[4][4];
  #pragma unroll
  for (int m = 0; m < 4; m++)
    #pragma unroll
    for (int n = 0; n < 4; n++) acc[m][n] = (f32x4){0.f, 0.f, 0.f, 0.f};

  const bf* Arow = Ag + (long)brow * K;
  const bf* Brow = Bg + (long)bcol * K;

  for (int p = 0; p < KP; ++p) {
    if (p) __syncthreads();               // previous panel fully consumed
    #pragma unroll
    for (int i = 0; i < 16; i++) {
      int c = (wid << 4) + i;             // 0..63: rg=c>>3, ks=c&7
      int rg = c >> 3, ks = c & 7;
      gl_lds16(Arow + (long)(rg * 16 + srow) * K + (p << 8) + ks * 32 + skp,
               &As[ks][rg * 16][0]);
      gl_lds16(Brow + (long)(rg * 16 + srow) * K + (p << 8) + ks * 32 + skp,
               &Bs[ks][rg * 16][0]);
    }
    __syncthreads();                      // drains vmcnt
    #pragma unroll
    for (int ks = 0; ks < 8; ks++) {
      short8 a[4], b[4];
      #pragma unroll
      for (int m = 0; m < 4; m++)
        a[m] = *(const short8*)&As[ks][wr + m * 16 + fr][fs * 8];
      #pragma unroll
      for (int n = 0; n < 4; n++)
        b[n] = *(const short8*)&Bs[ks][wc + n * 16 + fr][fs * 8];
      #pragma unroll
      for (int m = 0; m < 4; m++)
        #pragma unroll
        for (int n = 0; n < 4; n++)
          acc[m][n] = __builtin_amdgcn_mfma_f32_16x16x32_bf16(a[m], b[n], acc[m][n], 0, 0, 0);
    }
  }

  #pragma unroll
  for (int m = 0; m < 4; m++) {
    #pragma unroll
    for (int n = 0; n < 4; n++) {
      const int col = bcol + wc + n * 16 + fr;
      #pragma unroll
      for (int j = 0; j < 4; j++) {
        const long row = brow + wr + m * 16 + fs * 4 + j;
        float v = acc[m][n][j];
        if (EPI == 1) {
          v += bias[col] + Res[row * N + col];
          ((float*)Cg)[row * N + col] = v;
        } else if (EPI == 2) {
          v += bias[col];
          v = 0.5f * v * (1.f + erff(v * 0.70710678118654752f));
          ((bf*)Cg)[row * N + col] = __float2bfloat16(v);
        } else {  // EPI 3: head-major bf16 q/k/v
          int sect = col >> 9, h = (col >> 6) & 7, d = col & 63;
          long o = ((long)h * 8192 + row) * 64 + d;
          if (sect == 0)      Qb[o] = __float2bfloat16(v * 0.125f);
          else if (sect == 1) Kb[o] = __float2bfloat16(v);
          else                Vb[o] = __float2bfloat16(v);
        }
      }
    }
  }
}

// ---------------- batched bf16 MFMA GEMM, K=256 fixed, single panel ----------------
// EPI 3: bf16 C + TB[c][r] = (r==c? s:0) - v
// EPI 4: TB only, (r==c? s:0) - v
// EPI 5: bf16 C + TB[c][r] = +v
// EPI 6: TB only, +v, col<Nc guard
template<int EPI>
__global__ __launch_bounds__(256) void bgemm(
    const bf* __restrict__ Ag, const bf* __restrict__ Bg,
    void* __restrict__ Cg, bf* __restrict__ Tg,
    int Nc, float alpha, float s,
    long lda, long ldb, long ldc, long ldt,
    long sA, long sB, long sC, long sT)
{
  extern __shared__ short LDS[];
  short (*As)[128][32] = (short(*)[128][32])LDS;
  short (*Bs)[128][32] = (short(*)[128][32])(LDS + 32768);
  const int tid = threadIdx.x, lane = tid & 63, wid = tid >> 6;
  const int hh = blockIdx.z;
  const int brow = blockIdx.y << 7, bcol = blockIdx.x << 7;
  const int wr = (wid >> 1) << 6, wc = (wid & 1) << 6;
  const int fr = lane & 15, fs = lane >> 4;
  const int srow = lane >> 2, skp = (lane & 3) << 3;
  f32x4 acc[4][4];
  #pragma unroll
  for (int m = 0; m < 4; m++)
    #pragma unroll
    for (int n = 0; n < 4; n++) acc[m][n] = (f32x4){0.f, 0.f, 0.f, 0.f};

  const bf* Arow = Ag + hh * sA + (long)brow * lda;
  const bf* Brow = Bg + hh * sB + (long)bcol * ldb;

  #pragma unroll
  for (int i = 0; i < 16; i++) {
    int c = (wid << 4) + i;
    int rg = c >> 3, ks = c & 7;
    gl_lds16(Arow + (long)(rg * 16 + srow) * lda + ks * 32 + skp, &As[ks][rg * 16][0]);
    gl_lds16(Brow + (long)(rg * 16 + srow) * ldb + ks * 32 + skp, &Bs[ks][rg * 16][0]);
  }
  __syncthreads();
  #pragma unroll
  for (int ks = 0; ks < 8; ks++) {
    short8 a[4], b[4];
    #pragma unroll
    for (int m = 0; m < 4; m++)
      a[m] = *(const short8*)&As[ks][wr + m * 16 + fr][fs * 8];
    #pragma unroll
    for (int n = 0; n < 4; n++)
      b[n] = *(const short8*)&Bs[ks][wc + n * 16 + fr][fs * 8];
    #pragma unroll
    for (int m = 0; m < 4; m++)
      #pragma unroll
      for (int n = 0; n < 4; n++)
        acc[m][n] = __builtin_amdgcn_mfma_f32_16x16x32_bf16(a[m], b[n], acc[m][n], 0, 0, 0);
  }

  #pragma unroll
  for (int m = 0; m < 4; m++) {
    #pragma unroll
    for (int n = 0; n < 4; n++) {
      const int col = bcol + wc + n * 16 + fr;
      const int rbase = brow + wr + m * 16 + fs * 4;
      if (EPI == 3 || EPI == 5) {
        bf* Cb = (bf*)Cg + hh * sC;
        #pragma unroll
        for (int j = 0; j < 4; j++)
          Cb[(long)(rbase + j) * ldc + col] = __float2bfloat16(acc[m][n][j] * alpha);
      }
      if (EPI != 6 || col < Nc) {
        bf* Tb = Tg + hh * sT;
        short4v tv;
        #pragma unroll
        for (int j = 0; j < 4; j++) {
          float v = acc[m][n][j] * alpha;
          float o = (EPI == 3 || EPI == 4)
                    ? (((rbase + j) == col) ? (s - v) : (-v)) : v;
          tv[j] = (short)f2b(o);
        }
        *(short4v*)&Tb[(long)col * ldt + rbase] = tv;
      }
    }
  }
}

// ---------------- fp32 tiled GEMM (attn2 logits only) ----------------
__global__ __launch_bounds__(256) void sgemm_k(
    const float* __restrict__ A, const float* __restrict__ Bw,
    float* __restrict__ C,
    int K, long lda, long ldb, long ldc,
    long sA, long sB, long sC)
{
  __shared__ float As[16][68];
  __shared__ __align__(16) float Bs[16][68];
  const int tid = threadIdx.x;
  const int zz = blockIdx.z;
  const float* Ab = A + zz * sA;
  const float* Bb = Bw + zz * sB;
  float* Cb = C + zz * sC;
  const int brow = blockIdx.y * 64;
  const int bcol = blockIdx.x * 64;
  const int tm = tid >> 4, tn = tid & 15;
  const int lam = tid >> 2;
  const int lak = (tid & 3) << 2;
  const int lbk = tid >> 4;
  const int lbn = (tid & 15) << 2;
  float acc[4][4];
  #pragma unroll
  for (int i = 0; i < 4; i++)
    #pragma unroll
    for (int j = 0; j < 4; j++) acc[i][j] = 0.f;

  for (int k0 = 0; k0 < K; k0 += 16) {
    float4 av = *(const float4*)&Ab[(long)(brow + lam) * lda + k0 + lak];
    As[lak + 0][lam] = av.x; As[lak + 1][lam] = av.y;
    As[lak + 2][lam] = av.z; As[lak + 3][lam] = av.w;
    float4 bv = *(const float4*)&Bb[(long)(k0 + lbk) * ldb + bcol + lbn];
    *(float4*)&Bs[lbk][lbn] = bv;
    __syncthreads();
    #pragma unroll
    for (int kk = 0; kk < 16; kk++) {
      float a0 = As[kk][(tm << 2) + 0], a1 = As[kk][(tm << 2) + 1];
      float a2 = As[kk][(tm << 2) + 2], a3 = As[kk][(tm << 2) + 3];
      float b0 = Bs[kk][(tn << 2) + 0], b1 = Bs[kk][(tn << 2) + 1];
      float b2 = Bs[kk][(tn << 2) + 2], b3 = Bs[kk][(tn << 2) + 3];
      acc[0][0] += a0 * b0; acc[0][1] += a0 * b1; acc[0][2] += a0 * b2; acc[0][3] += a0 * b3;
      acc[1][0] += a1 * b0; acc[1][1] += a1 * b1; acc[1][2] += a1 * b2; acc[1][3] += a1 * b3;
      acc[2][0] += a2 * b0; acc[2][1] += a2 * b1; acc[2][2] += a2 * b2; acc[2][3] += a2 * b3;
      acc[3][0] += a3 * b0; acc[3][1] += a3 * b1; acc[3][2] += a3 * b2; acc[3][3] += a3 * b3;
    }
    __syncthreads();
  }
  #pragma unroll
  for (int i = 0; i < 4; i++) {
    const long row = brow + (tm << 2) + i;
    #pragma unroll
    for (int j = 0; j < 4; j++) {
      const int col = bcol + (tn << 2) + j;
      Cb[row * ldc + col] = acc[i][j];
    }
  }
}

// ---------------- landmarks from bf16 Q/K ----------------
__global__ __launch_bounds__(256) void landmarks_k(const bf* __restrict__ Qb,
    const bf* __restrict__ Kb,
    float* __restrict__ QL, float* __restrict__ KLT,
    bf* __restrict__ QLb, bf* __restrict__ KLb)
{
  int t = blockIdx.x * 256 + threadIdx.x;   // t = h*16384 + m*64 + d
  int d = t & 63; int m = (t >> 6) & 255; int h = t >> 14;
  const unsigned short* qp = (const unsigned short*)Qb + ((long)h * 8192 + m * 32) * 64 + d;
  const unsigned short* kp = (const unsigned short*)Kb + ((long)h * 8192 + m * 32) * 64 + d;
  float sq = 0.f, sk = 0.f;
  for (int i = 0; i < 32; i++) { sq += b2f(qp[i * 64]); sk += b2f(kp[i * 64]); }
  float qv = sq * (1.f / 32.f);       // Qb already prescaled 0.125
  QL[t] = qv;
  QLb[t] = __float2bfloat16(qv);
  float kv = sk * (1.f / 32.f);
  KLb[t] = __float2bfloat16(kv);
  KLT[(h << 14) + (d << 8) + m] = kv;
}

// ---------------- V transpose (bf16 -> bf16): VT[h][d][n] ----------------
__global__ __launch_bounds__(256) void vt_k(const bf* __restrict__ Vb,
    bf* __restrict__ VT)
{
  __shared__ unsigned short t[64][68];
  const int h = blockIdx.x & 7; const int n0 = (blockIdx.x >> 3) << 6;
  const int c = threadIdx.x & 63; const int r4 = threadIdx.x >> 6;
  const unsigned short* vp = (const unsigned short*)Vb;
  unsigned short* vo = (unsigned short*)VT;
  #pragma unroll 4
  for (int i = 0; i < 16; i++) {
    int r = r4 * 16 + i;
    t[r][c] = vp[((long)h * 8192 + n0 + r) * 64 + c];
  }
  __syncthreads();
  #pragma unroll 4
  for (int i = 0; i < 16; i++) {
    int d = r4 * 16 + i;
    vo[((long)(h << 6) + d) * 8192 + n0 + c] = t[c][d];
  }
}

// ---------------- row softmax, width 256, f32 in place ----------------
__global__ __launch_bounds__(256) void softmax256_k(float* __restrict__ X)
{
  __shared__ float red[256];
  const long row = blockIdx.x; const int tid = threadIdx.x;
  float v = X[row * 256 + tid];
  red[tid] = v; __syncthreads();
  for (int s = 128; s > 0; s >>= 1) { if (tid < s) red[tid] = fmaxf(red[tid], red[tid + s]); __syncthreads(); }
  float M = red[0]; __syncthreads();
  float e = __expf(v - M);
  red[tid] = e; __syncthreads();
  for (int s = 128; s > 0; s >>= 1) { if (tid < s) red[tid] += red[tid + s]; __syncthreads(); }
  float S = red[0];
  X[row * 256 + tid] = e / S;
}

// ---------------- pinv scalars ----------------
__global__ __launch_bounds__(256) void rowsum_k(const float* __restrict__ X, float* __restrict__ out)
{
  int t = blockIdx.x * 256 + threadIdx.x;
  const float* r = X + (long)t * 256;
  float s = 0.f;
  for (int j = 0; j < 256; j++) s += fabsf(r[j]);
  out[t] = s;
}
__global__ __launch_bounds__(256) void colsum_k(const float* __restrict__ X, float* __restrict__ out)
{
  int t = blockIdx.x * 256 + threadIdx.x; int h = t >> 8; int j = t & 255;
  const float* c = X + ((long)h << 16) + j;
  float s = 0.f;
  for (int i = 0; i < 256; i++) s += fabsf(c[(long)i << 8]);
  out[t] = s;
}
__global__ __launch_bounds__(256) void invscale_k(const float* __restrict__ rows,
    const float* __restrict__ cols, float* __restrict__ inv)
{
  __shared__ float red[256];
  int tid = threadIdx.x;
  float mr = -1e30f, mc = -1e30f;
  for (int i = tid; i < 2048; i += 256) { mr = fmaxf(mr, rows[i]); mc = fmaxf(mc, cols[i]); }
  red[tid] = mr; __syncthreads();
  for (int s = 128; s > 0; s >>= 1) { if (tid < s) red[tid] = fmaxf(red[tid], red[tid + s]); __syncthreads(); }
  mr = red[0]; __syncthreads();
  red[tid] = mc; __syncthreads();
  for (int s = 128; s > 0; s >>= 1) { if (tid < s) red[tid] = fmaxf(red[tid], red[tid + s]); __syncthreads(); }
  mc = red[0];
  if (tid == 0) inv[0] = 1.0f / (mr * mc);
}

// ---------------- pinv init: Xbf, z0 = X^T*inv, z0T = X*inv ----------------
__global__ __launch_bounds__(256) void xz_init_k(const float* __restrict__ ATT2,
    const float* __restrict__ inv, bf* __restrict__ Xb,
    bf* __restrict__ z0, bf* __restrict__ z0T)
{
  __shared__ float t[64][65];
  const int h = blockIdx.z;
  const int j0 = blockIdx.x << 6, i0 = blockIdx.y << 6;
  const int c = threadIdx.x & 63; const int r4 = threadIdx.x >> 6;
  const float iv = inv[0];
  #pragma unroll 4
  for (int i = 0; i < 16; i++) {
    int r = r4 * 16 + i;
    float v = ATT2[((long)h << 16) + (long)(i0 + r) * 256 + j0 + c];
    t[r][c] = v;
    Xb[((long)h << 16) + (long)(i0 + r) * 256 + j0 + c]  = __float2bfloat16(v);
    z0T[((long)h << 16) + (long)(i0 + r) * 256 + j0 + c] = __float2bfloat16(v * iv);
  }
  __syncthreads();
  #pragma unroll 4
  for (int i = 0; i < 16; i++) {
    int r = r4 * 16 + i;
    z0[((long)h << 16) + (long)(j0 + r) * 256 + i0 + c] = __float2bfloat16(t[c][r] * iv);
  }
}

// ---------------- flash attn3: per (chunk, mtile, head) partials ----------------
__global__ __launch_bounds__(256) void attn3f_k(
    const bf* __restrict__ Qlb, const bf* __restrict__ Kb, const bf* __restrict__ Vt,
    float* __restrict__ Op, float* __restrict__ Mp, float* __restrict__ Lp)
{
  __shared__ __align__(16) short Qs[2][128][32];
  __shared__ __align__(16) short Ks[2][128][32];
  __shared__ __align__(16) short Vs[4][64][32];
  __shared__ __align__(16) short Ps[4][4][32][32];
  const int tid = threadIdx.x, lane = tid & 63, wid = tid >> 6;
  const int fr = lane & 15, fs = lane >> 4;
  const int srow = lane >> 2, skp = (lane & 3) << 3;
  const int chunk = blockIdx.x, mt = blockIdx.y, h = blockIdx.z;
  const int wrb = wid << 5;
  const bf* Qg = Qlb + ((long)h * 256 + mt * 128) * 64;
  #pragma unroll
  for (int i = 0; i < 4; i++) {
    int c = (wid << 2) + i, rg = c >> 1, hf = c & 1;
    gl_lds16(Qg + (long)(rg * 16 + srow) * 64 + hf * 32 + skp, &Qs[hf][rg * 16][0]);
  }
  f32x4 acc2[2][4];
  float mrun[2][4], lrun[2][4];
  #pragma unroll
  for (int m = 0; m < 2; m++)
    #pragma unroll
    for (int n = 0; n < 4; n++) { acc2[m][n] = (f32x4){0.f,0.f,0.f,0.f}; mrun[m][n] = -1e30f; lrun[m][n] = 0.f; }

  for (int t = 0; t < 8; t++) {
    const int key0 = (chunk << 10) + (t << 7);
    const bf* Kg = Kb + ((long)h * 8192 + key0) * 64;
    #pragma unroll
    for (int i = 0; i < 4; i++) {
      int c = (wid << 2) + i, rg = c >> 1, hf = c & 1;
      gl_lds16(Kg + (long)(rg * 16 + srow) * 64 + hf * 32 + skp, &Ks[hf][rg * 16][0]);
    }
    #pragma unroll
    for (int i = 0; i < 4; i++) {
      int c = (wid << 2) + i, dg = c >> 2, ks = c & 3;
      gl_lds16(Vt + ((long)h * 64 + dg * 16 + srow) * 8192 + key0 + ks * 32 + skp,
               &Vs[ks][dg * 16][0]);
    }
    __syncthreads();
    f32x4 lac[2][8];
    #pragma unroll
    for (int m = 0; m < 2; m++)
      #pragma unroll
      for (int n = 0; n < 8; n++) lac[m][n] = (f32x4){0.f,0.f,0.f,0.f};
    #pragma unroll
    for (int kk = 0; kk < 2; kk++) {
      short8 a[2];
      #pragma unroll
      for (int m = 0; m < 2; m++)
        a[m] = *(const short8*)&Qs[kk][wrb + m * 16 + fr][fs * 8];
      #pragma unroll
      for (int n = 0; n < 8; n++) {
        short8 b = *(const short8*)&Ks[kk][n * 16 + fr][fs * 8];
        #pragma unroll
        for (int m = 0; m < 2; m++)
          lac[m][n] = __builtin_amdgcn_mfma_f32_16x16x32_bf16(a[m], b, lac[m][n], 0, 0, 0);
      }
    }
    #pragma unroll
    for (int m = 0; m < 2; m++) {
      #pragma unroll
      for (int j = 0; j < 4; j++) {
        float tmax = lac[m][0][j];
        #pragma unroll
        for (int n = 1; n < 8; n++) tmax = fmaxf(tmax, lac[m][n][j]);
        tmax = fmaxf(tmax, __shfl_xor(tmax, 1));
        tmax = fmaxf(tmax, __shfl_xor(tmax, 2));
        tmax = fmaxf(tmax, __shfl_xor(tmax, 4));
        tmax = fmaxf(tmax, __shfl_xor(tmax, 8));
        float mnew = fmaxf(mrun[m][j], tmax);
        float sc = __expf(mrun[m][j] - mnew);
        #pragma unroll
        for (int n2 = 0; n2 < 4; n2++) acc2[m][n2][j] *= sc;
        float lsum = 0.f;
        #pragma unroll
        for (int n = 0; n < 8; n++) {
          float p = __expf(lac[m][n][j] - mnew);
          lac[m][n][j] = p; lsum += p;
        }
        lsum += __shfl_xor(lsum, 1);
        lsum += __shfl_xor(lsum, 2);
        lsum += __shfl_xor(lsum, 4);
        lsum += __shfl_xor(lsum, 8);
        lrun[m][j] = lrun[m][j] * sc + lsum;
        mrun[m][j] = mnew;
      }
    }
    #pragma unroll
    for (int m = 0; m < 2; m++)
      #pragma unroll
      for (int n = 0; n < 8; n++) {
        int col = n * 16 + fr;
        #pragma unroll
        for (int j = 0; j < 4; j++)
          Ps[wid][col >> 5][m * 16 + fs * 4 + j][col & 31] = (short)f2b(lac[m][n][j]);
      }
    #pragma unroll
    for (int ks = 0; ks < 4; ks++) {
      short8 a2[2];
      #pragma unroll
      for (int m = 0; m < 2; m++)
        a2[m] = *(const short8*)&Ps[wid][ks][m * 16 + fr][fs * 8];
      #pragma unroll
      for (int n = 0; n < 4; n++) {
        short8 b2 = *(const short8*)&Vs[ks][n * 16 + fr][fs * 8];
        #pragma unroll
        for (int m = 0; m < 2; m++)
          acc2[m][n] = __builtin_amdgcn_mfma_f32_16x16x32_bf16(a2[m], b2, acc2[m][n], 0, 0, 0);
      }
    }
    __syncthreads();
  }
  const long base = (long)(chunk * 8 + h) * 2 + mt;
  #pragma unroll
  for (int m = 0; m < 2; m++)
    #pragma unroll
    for (int n = 0; n < 4; n++) {
      int col = n * 16 + fr;
      #pragma unroll
      for (int j = 0; j < 4; j++)
        Op[base * 8192 + (long)(wrb + m * 16 + fs * 4 + j) * 64 + col] = acc2[m][n][j];
    }
  if (fr == 0) {
    #pragma unroll
    for (int m = 0; m < 2; m++)
      #pragma unroll
      for (int j = 0; j < 4; j++) {
        int r = wrb + m * 16 + fs * 4 + j;
        Mp[base * 128 + r] = mrun[m][j];
        Lp[base * 128 + r] = lrun[m][j];
      }
  }
}

// ---------------- flash attn3 combine -> AVT bf16 [h][d][m] ----------------
__global__ __launch_bounds__(256) void attn3c_k(
    const float* __restrict__ Op, const float* __restrict__ Mp,
    const float* __restrict__ Lp, bf* __restrict__ AVT)
{
  __shared__ float wm[8][128];
  __shared__ float wl[8][128];
  const int bid = blockIdx.x;
  const int h = bid >> 1, mt = bid & 1, tid = threadIdx.x;
  for (int i = 0; i < 4; i++) {
    int idx = i * 256 + tid;
    int c = idx >> 7, r = idx & 127;
    wm[c][r] = Mp[((long)(c * 8 + h) * 2 + mt) * 128 + r];
    wl[c][r] = Lp[((long)(c * 8 + h) * 2 + mt) * 128 + r];
  }
  __syncthreads();
  if (tid < 128) {
    float M = wm[0][tid];
    #pragma unroll
    for (int c = 1; c < 8; c++) M = fmaxf(M, wm[c][tid]);
    float D = 0.f;
    #pragma unroll
    for (int c = 0; c < 8; c++) D += __expf(wm[c][tid] - M) * wl[c][tid];
    float rv = 1.0f / D;
    #pragma unroll
    for (int c = 0; c < 8; c++) wm[c][tid] = __expf(wm[c][tid] - M) * rv;
  }
  __syncthreads();
  for (int i = 0; i < 32; i++) {
    int idx = i * 256 + tid;
    int r = idx >> 6, d = idx & 63;
    float s = 0.f;
    #pragma unroll
    for (int c = 0; c < 8; c++)
      s += wm[c][r] * Op[((long)(c * 8 + h) * 2 + mt) * 8192 + (long)r * 64 + d];
    AVT[(long)h * 16384 + d * 256 + mt * 128 + r] = __float2bfloat16(s);
  }
}

// ---------------- fused attn1: logits -> softmax -> @CM -> Bhbf ----------------
__global__ __launch_bounds__(256) void attn1_k(
    const bf* __restrict__ Qb, const bf* __restrict__ KLb,
    const bf* __restrict__ CMT, bf* __restrict__ Bhb)
{
  __shared__ __align__(16) char U[65536];
  short (*As)[128][32] = (short(*)[128][32])U;           // [2][128][32]
  short (*Bs)[256][32] = (short(*)[256][32])(U + 16384); // [2][256][32]
  short (*Ps)[128][32] = (short(*)[128][32])U;           // [8][128][32] aliases As+Bs
  __shared__ __align__(16) short Cs[8][64][32];
  __shared__ float red[2][2][128];

  const int tid = threadIdx.x;
  const int lane = tid & 63, wid = tid >> 6;
  const int fr = lane & 15, fs = lane >> 4;
  const int srow = lane >> 2, skp = (lane & 3) << 3;
  const int n0 = blockIdx.x << 7, h = blockIdx.y;
  const int half = wid & 1, wrb = (wid >> 1) << 6;

  const bf* Aq = Qb  + (long)h * 524288 + (long)n0 * 64;
  const bf* Bk = KLb + (long)h * 16384;
  const bf* Cm = CMT + (long)h * 16384;

  for (int i = 0; i < 20; i++) {
    int c = wid * 20 + i;
    if (c < 16) {
      int rg = c >> 1, hf = c & 1;
      gl_lds16(Aq + (long)(rg * 16 + srow) * 64 + hf * 32 + skp, &As[hf][rg * 16][0]);
    } else if (c < 48) {
      int c2 = c - 16; int rg = c2 >> 1, hf = c2 & 1;
      gl_lds16(Bk + (long)(rg * 16 + srow) * 64 + hf * 32 + skp, &Bs[hf][rg * 16][0]);
    } else {
      int c3 = c - 48; int rg = c3 >> 3, ks = c3 & 7;
      gl_lds16(Cm + (long)(rg * 16 + srow) * 256 + ks * 32 + skp, &Cs[ks][rg * 16][0]);
    }
  }
  __syncthreads();

  f32x4 acc[4][8];
  #pragma unroll
  for (int m = 0; m < 4; m++)
    #pragma unroll
    for (int n = 0; n < 8; n++) acc[m][n] = (f32x4){0.f, 0.f, 0.f, 0.f};
  #pragma unroll
  for (int kk = 0; kk < 2; kk++) {
    short8 a[4];
    #pragma unroll
    for (int m = 0; m < 4; m++)
      a[m] = *(const short8*)&As[kk][wrb + m * 16 + fr][fs * 8];
    #pragma unroll
    for (int n = 0; n < 8; n++) {
      short8 b = *(const short8*)&Bs[kk][half * 128 + n * 16 + fr][fs * 8];
      #pragma unroll
      for (int m = 0; m < 4; m++)
        acc[m][n] = __builtin_amdgcn_mfma_f32_16x16x32_bf16(a[m], b, acc[m][n], 0, 0, 0);
    }
  }

  #pragma unroll
  for (int m = 0; m < 4; m++)
    #pragma unroll
    for (int j = 0; j < 4; j++) {
      float mx = -1e30f;
      #pragma unroll
      for (int n = 0; n < 8; n++) mx = fmaxf(mx, acc[m][n][j]);
      mx = fmaxf(mx, __shfl_xor(mx, 1));
      mx = fmaxf(mx, __shfl_xor(mx, 2));
      mx = fmaxf(mx, __shfl_xor(mx, 4));
      mx = fmaxf(mx, __shfl_xor(mx, 8));
      int rloc = wrb + m * 16 + fs * 4 + j;
      if (fr == 0) red[0][half][rloc] = mx;
    }
  __syncthreads();
  #pragma unroll
  for (int m = 0; m < 4; m++)
    #pragma unroll
    for (int j = 0; j < 4; j++) {
      int rloc = wrb + m * 16 + fs * 4 + j;
      float Mx = fmaxf(red[0][0][rloc], red[0][1][rloc]);
      float s = 0.f;
      #pragma unroll
      for (int n = 0; n < 8; n++) {
        float e = __expf(acc[m][n][j] - Mx);
        acc[m][n][j] = e; s += e;
      }
      s += __shfl_xor(s, 1);
      s += __shfl_xor(s, 2);
      s += __shfl_xor(s, 4);
      s += __shfl_xor(s, 8);
      if (fr == 0) red[1][half][rloc] = s;
    }
  __syncthreads();
  #pragma unroll
  for (int m = 0; m < 4; m++)
    #pragma unroll
    for (int j = 0; j < 4; j++) {
      int rloc = wrb + m * 16 + fs * 4 + j;
      float inv = 1.0f / (red[1][0][rloc] + red[1][1][rloc]);
      #pragma unroll
      for (int n = 0; n < 8; n++) {
        int col = half * 128 + n * 16 + fr;
        Ps[col >> 5][rloc][col & 31] = (short)f2b(acc[m][n][j] * inv);
      }
    }
  __syncthreads();

  f32x4 acc2[4][2];
  #pragma unroll
  for (int m = 0; m < 4; m++)
    #pragma unroll
    for (int n = 0; n < 2; n++) acc2[m][n] = (f32x4){0.f, 0.f, 0.f, 0.f};
  const int wc2 = half * 32;
  #pragma unroll
  for (int kk = 0; kk < 8; kk++) {
    short8 a2[4];
    #pragma unroll
    for (int m = 0; m < 4; m++)
      a2[m] = *(const short8*)&Ps[kk][wrb + m * 16 + fr][fs * 8];
    #pragma unroll
    for (int n = 0; n < 2; n++) {
      short8 b2 = *(const short8*)&Cs[kk][wc2 + n * 16 + fr][fs * 8];
      #pragma unroll
      for (int m = 0; m < 4; m++)
        acc2[m][n] = __builtin_amdgcn_mfma_f32_16x16x32_bf16(a2[m], b2, acc2[m][n], 0, 0, 0);
    }
  }
  #pragma unroll
  for (int m = 0; m < 4; m++)
    #pragma unroll
    for (int n = 0; n < 2; n++) {
      int col = wc2 + n * 16 + fr;
      #pragma unroll
      for (int j = 0; j < 4; j++) {
        long row = n0 + wrb + m * 16 + fs * 4 + j;
        Bhb[row * 512 + h * 64 + col] = __float2bfloat16(acc2[m][n][j]);
      }
    }
}

// ---------------- depthwise conv residual, bf16 RMW into Bhbf ----------------
__global__ __launch_bounds__(256) void convres_k(const bf* __restrict__ Vb,
    const float* __restrict__ W, bf* __restrict__ Bhb)
{
  const int gid = blockIdx.x * 256 + threadIdx.x;   // 0..1048575
  const int n = gid >> 7, q = gid & 127;
  const int j0 = q << 2, h = j0 >> 6, d0 = j0 & 63;
  float a0 = 0.f, a1 = 0.f, a2 = 0.f, a3 = 0.f;
  const unsigned short* vb = (const unsigned short*)Vb + (long)h * 524288 + d0;
  #pragma unroll
  for (int kk = 0; kk < 33; kk++) {
    int nn = n + kk - 16;
    if (nn >= 0 && nn < 8192) {
      float w = W[h * 33 + kk];
      uint2 raw = *(const uint2*)(vb + (long)nn * 64);
      a0 += w * b2f(raw.x & 0xffff); a1 += w * b2f(raw.x >> 16);
      a2 += w * b2f(raw.y & 0xffff); a3 += w * b2f(raw.y >> 16);
    }
  }
  unsigned short* o = (unsigned short*)Bhb + (long)n * 512 + j0;
  uint2 cur = *(uint2*)o;
  uint2 outv;
  outv.x = (unsigned)f2b(b2f(cur.x & 0xffff) + a0) | ((unsigned)f2b(b2f(cur.x >> 16) + a1) << 16);
  outv.y = (unsigned)f2b(b2f(cur.y & 0xffff) + a2) | ((unsigned)f2b(b2f(cur.y >> 16) + a3) << 16);
  *(uint2*)o = outv;
}

// ---------------- host ----------------
extern "C" void kernel_launch(void* const* d_in, const int* in_sizes, int n_in,
                              void* d_out, int out_size, void* d_ws, size_t ws_size,
                              hipStream_t stream)
{
  const float* x     = (const float*)d_in[0];
  const float* cls   = (const float*)d_in[1];
  const float* ln1g  = (const float*)d_in[2];
  const float* ln1b  = (const float*)d_in[3];
  const float* wqkv  = (const float*)d_in[4];
  const float* wout  = (const float*)d_in[5];
  const float* bout  = (const float*)d_in[6];
  const float* convw = (const float*)d_in[7];
  const float* ln2g  = (const float*)d_in[8];
  const float* ln2b  = (const float*)d_in[9];
  const float* w1    = (const float*)d_in[10];
  const float* b1    = (const float*)d_in[11];
  const float* w2    = (const float*)d_in[12];
  const float* b2    = (const float*)d_in[13];
  float* out = (float*)d_out;
  float* ws  = (float*)d_ws;

  // allow 128 KiB dynamic LDS on the panel-staged GEMMs (host-side, capture-safe)
  const int DLDS = 131072;
  hipFuncSetAttribute((const void*)mgemm<1,2>, hipFuncAttributeMaxDynamicSharedMemorySize, DLDS);
  hipFuncSetAttribute((const void*)mgemm<1,8>, hipFuncAttributeMaxDynamicSharedMemorySize, DLDS);
  hipFuncSetAttribute((const void*)mgemm<2,2>, hipFuncAttributeMaxDynamicSharedMemorySize, DLDS);
  hipFuncSetAttribute((const void*)mgemm<3,2>, hipFuncAttributeMaxDynamicSharedMemorySize, DLDS);
  hipFuncSetAttribute((const void*)bgemm<3>,   hipFuncAttributeMaxDynamicSharedMemorySize, DLDS);
  hipFuncSetAttribute((const void*)bgemm<4>,   hipFuncAttributeMaxDynamicSharedMemorySize, DLDS);
  hipFuncSetAttribute((const void*)bgemm<5>,   hipFuncAttributeMaxDynamicSharedMemorySize, DLDS);
  hipFuncSetAttribute((const void*)bgemm<6>,   hipFuncAttributeMaxDynamicSharedMemorySize, DLDS);

  float* A     = ws + 0;              // [8192][512] f32
  float* QL    = ws + 4194304;        // [8][256][64]
  float* KLT   = ws + 4325376;        // [8][64][256]
  float* ATT2  = ws + 4456448;        // [8][256][256]
  float* rsum  = ws + 4980736;
  float* csum  = ws + 4982784;
  float* inv   = ws + 4984832;        // 8
  float* Opart = ws + 4984840;        // [8][8][2][128][64] f32
  float* Mpart = ws + 6033416;        // [8][8][2][128]
  float* Lpart = ws + 6049800;
  bf* Qbf  = (bf*)(ws + 6066184);     // [8][8192][64] prescaled 0.125
  bf* Kbf  = (bf*)(ws + 8163336);     // [8][8192][64]
  bf* Vbf  = (bf*)(ws + 10260488);    // [8][8192][64]
  bf* VT   = (bf*)(ws + 12357640);    // [8][64][8192]
  bf* QLbf = (bf*)(ws + 14454792);    // [8][256][64]
  bf* KLbf = (bf*)(ws + 14520328);
  bf* Xbf  = (bf*)(ws + 14585864);    // [8][256][256]
  bf* zA   = (bf*)(ws + 14848008);
  bf* zAT  = (bf*)(ws + 15110152);
  bf* zB   = (bf*)(ws + 15372296);
  bf* zBT  = (bf*)(ws + 15634440);
  bf* Gbf  = (bf*)(ws + 15896584);
  bf* TB0  = (bf*)(ws + 16158728);
  bf* TB1  = (bf*)(ws + 16420872);
  bf* AVT  = (bf*)(ws + 16683016);    // [8][64][256]
  bf* CMT  = (bf*)(ws + 16748552);    // [8][64][256]
  float* R = ws + 16814088;           // reusable region (8.39M floats)
  bf* wqkvT = (bf*)R;                 // [1536][512]
  bf* ln1bf = (bf*)(R + 393216);      // [8192][512]
  bf* Bhbf  = (bf*)(R + 393216);      // [8192][512] (after ln1bf dead)
  bf* FF1bf = (bf*)R;                 // [8192][2048] (after Bhbf dead)
  bf* w1T   = Kbf;                    // [2048][512] alias (Kbf dead after attn3f)
  bf* w2T   = Kbf + 1048576;          // [512][2048]
  bf* woutT = Kbf + 2097152;          // [512][512]
  bf* ln2bf = VT;                     // [8192][512] alias (VT dead after attn3f)

  concat_ln_k<<<8192, 256, 0, stream>>>(x, cls, ln1g, ln1b, A, ln1bf);
  tconv_k<<<dim3(24, 8), 256, 0, stream>>>(wqkv, wqkvT, 512, 1536);
  // qkv: head-major bf16 Q(.125)/K/V   (panel-staged MFMA, K=512)
  mgemm<3,2><<<dim3(12, 64), 256, DLDS, stream>>>(ln1bf, wqkvT, nullptr, nullptr, nullptr,
      1536, Qbf, Kbf, Vbf);
  landmarks_k<<<512, 256, 0, stream>>>(Qbf, Kbf, QL, KLT, QLbf, KLbf);
  vt_k<<<1024, 256, 0, stream>>>(Vbf, VT);
  // attn2 logits (fp32) + softmax + pinv scalars
  sgemm_k<<<dim3(4, 4, 8), 256, 0, stream>>>(QL, KLT, ATT2,
      64, 64, 256, 256, 16384, 16384, 65536);
  softmax256_k<<<2048, 256, 0, stream>>>(ATT2);
  rowsum_k<<<8, 256, 0, stream>>>(ATT2, rsum);
  colsum_k<<<8, 256, 0, stream>>>(ATT2, csum);
  invscale_k<<<1, 256, 0, stream>>>(rsum, csum, inv);
  xz_init_k<<<dim3(4, 4, 8), 256, 0, stream>>>(ATT2, inv, Xbf, zA, zAT);
  // pinv: 6 iters x 4 single-panel MFMA GEMMs (K=256, zero mid-kernel barriers)
  bf* zc = zA; bf* zcT = zAT; bf* zn = zB; bf* znT = zBT;
  for (int it = 0; it < 6; ++it) {
    bgemm<3><<<dim3(2, 2, 8), 256, DLDS, stream>>>(Xbf, zcT, Gbf, TB0,
        256, 1.f, 7.f, 256, 256, 256, 256, 65536, 65536, 65536, 65536);
    bgemm<4><<<dim3(2, 2, 8), 256, DLDS, stream>>>(Gbf, TB0, nullptr, TB1,
        256, 1.f, 15.f, 256, 256, 256, 256, 65536, 65536, 0, 65536);
    bgemm<4><<<dim3(2, 2, 8), 256, DLDS, stream>>>(Gbf, TB1, nullptr, TB0,
        256, 1.f, 13.f, 256, 256, 256, 256, 65536, 65536, 0, 65536);
    bgemm<5><<<dim3(2, 2, 8), 256, DLDS, stream>>>(zc, TB0, zn, znT,
        256, 0.25f, 0.f, 256, 256, 256, 256, 65536, 65536, 65536, 65536);
    bf* t;
    t = zc; zc = zn; zn = t;
    t = zcT; zcT = znT; znT = t;
  }
  // flash attn3 + combine -> AVT
  attn3f_k<<<dim3(8, 2, 8), 256, 0, stream>>>(QLbf, Kbf, VT, Opart, Mpart, Lpart);
  attn3c_k<<<16, 256, 0, stream>>>(Opart, Mpart, Lpart, AVT);
  // CM^T = (Z @ AV)^T
  bgemm<6><<<dim3(1, 2, 8), 256, DLDS, stream>>>(zc, AVT, nullptr, CMT,
      64, 1.f, 0.f, 256, 256, 0, 256, 65536, 16384, 0, 16384);
  // weight transposes (Kbf/VT now dead)
  tconv_k<<<dim3(32, 8), 256, 0, stream>>>(w1, w1T, 512, 2048);
  tconv_k<<<dim3(8, 32), 256, 0, stream>>>(w2, w2T, 2048, 512);
  tconv_k<<<dim3(8, 8), 256, 0, stream>>>(wout, woutT, 512, 512);
  // fused attn1 -> Bhbf, conv residual RMW
  attn1_k<<<dim3(64, 8), 256, 0, stream>>>(Qbf, KLbf, CMT, Bhbf);
  convres_k<<<4096, 256, 0, stream>>>(Vbf, convw, Bhbf);
  // A = A + Bh @ wout + bout   (K=512)
  mgemm<1,2><<<dim3(4, 64), 256, DLDS, stream>>>(Bhbf, woutT, A, A, bout, 512,
      nullptr, nullptr, nullptr);
  ln_bf16_k<<<8192, 256, 0, stream>>>(A, ln2g, ln2b, ln2bf);
  // FF1 = gelu(ln2 @ w1 + b1)  (bf16 out, K=512)
  mgemm<2,2><<<dim3(16, 64), 256, DLDS, stream>>>(ln2bf, w1T, FF1bf, nullptr, b1, 2048,
      nullptr, nullptr, nullptr);
  // out = A + FF1 @ w2 + b2   (K=2048)
  mgemm<1,8><<<dim3(4, 64), 256, DLDS, stream>>>(FF1bf, w2T, out, A, b2, 512,
      nullptr, nullptr, nullptr);
}